// Round 15
// baseline (5691.375 us; speedup 1.0000x reference)
//
#include <hip/hip_runtime.h>
#include <hip/hip_bf16.h>
#include <math.h>

#define DEPTH   6
#define DIM     200
#define HEADS   10
#define DH      20
#define NBF     59
#define FFD     800
#define DMODEL  512
#define NSEQ    64
#define SEQ     2048
#define NTOK    (NSEQ*SEQ)   // 131072
#define KPAD    224          // ceil(200/32)*32
#define BUFPAD  64
#define KNROW   40           // staged row stride (shorts) for kn/qn/proj
#define VROW    136          // vT row stride
#define KPROW   136          // kp row stride
#define QPROW   72           // qp / ctxT row stride
#define CTXR    21           // ctx rows stored (d=0..19 + ksum row 20)
#define HSROW   132          // ff hidden LDS row stride (66 dwords == 2 mod 32)
// panel element counts
#define PKV_E   (512*KPAD)
#define PQ_E    (256*KPAD)
#define PWO_E   (256*KPAD)
#define PF1_E   (896*KPAD)
#define PF2_E   (256*800)

typedef __hip_bfloat16 bf16;
typedef unsigned short u16;
typedef short s8v __attribute__((ext_vector_type(8)));
typedef short s4v __attribute__((ext_vector_type(4)));
typedef float f4v __attribute__((ext_vector_type(4)));

constexpr float SCALE = 0.4728708045015879f;   // 20^-0.25
constexpr float RATIO = 0.1301889109808239f;   // 59^-0.5
constexpr float KEPS  = 1e-4f;

__device__ __forceinline__ float b2f(bf16 v) { return __bfloat162float(v); }
__device__ __forceinline__ bf16 f2b(float v) { return __float2bfloat16(v); }
__device__ __forceinline__ float bfu(u16 u) {
    return __uint_as_float(((unsigned)u) << 16);
}
__device__ __forceinline__ u16 f2u(float v) {
    bf16 hb = __float2bfloat16(v);
    return *(u16*)&hb;
}
// tanh-form gelu: max |diff| vs exact-erf gelu ~5e-4, far below bf16 quantum
// of the hidden activations; overflow-safe (e->inf => factor->1).
__device__ __forceinline__ float gelu_f(float x) {
    float inner = 0.7978845608028654f * (x + 0.044715f * x * x * x);
    float e = __expf(2.f * inner);
    return x * (1.f - 1.f / (e + 1.f));
}
// async global -> LDS, 16B per lane; LDS dest = wave-uniform base + lane*16
__device__ __forceinline__ void gld_lds16(const short* g, short* l) {
    __builtin_amdgcn_global_load_lds(
        (const __attribute__((address_space(1))) void*)g,
        (__attribute__((address_space(3))) void*)l, 16, 0, 0);
}
#define MFMA16(a, b, c) __builtin_amdgcn_mfma_f32_16x16x32_bf16(a, b, c, 0, 0, 0)

// ---------------- sentinel: encodes ws_size(MB) into out[0] ----------------
__global__ void sentinel_kernel(float* out, float wsmb) {
    if (threadIdx.x == 0) out[0] = wsmb;
}

__global__ void zeropad_kernel(bf16* p1, bf16* p2, bf16* p3, bf16* p4) {
    int i = threadIdx.x;
    if (i < BUFPAD) {
        bf16 z = f2b(0.f);
        p1[i] = z; p2[i] = z; p3[i] = z; p4[i] = z;
    }
}

// ---- per-layer prep: all weight panels + LN-fold vectors, one launch ------
// uw layout (floats): [0..511]=ukv [512..1023]=wkv [1024..1279]=uq
// [1280..1535]=wq [1536..2431]=u1 [2432..3327]=w1
__global__ __launch_bounds__(256) void prep_layer(
        const float* __restrict__ wq, const float* __restrict__ wk,
        const float* __restrict__ wv, const float* __restrict__ wo,
        const float* __restrict__ f1, const float* __restrict__ f2,
        const float* __restrict__ g1, const float* __restrict__ b1,
        const float* __restrict__ g2, const float* __restrict__ b2,
        const float* __restrict__ bq, const float* __restrict__ bk,
        const float* __restrict__ bv, const float* __restrict__ f1b,
        bf16* __restrict__ pKV, bf16* __restrict__ pQ, bf16* __restrict__ pWO,
        bf16* __restrict__ pF1, bf16* __restrict__ pF2,
        float* __restrict__ uw) {
    int b = blockIdx.x, t = threadIdx.x;
    if (b < 448) {                      // pKV: rows 0..255 = k, 256..511 = v
        int idx = b * 256 + t;
        int row = idx / KPAD, k = idx % KPAD;
        float v = 0.f;
        if (k < DIM) {
            if (row < DIM) v = wk[(size_t)k * DIM + row] * g1[k];
            else if (row >= 256 && row < 256 + DIM)
                v = wv[(size_t)k * DIM + (row - 256)] * g1[k];
        }
        pKV[idx] = f2b(v);
    } else if (b < 672) {               // pQ
        int idx = (b - 448) * 256 + t;
        int row = idx / KPAD, k = idx % KPAD;
        float v = (row < DIM && k < DIM) ? wq[(size_t)k * DIM + row] * g1[k] : 0.f;
        pQ[idx] = f2b(v);
    } else if (b < 896) {               // pWO (no fold)
        int idx = (b - 672) * 256 + t;
        int row = idx / KPAD, k = idx % KPAD;
        float v = (row < DIM && k < DIM) ? wo[(size_t)k * DIM + row] : 0.f;
        pWO[idx] = f2b(v);
    } else if (b < 1680) {              // pF1 (g2-folded)
        int idx = (b - 896) * 256 + t;
        int row = idx / KPAD, k = idx % KPAD;
        float v = (row < FFD && k < DIM) ? f1[(size_t)k * FFD + row] * g2[k] : 0.f;
        pF1[idx] = f2b(v);
    } else if (b < 2480) {              // pF2 [256][800]
        int idx = (b - 1680) * 256 + t;
        int row = idx / 800, k = idx % 800;
        float v = (row < DIM) ? f2[(size_t)k * DIM + row] : 0.f;
        pF2[idx] = f2b(v);
    } else if (b < 2482) {              // u/w for fused KV
        int j = b - 2480;
        const float* W    = j ? wv : wk;
        const float* bias = j ? bv : bk;
        int n = t;
        float su = 0.f, sw = 0.f;
        if (n < DIM) {
            for (int k = 0; k < DIM; ++k) {
                float wvv = W[(size_t)k * DIM + n];
                su += g1[k] * wvv;
                sw += b1[k] * wvv;
            }
            sw += bias[n];
        }
        uw[j * 256 + n] = su;
        uw[512 + j * 256 + n] = sw;
    } else if (b == 2482) {             // u/w for Q
        int n = t;
        float su = 0.f, sw = 0.f;
        if (n < DIM) {
            for (int k = 0; k < DIM; ++k) {
                float wvv = wq[(size_t)k * DIM + n];
                su += g1[k] * wvv;
                sw += b1[k] * wvv;
            }
            sw += bq[n];
        }
        uw[1024 + n] = su;
        uw[1280 + n] = sw;
    } else {                            // u/w for FF1 (896 outputs)
        int n = (b - 2483) * 256 + t;
        if (n < 896) {
            float su = 0.f, sw = 0.f;
            if (n < FFD) {
                for (int k = 0; k < DIM; ++k) {
                    float wvv = f1[(size_t)k * FFD + n];
                    su += g2[k] * wvv;
                    sw += b2[k] * wvv;
                }
                sw += f1b[n];
            }
            uw[1536 + n] = su;
            uw[2432 + n] = sw;
        }
    }
}

// ---------------- embedding: tokens are 1 (x<=0) or 5 (x>0) ----------------
__global__ __launch_bounds__(256) void embed_kernel(const float* __restrict__ x,
        const float* __restrict__ emb, bf16* __restrict__ x1, bf16* __restrict__ x2) {
    int idx = blockIdx.x * 256 + threadIdx.x;      // NTOK*25
    if (idx >= NTOK * 25) return;
    int t = idx / 25, c = idx % 25;
    int row = (x[t] > 0.f) ? 5 : 1;
    const float4* e4 = (const float4*)(emb + row * DIM + c * 8);
    float4 e0 = e4[0], e1 = e4[1];
    s8v o;
    o[0] = (short)f2u(e0.x); o[1] = (short)f2u(e0.y);
    o[2] = (short)f2u(e0.z); o[3] = (short)f2u(e0.w);
    o[4] = (short)f2u(e1.x); o[5] = (short)f2u(e1.y);
    o[6] = (short)f2u(e1.z); o[7] = (short)f2u(e1.w);
    size_t off = (size_t)t * DIM + c * 8;
    *(s8v*)((short*)x1 + off) = o;
    *(s8v*)((short*)x2 + off) = o;
}

// ---------------- LN stats (one wave per token row of 200) ----------------
__global__ __launch_bounds__(256) void lnstats_kernel(const bf16* __restrict__ in,
        float* __restrict__ mu_o, float* __restrict__ rstd_o) {
    int lane = threadIdx.x & 63;
    size_t t = (size_t)blockIdx.x * 4 + (threadIdx.x >> 6);
    const u16* row = (const u16*)in + t * DIM;
    float v0 = 0.f, v1 = 0.f, v2 = 0.f, v3 = 0.f;
    if (lane < 50) {
        ushort4 u4 = ((const ushort4*)row)[lane];
        v0 = bfu(u4.x); v1 = bfu(u4.y); v2 = bfu(u4.z); v3 = bfu(u4.w);
    }
    float s = v0 + v1 + v2 + v3, qq = v0*v0 + v1*v1 + v2*v2 + v3*v3;
    #pragma unroll
    for (int o = 32; o > 0; o >>= 1) { s += __shfl_xor(s, o); qq += __shfl_xor(qq, o); }
    if (lane == 0) {
        float mu = s * (1.f / DIM);
        mu_o[t] = mu;
        rstd_o[t] = rsqrtf(qq * (1.f / DIM) - mu * mu + 1e-5f);
    }
}

__global__ __launch_bounds__(256) void finalln_kernel(const bf16* __restrict__ in1,
        const bf16* __restrict__ in2, const float* __restrict__ g,
        const float* __restrict__ b, bf16* __restrict__ out) {
    int lane = threadIdx.x & 63;
    size_t t = (size_t)blockIdx.x * 4 + (threadIdx.x >> 6);
    const u16* r1 = (const u16*)in1 + t * DIM;
    const u16* r2 = (const u16*)in2 + t * DIM;
    float v0 = 0.f, v1 = 0.f, v2 = 0.f, v3 = 0.f;
    if (lane < 50) {
        ushort4 a4 = ((const ushort4*)r1)[lane];
        ushort4 b4 = ((const ushort4*)r2)[lane];
        v0 = 0.5f * (bfu(a4.x) + bfu(b4.x));
        v1 = 0.5f * (bfu(a4.y) + bfu(b4.y));
        v2 = 0.5f * (bfu(a4.z) + bfu(b4.z));
        v3 = 0.5f * (bfu(a4.w) + bfu(b4.w));
    }
    float s = v0 + v1 + v2 + v3, qq = v0*v0 + v1*v1 + v2*v2 + v3*v3;
    #pragma unroll
    for (int o = 32; o > 0; o >>= 1) { s += __shfl_xor(s, o); qq += __shfl_xor(qq, o); }
    float mu = s * (1.f / DIM);
    float rstd = rsqrtf(qq * (1.f / DIM) - mu * mu + 1e-5f);
    if (lane < 50) {
        float4 g4 = ((const float4*)g)[lane];
        float4 b4f = ((const float4*)b)[lane];
        ushort4 o4;
        o4.x = f2u((v0 - mu) * rstd * g4.x + b4f.x);
        o4.y = f2u((v1 - mu) * rstd * g4.y + b4f.y);
        o4.z = f2u((v2 - mu) * rstd * g4.z + b4f.z);
        o4.w = f2u((v3 - mu) * rstd * g4.w + b4f.w);
        ((ushort4*)((u16*)out + t * DIM))[lane] = o4;
    }
}

// ---------------- MFMA GEMM: C = epi(A @ Bt^T) + LN-epilogue ----------------
// global_load_lds staging, both-sides XOR swizzle (r9 structure, proven).
template<int EPI, int LNE, int KV>
__global__ __launch_bounds__(256) void gemm_m(
        const bf16* __restrict__ A, const bf16* __restrict__ Bt,
        const float* __restrict__ wv_, const float* __restrict__ uv_,
        const float* __restrict__ mu, const float* __restrict__ rstd,
        bf16* __restrict__ C, bf16* __restrict__ C2,
        int M, int N, int K, int Kpad) {
    __shared__ __align__(16) short As[128 * 32];
    __shared__ __align__(16) short Bs[128 * 32];
    int bm = blockIdx.x * 128, bn = blockIdx.y * 128;
    int t = threadIdx.x, l = t & 63, w = t >> 6;
    int wr = (w >> 1) * 64, wc = (w & 1) * 64;
    int lr = l & 15, lk16 = l >> 4;
    f4v acc[4][4];
    #pragma unroll
    for (int i = 0; i < 4; ++i)
        #pragma unroll
        for (int j = 0; j < 4; ++j) acc[i][j] = (f4v){0.f, 0.f, 0.f, 0.f};

    const short* Ash = (const short*)A;
    const short* Bsh = (const short*)Bt;
    int srow0 = 32 * w + (l >> 2);
    int c16 = l & 3;
    for (int k0 = 0; k0 < Kpad; k0 += 32) {
        __syncthreads();
        #pragma unroll
        for (int j = 0; j < 2; ++j) {
            int row = srow0 + 16 * j;
            int xc = (c16 ^ ((row >> 1) & 3)) * 8;
            gld_lds16(Ash + (size_t)(bm + row) * K + k0 + xc,
                      &As[(32 * w + 16 * j) * 32]);
            gld_lds16(Bsh + (size_t)(bn + row) * Kpad + k0 + xc,
                      &Bs[(32 * w + 16 * j) * 32]);
        }
        __syncthreads();
        s8v a[4], b[4];
        #pragma unroll
        for (int fi = 0; fi < 4; ++fi) {
            int R = wr + fi * 16 + lr;
            a[fi] = *(const s8v*)&As[R * 32 + ((lk16 ^ ((R >> 1) & 3)) * 8)];
        }
        #pragma unroll
        for (int fj = 0; fj < 4; ++fj) {
            int R = wc + fj * 16 + lr;
            b[fj] = *(const s8v*)&Bs[R * 32 + ((lk16 ^ ((R >> 1) & 3)) * 8)];
        }
        #pragma unroll
        for (int fi = 0; fi < 4; ++fi)
            #pragma unroll
            for (int fj = 0; fj < 4; ++fj)
                acc[fi][fj] = MFMA16(a[fi], b[fj], acc[fi][fj]);
    }
    int r0 = (l >> 4) * 4;
    #pragma unroll
    for (int fi = 0; fi < 4; ++fi) {
        int rowb = bm + wr + fi * 16 + r0;
        float sr[4] = {1.f, 1.f, 1.f, 1.f}, tr[4] = {0.f, 0.f, 0.f, 0.f};
        if (LNE) {
            #pragma unroll
            for (int r = 0; r < 4; ++r) {
                sr[r] = rstd[rowb + r];
                tr[r] = mu[rowb + r] * sr[r];
            }
        }
        #pragma unroll
        for (int fj = 0; fj < 4; ++fj) {
            int col = bn + wc + fj * 16 + lr;
            if (KV) {
                int cc = col & 255;
                if (cc < DIM) {
                    bf16* dst = (col < 256) ? C : C2;
                    float ww = wv_[col], uu = uv_[col];
                    #pragma unroll
                    for (int r = 0; r < 4; ++r) {
                        size_t idx = (size_t)(rowb + r) * DIM + cc;
                        float v = sr[r] * acc[fi][fj][r] - tr[r] * uu + ww;
                        dst[idx] = f2b(v);
                    }
                }
            } else if (col < N) {
                float ww = wv_[col];
                float uu = LNE ? uv_[col] : 0.f;
                #pragma unroll
                for (int r = 0; r < 4; ++r) {
                    size_t idx = (size_t)(rowb + r) * N + col;
                    float v = LNE ? (sr[r] * acc[fi][fj][r] - tr[r] * uu + ww)
                                  : (acc[fi][fj][r] + ww);
                    if (EPI == 1) v += b2f(C[idx]);
                    if (EPI == 2) v = gelu_f(v);
                    C[idx] = f2b(v);
                }
            }
        }
    }
}

// ---------------- fused FF: x2 += gelu(LN(x1)@W1+b1) @ W2 + b2 --------------
// BM=64. x1 tile staged to LDS once, then per-thread A-fragments (2 rows x
// 7 k-chunks = 14 s8v) hoisted to REGISTERS; the 32KB Ax LDS is then reused
// (union) for Bs+hS -> LDS/block 33.3KB -> 3 blocks/CU. Phase-1 dbuf, hS
// swizzle, fused next-layer LN1 stats as in r14.
struct SmemFF {
    union {
        short Ax[64 * 256];                              // 32KB staging
        struct { short Bs[2 * 128 * 32]; short hS[64 * HSROW]; } p;  // 33.3KB
    };
};
__global__ __launch_bounds__(256, 3) void ff_fused(
        const bf16* __restrict__ x1, const bf16* __restrict__ pF1,
        const bf16* __restrict__ pF2, const float* __restrict__ u1,
        const float* __restrict__ w1f, const float* __restrict__ fb2,
        const float* __restrict__ mu_in, const float* __restrict__ rstd_in,
        float* __restrict__ mu_out, float* __restrict__ rstd_out,
        bf16* __restrict__ x2) {
    __shared__ __align__(16) SmemFF sm;
    int bm = blockIdx.x * 64;
    int t = threadIdx.x, l = t & 63, w = t >> 6;
    int wrA = (w >> 1) * 32;          // rows (both phases)
    int wcA = (w & 1) * 64;           // phase-1 hidden cols
    int wcB = (w & 1) * 128;          // phase-2 output cols
    int lr = l & 15, lk16 = l >> 4;
    int r0 = (l >> 4) * 4;
    const short* X1 = (const short*)x1;
    const short* F1 = (const short*)pF1;
    const short* F2 = (const short*)pF2;

    // ---- stage x1 tile once, hoist per-thread fragments to registers ----
    {
        int c = l & 31, rsub = l >> 5;
        #pragma unroll
        for (int j = 0; j < 8; ++j) {
            int row0 = w * 16 + j * 2;
            int row = row0 + rsub;
            gld_lds16(X1 + (size_t)(bm + row) * DIM + ((c ^ (row & 7)) * 8),
                      &sm.Ax[row0 * 256]);
        }
    }
    __syncthreads();
    s8v areg[7][2];
    #pragma unroll
    for (int kt = 0; kt < 7; ++kt) {
        int cg = kt * 4 + lk16;
        #pragma unroll
        for (int fi = 0; fi < 2; ++fi) {
            int R = wrA + fi * 16 + lr;
            areg[kt][fi] = *(const s8v*)&sm.Ax[R * 256 + ((cg ^ (R & 7)) * 8)];
        }
    }
    __syncthreads();   // Ax reads done; union region free for Bs/hS

    f4v acc2[2][8];
    #pragma unroll
    for (int i = 0; i < 2; ++i)
        #pragma unroll
        for (int j = 0; j < 8; ++j) acc2[i][j] = (f4v){0.f, 0.f, 0.f, 0.f};

    int srow0 = 32 * w + (l >> 2);
    int c16 = l & 3;
    #pragma unroll 1
    for (int hc = 0; hc < 7; ++hc) {
        // prologue: stage kt=0 into half 0 (prev phase-2 reads drained by
        // the barrier ending the previous hc iteration / areg barrier)
        #pragma unroll
        for (int j = 0; j < 2; ++j) {
            int row = srow0 + 16 * j;
            int xc = (c16 ^ ((row >> 1) & 3)) * 8;
            gld_lds16(F1 + (size_t)(hc * 128 + row) * KPAD + 0 + xc,
                      &sm.p.Bs[(32 * w + 16 * j) * 32]);
        }
        __syncthreads();   // F1 kt0 ready
        // ---- phase 1: h_chunk[64][128], dbuf, 1 barrier per kt ----
        f4v acc1[2][4];
        #pragma unroll
        for (int i = 0; i < 2; ++i)
            #pragma unroll
            for (int j = 0; j < 4; ++j) acc1[i][j] = (f4v){0.f, 0.f, 0.f, 0.f};
        #pragma unroll 1
        for (int kt = 0; kt < 7; ++kt) {
            if (kt < 6) {  // issue next k-tile into other half (no barrier)
                int k0n = (kt + 1) * 32;
                int hb = ((kt + 1) & 1) * 4096;
                #pragma unroll
                for (int j = 0; j < 2; ++j) {
                    int row = srow0 + 16 * j;
                    int xc = (c16 ^ ((row >> 1) & 3)) * 8;
                    gld_lds16(F1 + (size_t)(hc * 128 + row) * KPAD + k0n + xc,
                              &sm.p.Bs[hb + (32 * w + 16 * j) * 32]);
                }
            }
            int hb = (kt & 1) * 4096;
            s8v b[4];
            #pragma unroll
            for (int fj = 0; fj < 4; ++fj) {
                int R = wcA + fj * 16 + lr;
                b[fj] = *(const s8v*)&sm.p.Bs[hb + R * 32 + ((lk16 ^ ((R >> 1) & 3)) * 8)];
            }
            #pragma unroll
            for (int fi = 0; fi < 2; ++fi)
                #pragma unroll
                for (int fj = 0; fj < 4; ++fj)
                    acc1[fi][fj] = MFMA16(areg[kt][fi], b[fj], acc1[fi][fj]);
            __syncthreads();   // next half ready (vmcnt drained) + reads done
        }
        // h epilogue -> hS (stride HSROW, chunk ^ row&7 swizzle)
        #pragma unroll
        for (int fi = 0; fi < 2; ++fi) {
            int rowL = wrA + fi * 16 + r0;
            f4v rs = *(const f4v*)&rstd_in[bm + rowL];
            f4v mm = *(const f4v*)&mu_in[bm + rowL];
            #pragma unroll
            for (int fj = 0; fj < 4; ++fj) {
                int col = wcA + fj * 16 + lr;
                int gcol = hc * 128 + col;
                float uu = u1[gcol], ww = w1f[gcol];
                #pragma unroll
                for (int r = 0; r < 4; ++r) {
                    float v = rs[r] * acc1[fi][fj][r] - mm[r] * rs[r] * uu + ww;
                    v = gelu_f(v);
                    int rr = rowL + r;
                    sm.p.hS[rr * HSROW + (((col >> 3) ^ (rr & 7)) * 8) + (col & 7)]
                        = (short)f2u(v);
                }
            }
        }
        // ---- phase 2: acc2 += h_chunk @ W2chunk (K=128) ----
        #pragma unroll 1
        for (int ks = 0; ks < 4; ++ks) {
            __syncthreads();   // hS visible (ks=0) / prev Bs reads done
            #pragma unroll
            for (int j = 0; j < 4; ++j) {
                int row = (w * 4 + j) * 16 + (l >> 2);
                int xc = (c16 ^ ((row >> 1) & 3)) * 8;
                gld_lds16(F2 + (size_t)row * 800 + hc * 128 + ks * 32 + xc,
                          &sm.p.Bs[(w * 4 + j) * 16 * 32]);
            }
            __syncthreads();
            s8v a[2];
            int cg = ks * 4 + lk16;
            #pragma unroll
            for (int fi = 0; fi < 2; ++fi) {
                int R = wrA + fi * 16 + lr;
                a[fi] = *(const s8v*)&sm.p.hS[R * HSROW + ((cg ^ (R & 7)) * 8)];
            }
            #pragma unroll
            for (int fj = 0; fj < 8; ++fj) {
                int Br = wcB + fj * 16 + lr;
                s8v bfr = *(const s8v*)&sm.p.Bs[Br * 32 + ((lk16 ^ ((Br >> 1) & 3)) * 8)];
                #pragma unroll
                for (int fi = 0; fi < 2; ++fi)
                    acc2[fi][fj] = MFMA16(a[fi], bfr, acc2[fi][fj]);
            }
        }
        __syncthreads();   // phase-2 Bs/hS reads done before next hc staging
    }
    // ---- final epilogue: x2 += acc2 + b2, plus next-layer LN1 stats ----
    float* sp = (float*)sm.p.hS;     // [64][2(half)][2(sum,sq)]
    float rsum[2][4], rsq[2][4];
    #pragma unroll
    for (int fi = 0; fi < 2; ++fi)
        #pragma unroll
        for (int r = 0; r < 4; ++r) { rsum[fi][r] = 0.f; rsq[fi][r] = 0.f; }
    #pragma unroll
    for (int fi = 0; fi < 2; ++fi) {
        int rowb = bm + wrA + fi * 16 + r0;
        #pragma unroll
        for (int fj = 0; fj < 8; ++fj) {
            int col = wcB + fj * 16 + lr;
            if (col < DIM) {
                float bb = fb2[col];
                #pragma unroll
                for (int r = 0; r < 4; ++r) {
                    size_t idx = (size_t)(rowb + r) * DIM + col;
                    float v = acc2[fi][fj][r] + bb + b2f(x2[idx]);
                    x2[idx] = f2b(v);
                    rsum[fi][r] += v;
                    rsq[fi][r] += v * v;
                }
            }
        }
    }
    // lane-reduce across the 16 lr lanes (cols), then cross-wave via LDS
    #pragma unroll
    for (int fi = 0; fi < 2; ++fi)
        #pragma unroll
        for (int r = 0; r < 4; ++r) {
            float s = rsum[fi][r], q = rsq[fi][r];
            #pragma unroll
            for (int o = 8; o > 0; o >>= 1) {
                s += __shfl_xor(s, o);
                q += __shfl_xor(q, o);
            }
            rsum[fi][r] = s; rsq[fi][r] = q;
        }
    if (lr == 0) {
        #pragma unroll
        for (int fi = 0; fi < 2; ++fi)
            #pragma unroll
            for (int r = 0; r < 4; ++r) {
                int rowL = wrA + fi * 16 + r0 + r;
                sp[rowL * 4 + (w & 1) * 2 + 0] = rsum[fi][r];
                sp[rowL * 4 + (w & 1) * 2 + 1] = rsq[fi][r];
            }
    }
    __syncthreads();
    if (t < 64) {
        float s = sp[t * 4 + 0] + sp[t * 4 + 2];
        float q = sp[t * 4 + 1] + sp[t * 4 + 3];
        float mu = s * (1.f / DIM);
        mu_out[bm + t] = mu;
        rstd_out[bm + t] = rsqrtf(q * (1.f / DIM) - mu * mu + 1e-5f);
    }
}

// ---- MFMA kvctx with ONLINE per-(n,h) max (flash-style) --------------------
__global__ __launch_bounds__(256) void kvctx_mfma(const bf16* __restrict__ k,
        const bf16* __restrict__ v, const float* __restrict__ proj,
        float* __restrict__ ctxg) {
    __shared__ __align__(16) short ph[64 * KNROW];
    __shared__ __align__(16) short pl[64 * KNROW];
    __shared__ __align__(16) short knh[128 * KNROW];
    __shared__ __align__(16) short knl[128 * KNROW];
    __shared__ __align__(16) short vT[32 * VROW];
    __shared__ __align__(16) short kp[64 * KPROW];
    __shared__ __align__(16) float diag[128];
    __shared__ float wmax[4];
    int nh = blockIdx.x, n = nh / HEADS, h = nh % HEADS;
    int t = threadIdx.x, l = t & 63, w = t >> 6;
    int lr = l & 15, lk = (l >> 4) * 8, l4 = (l >> 4) * 4;
    for (int i = t; i < 64 * 32; i += 256) {
        int m = i >> 5, d = i & 31;
        float val = (m < NBF && d < DH) ? proj[m * DH + d] : 0.f;
        u16 hi = f2u(val);
        ph[m * KNROW + d] = (short)hi;
        pl[m * KNROW + d] = (short)f2u(val - bfu(hi));
    }
    for (int i = t; i < 128 * 12; i += 256) {
        int s = i / 12, d = 20 + i % 12;
        knh[s * KNROW + d] = 0; knl[s * KNROW + d] = 0;
    }
    for (int i = t; i < 12 * 128; i += 256) {
        int d = 20 + (i >> 7), s = i & 127;
        vT[d * VROW + s] = (short)((d == 20) ? f2u(1.0f) : 0);
    }
    s8v ones;
    #pragma unroll
    for (int i = 0; i < 8; ++i) ones[i] = (short)f2u(1.0f);
    float Mrun = -3.0e38f;
    f4v cd0 = {0.f,0.f,0.f,0.f}, cd1 = {0.f,0.f,0.f,0.f};
    f4v vs0 = {0.f,0.f,0.f,0.f}, vs1 = {0.f,0.f,0.f,0.f};
    for (int c = 0; c < 16; ++c) {
        int s0 = c * 128;
        __syncthreads();
        if (t < 128) {          // waves 0,1: stage kn hi/lo + diag
            int s = t;
            const u16* kr = (const u16*)k + ((size_t)(n * SEQ + s0 + s)) * DIM + h * DH;
            float dg = 0.f;
            #pragma unroll
            for (int q5 = 0; q5 < 5; ++q5) {
                ushort4 u4 = ((const ushort4*)kr)[q5];
                float f0 = bfu(u4.x) * SCALE, f1 = bfu(u4.y) * SCALE;
                float f2_ = bfu(u4.z) * SCALE, f3 = bfu(u4.w) * SCALE;
                dg += f0*f0 + f1*f1 + f2_*f2_ + f3*f3;
                u16 h0 = f2u(f0), h1 = f2u(f1), h2 = f2u(f2_), h3 = f2u(f3);
                s4v hv = {(short)h0, (short)h1, (short)h2, (short)h3};
                *(s4v*)&knh[s * KNROW + q5 * 4] = hv;
                s4v lv = {(short)f2u(f0 - bfu(h0)), (short)f2u(f1 - bfu(h1)),
                          (short)f2u(f2_ - bfu(h2)), (short)f2u(f3 - bfu(h3))};
                *(s4v*)&knl[s * KNROW + q5 * 4] = lv;
            }
            diag[s] = 0.5f * dg;
        } else {                // waves 2,3: stage vT (scatter to [d][s])
            int s = t - 128;
            const u16* vr = (const u16*)v + ((size_t)(n * SEQ + s0 + s)) * DIM + h * DH;
            #pragma unroll
            for (int q5 = 0; q5 < 5; ++q5) {
                ushort4 u4 = ((const ushort4*)vr)[q5];
                vT[(q5 * 4 + 0) * VROW + s] = (short)u4.x;
                vT[(q5 * 4 + 1) * VROW + s] = (short)u4.y;
                vT[(q5 * 4 + 2) * VROW + s] = (short)u4.z;
                vT[(q5 * 4 + 3) * VROW + s] = (short)u4.w;
            }
        }
        __syncthreads();
        s8v ah0 = *(const s8v*)&knh[(32 * w + lr) * KNROW + lk];
        s8v al0 = *(const s8v*)&knl[(32 * w + lr) * KNROW + lk];
        s8v ah1 = *(const s8v*)&knh[(32 * w + 16 + lr) * KNROW + lk];
        s8v al1 = *(const s8v*)&knl[(32 * w + 16 + lr) * KNROW + lk];
        f4v dg0 = *(const f4v*)&diag[32 * w + l4];
        f4v dg1 = *(const f4v*)&diag[32 * w + 16 + l4];
        f4v D0[4], D1[4];
        #pragma unroll
        for (int mt = 0; mt < 4; ++mt) {
            s8v bh = *(const s8v*)&ph[(mt * 16 + lr) * KNROW + lk];
            s8v bl = *(const s8v*)&pl[(mt * 16 + lr) * KNROW + lk];
            f4v d0 = {0.f, 0.f, 0.f, 0.f}, d1 = {0.f, 0.f, 0.f, 0.f};
            d0 = MFMA16(ah0, bh, d0); d0 = MFMA16(ah0, bl, d0); d0 = MFMA16(al0, bh, d0);
            d1 = MFMA16(ah1, bh, d1); d1 = MFMA16(ah1, bl, d1); d1 = MFMA16(al1, bh, d1);
            D0[mt] = d0; D1[mt] = d1;
        }
        float mm = -3.0e38f;
        #pragma unroll
        for (int mt = 0; mt < 4; ++mt) {
            int lim = (mt < 3) ? 16 : (NBF - 48);
            if (lr < lim) {
                #pragma unroll
                for (int r = 0; r < 4; ++r)
                    mm = fmaxf(mm, fmaxf(D0[mt][r], D1[mt][r]));
            }
        }
        #pragma unroll
        for (int o = 32; o > 0; o >>= 1) mm = fmaxf(mm, __shfl_xor(mm, o));
        if (l == 0) wmax[w] = mm;
        __syncthreads();
        float Mnew = fmaxf(fmaxf(wmax[0], wmax[1]), fmaxf(wmax[2], wmax[3]));
        Mnew = fmaxf(Mrun, Mnew);
        float scl = __expf(Mrun - Mnew);
        #pragma unroll
        for (int r = 0; r < 4; ++r) { cd0[r] *= scl; cd1[r] *= scl; }
        Mrun = Mnew;
        #pragma unroll
        for (int mt = 0; mt < 4; ++mt) {
            int m = mt * 16 + lr;
            bool valid = m < NBF;
            s4v o0, o1;
            #pragma unroll
            for (int r = 0; r < 4; ++r) {
                float kp0 = valid ? __expf(D0[mt][r] - dg0[r] - Mnew) : 0.f;
                float kp1 = valid ? __expf(D1[mt][r] - dg1[r] - Mnew) : 0.f;
                o0[r] = (short)f2u(kp0);
                o1[r] = (short)f2u(kp1);
            }
            *(s4v*)&kp[m * KPROW + 32 * w + l4] = o0;
            *(s4v*)&kp[m * KPROW + 32 * w + 16 + l4] = o1;
        }
        __syncthreads();
        #pragma unroll
        for (int ks = 0; ks < 4; ++ks) {
            s8v a  = *(const s8v*)&kp[(16 * w + lr) * KPROW + ks * 32 + lk];
            s8v b0 = *(const s8v*)&vT[lr * VROW + ks * 32 + lk];
            s8v b1 = *(const s8v*)&vT[(16 + lr) * VROW + ks * 32 + lk];
            cd0 = MFMA16(a, b0, cd0);
            cd1 = MFMA16(a, b1, cd1);
            vs0 = MFMA16(ones, b0, vs0);
            vs1 = MFMA16(ones, b1, vs1);
        }
    }
    float* cg = ctxg + (size_t)nh * CTXR * 64;
    int m0 = 16 * w + l4;
    f4v r0v, r1v;
    #pragma unroll
    for (int r = 0; r < 4; ++r) {
        r0v[r] = RATIO * (cd0[r] + KEPS * vs0[r]);
        r1v[r] = RATIO * (cd1[r] + KEPS * vs1[r]);
    }
    *(f4v*)&cg[lr * 64 + m0] = r0v;
    if (lr < 5) *(f4v*)&cg[(16 + lr) * 64 + m0] = r1v;
}

// ---- MFMA qattn: out = (qp @ ctx) * dinv (den via ksum column) -------------
__global__ __launch_bounds__(256) void qattn_mfma(const bf16* __restrict__ q,
        const float* __restrict__ proj, const float* __restrict__ ctxg,
        bf16* __restrict__ ao) {
    __shared__ __align__(16) short ph[64 * KNROW];
    __shared__ __align__(16) short pl[64 * KNROW];
    __shared__ __align__(16) short qnh[128 * KNROW];
    __shared__ __align__(16) short qnl[128 * KNROW];
    __shared__ __align__(16) short qp[128 * QPROW];
    __shared__ __align__(16) short cT[32 * QPROW];
    __shared__ __align__(16) float dgs[128];
    __shared__ __align__(16) float osf[128][22];
    int b = blockIdx.x;
    int nh = b >> 1, sc = b & 1;
    int n = nh / HEADS, h = nh % HEADS;
    int t = threadIdx.x, l = t & 63, w = t >> 6;
    int lr = l & 15, lk = (l >> 4) * 8, l4 = (l >> 4) * 4;
    for (int i = t; i < 64 * 32; i += 256) {
        int m = i >> 5, d = i & 31;
        float val = (m < NBF && d < DH) ? proj[m * DH + d] : 0.f;
        u16 hi = f2u(val);
        ph[m * KNROW + d] = (short)hi;
        pl[m * KNROW + d] = (short)f2u(val - bfu(hi));
    }
    for (int i = t; i < 128 * 12; i += 256) {
        int s = i / 12, d = 20 + i % 12;
        qnh[s * KNROW + d] = 0; qnl[s * KNROW + d] = 0;
    }
    for (int i = t; i < 32 * 64; i += 256) {
        int d = i >> 6, m = i & 63;
        float val = (d < CTXR) ? ctxg[(size_t)nh * CTXR * 64 + d * 64 + m] : 0.f;
        cT[d * QPROW + m] = (short)f2u(val);
    }
    for (int c = 0; c < 8; ++c) {
        int s0 = (sc * 8 + c) * 128;
        __syncthreads();
        if (t < 128) {
            int s = t;
            const u16* qr = (const u16*)q + ((size_t)(n * SEQ + s0 + s)) * DIM + h * DH;
            float dg = 0.f;
            #pragma unroll
            for (int q5 = 0; q5 < 5; ++q5) {
                ushort4 u4 = ((const ushort4*)qr)[q5];
                float f0 = bfu(u4.x) * SCALE, f1 = bfu(u4.y) * SCALE;
                float f2_ = bfu(u4.z) * SCALE, f3 = bfu(u4.w) * SCALE;
                dg += f0*f0 + f1*f1 + f2_*f2_ + f3*f3;
                u16 h0 = f2u(f0), h1 = f2u(f1), h2 = f2u(f2_), h3 = f2u(f3);
                s4v hv = {(short)h0, (short)h1, (short)h2, (short)h3};
                *(s4v*)&qnh[s * KNROW + q5 * 4] = hv;
                s4v lv = {(short)f2u(f0 - bfu(h0)), (short)f2u(f1 - bfu(h1)),
                          (short)f2u(f2_ - bfu(h2)), (short)f2u(f3 - bfu(h3))};
                *(s4v*)&qnl[s * KNROW + q5 * 4] = lv;
            }
            dgs[s] = 0.5f * dg;
        }
        __syncthreads();
        s8v ah0 = *(const s8v*)&qnh[(32 * w + lr) * KNROW + lk];
        s8v al0 = *(const s8v*)&qnl[(32 * w + lr) * KNROW + lk];
        s8v ah1 = *(const s8v*)&qnh[(32 * w + 16 + lr) * KNROW + lk];
        s8v al1 = *(const s8v*)&qnl[(32 * w + 16 + lr) * KNROW + lk];
        f4v D0[4], D1[4];
        #pragma unroll
        for (int mt = 0; mt < 4; ++mt) {
            s8v bh = *(const s8v*)&ph[(mt * 16 + lr) * KNROW + lk];
            s8v bl = *(const s8v*)&pl[(mt * 16 + lr) * KNROW + lk];
            f4v d0 = {0.f, 0.f, 0.f, 0.f}, d1 = {0.f, 0.f, 0.f, 0.f};
            d0 = MFMA16(ah0, bh, d0); d0 = MFMA16(ah0, bl, d0); d0 = MFMA16(al0, bh, d0);
            d1 = MFMA16(ah1, bh, d1); d1 = MFMA16(ah1, bl, d1); d1 = MFMA16(al1, bh, d1);
            D0[mt] = d0; D1[mt] = d1;
        }
        f4v dg0 = *(const f4v*)&dgs[32 * w + l4];
        f4v dg1 = *(const f4v*)&dgs[32 * w + 16 + l4];
        float mx0[4], mx1[4];
        #pragma unroll
        for (int r = 0; r < 4; ++r) {
            float v3 = (lr < NBF - 48) ? D0[3][r] : -3.4e38f;
            float mm = fmaxf(fmaxf(D0[0][r], D0[1][r]), fmaxf(D0[2][r], v3));
            mm = fmaxf(mm, __shfl_xor(mm, 1));
            mm = fmaxf(mm, __shfl_xor(mm, 2));
            mm = fmaxf(mm, __shfl_xor(mm, 4));
            mm = fmaxf(mm, __shfl_xor(mm, 8));
            mx0[r] = mm;
            float u3 = (lr < NBF - 48) ? D1[3][r] : -3.4e38f;
            float nn = fmaxf(fmaxf(D1[0][r], D1[1][r]), fmaxf(D1[2][r], u3));
            nn = fmaxf(nn, __shfl_xor(nn, 1));
            nn = fmaxf(nn, __shfl_xor(nn, 2));
            nn = fmaxf(nn, __shfl_xor(nn, 4));
            nn = fmaxf(nn, __shfl_xor(nn, 8));
            mx1[r] = nn;
        }
        #pragma unroll
        for (int mt = 0; mt < 4; ++mt) {
            int m = mt * 16 + lr;
            bool valid = m < NBF;
            #pragma unroll
            for (int r = 0; r < 4; ++r) {
                float p0 = valid ? RATIO * (__expf(D0[mt][r] - dg0[r] - mx0[r]) + KEPS) : 0.f;
                float p1 = valid ? RATIO * (__expf(D1[mt][r] - dg1[r] - mx1[r]) + KEPS) : 0.f;
                qp[(32 * w + l4 + r) * QPROW + m] = (short)f2u(p0);
                qp[(32 * w + 16 + l4 + r) * QPROW + m] = (short)f2u(p1);
            }
        }
        __syncthreads();
        f4v o00 = {0.f,0.f,0.f,0.f}, o01 = {0.f,0.f,0.f,0.f};
        f4v o10 = {0.f,0.f,0.f,0.f}, o11 = {0.f,0.f,0.f,0.f};
        #pragma unroll
        for (int ks = 0; ks < 2; ++ks) {
            s8v a0 = *(const s8v*)&qp[(32 * w + lr) * QPROW + ks * 32 + lk];
            s8v a1 = *(const s8v*)&qp[(32 * w + 16 + lr) * QPROW + ks * 32 + lk];
            s8v b0 = *(const s8v*)&cT[lr * QPROW + ks * 32 + lk];
            s8v b1 = *(const s8v*)&cT[(16 + lr) * QPROW + ks * 32 + lk];
            o00 = MFMA16(a0, b0, o00); o01 = MFMA16(a0, b1, o01);
            o10 = MFMA16(a1, b0, o10); o11 = MFMA16(a1, b1, o11);
        }
        #pragma unroll
        for (int r = 0; r < 4; ++r) {
            osf[32 * w + l4 + r][lr] = o00[r];
            osf[32 * w + 16 + l4 + r][lr] = o10[r];
            if (lr < 5) {
                osf[32 * w + l4 + r][16 + lr] = o01[r];
                osf[32 * w + 16 + l4 + r][16 + lr] = o11[r];
            }
        }
        __syncthreads();
        if (t < 128) osf[t][21] = 1.f / osf[t][20];
        __syncthreads();
        int tokb = n * SEQ + s0;
        for (int idx = t; idx < 128 * 10; idx += 256) {
            int row = idx / 10, seg = idx % 10;
            float di = osf[row][21];
            ushort2 o2;
            o2.x = f2u(osf[row][seg * 2] * di);
            o2.y = f2u(osf[row][seg * 2 + 1] * di);
            *(ushort2*)((u16*)ao + (size_t)(tokb + row) * DIM + h * DH + seg * 2) = o2;
        }
    }
}

// ---------------- pooling ----------------
__global__ __launch_bounds__(256) void pool1_kernel(const bf16* __restrict__ hn,
        float* __restrict__ partial) {
    int n = blockIdx.x / 16, c = blockIdx.x % 16;
    int d = threadIdx.x;
    if (d >= DIM) return;
    float acc = 0.f;
    const bf16* base = hn + ((size_t)n * SEQ + c * 128) * DIM + d;
    for (int s = 0; s < 128; ++s) acc += b2f(base[(size_t)s * DIM]);
    partial[(size_t)blockIdx.x * DIM + d] = acc;
}

__global__ __launch_bounds__(256) void pool2_kernel(const float* __restrict__ partial,
        float* __restrict__ pooled) {
    int n = blockIdx.x, d = threadIdx.x;
    if (d >= DIM) return;
    float acc = 0.f;
    for (int c = 0; c < 16; ++c) acc += partial[(size_t)(n * 16 + c) * DIM + d];
    pooled[n * DIM + d] = acc * (1.f / SEQ);
}

__global__ __launch_bounds__(512) void finalproj_kernel(const float* __restrict__ pooled,
        const float* __restrict__ pw, const float* __restrict__ pb,
        float* __restrict__ out) {
    __shared__ float ps[DIM];
    int n = blockIdx.x;
    for (int i = threadIdx.x; i < DIM; i += 512) ps[i] = pooled[n * DIM + i];
    __syncthreads();
    int j = threadIdx.x;
    float acc = pb[j];
    for (int d = 0; d < DIM; ++d) acc += ps[d] * pw[d * DMODEL + j];
    out[n * DMODEL + j] = acc;
}

// ---------------- host launch ----------------
extern "C" void kernel_launch(void* const* d_in, const int* in_sizes, int n_in,
                              void* d_out, int out_size, void* d_ws, size_t ws_size,
                              hipStream_t stream) {
    (void)in_sizes; (void)n_in; (void)out_size;
    const float* x    = (const float*)d_in[0];
    const float* emb  = (const float*)d_in[1];
    const float* ln1g = (const float*)d_in[2];
    const float* ln1b = (const float*)d_in[3];
    const float* wq   = (const float*)d_in[4];
    const float* bq   = (const float*)d_in[5];
    const float* wk   = (const float*)d_in[6];
    const float* bk   = (const float*)d_in[7];
    const float* wv   = (const float*)d_in[8];
    const float* bv   = (const float*)d_in[9];
    const float* proj = (const float*)d_in[10];
    const float* wo   = (const float*)d_in[11];
    const float* bo   = (const float*)d_in[12];
    const float* ln2g = (const float*)d_in[13];
    const float* ln2b = (const float*)d_in[14];
    const float* ffw1 = (const float*)d_in[15];
    const float* ffb1 = (const float*)d_in[16];
    const float* ffw2 = (const float*)d_in[17];
    const float* ffb2 = (const float*)d_in[18];
    const float* lnfg = (const float*)d_in[19];
    const float* lnfb = (const float*)d_in[20];
    const float* pw   = (const float*)d_in[21];
    const float* pb   = (const float*)d_in[22];
    float* out = (float*)d_out;

    const size_t A_ = (size_t)NTOK * DIM;
    bf16* x1 = (bf16*)d_ws;
    bf16* x2 = x1 + A_ + BUFPAD;
    bf16* b3 = x2 + A_ + BUFPAD;     // k -> q
    bf16* b4 = b3 + A_ + BUFPAD;     // v -> attn out
    bf16* pKV = b4 + A_ + BUFPAD;
    bf16* pQ  = pKV + PKV_E;
    bf16* pWO = pQ + PQ_E;
    bf16* pF1 = pWO + PWO_E;
    bf16* pF2 = pF1 + PF1_E;
    float* muB   = (float*)(pF2 + PF2_E);      // x2 / LN1 stats
    float* rstdB = muB + NTOK;
    float* muC   = rstdB + NTOK;               // x1 / LN2 stats
    float* rstdC = muC + NTOK;
    float* uw    = rstdC + NTOK;               // 3328 floats
    float* ctxg  = uw + 3328;                  // 640 * 21 * 64 floats
    float* wsend = ctxg + (size_t)NSEQ * HEADS * CTXR * 64;

    float* ukv = uw,        *wkv = uw + 512;
    float* uq  = uw + 1024, *wqf = uw + 1280;
    float* u1  = uw + 1536, *w1f = uw + 2432;

    size_t need = (char*)wsend - (char*)d_ws;
    if (ws_size < need) {
        sentinel_kernel<<<1, 64, 0, stream>>>(out, (float)(ws_size >> 20));
        return;
    }

    zeropad_kernel<<<1, 64, 0, stream>>>(x1 + A_, x2 + A_, b3 + A_, b4 + A_);
    embed_kernel<<<(NTOK * 25 + 255) / 256, 256, 0, stream>>>(x, emb, x1, x2);
    // prime LN1 stats for layer 0 (subsequent layers: computed inside ff_fused)
    lnstats_kernel<<<NTOK / 4, 256, 0, stream>>>(x2, muB, rstdB);

    dim3 gkv(NTOK / 128, 4);
    dim3 gd(NTOK / 128, 2);
    for (int l = 0; l < DEPTH; ++l) {
        const float* wq_l = wq + (size_t)l * DIM * DIM;
        const float* wk_l = wk + (size_t)l * DIM * DIM;
        const float* wv_l = wv + (size_t)l * DIM * DIM;
        const float* wo_l = wo + (size_t)l * DIM * DIM;
        const float* f1_l = ffw1 + (size_t)l * DIM * FFD;
        const float* f2_l = ffw2 + (size_t)l * FFD * DIM;
        const float* pj_l = proj + (size_t)l * NBF * DH;
        const float* g1 = ln1g + l * DIM, *b1 = ln1b + l * DIM;
        const float* g2 = ln2g + l * DIM, *b2 = ln2b + l * DIM;

        prep_layer<<<2487, 256, 0, stream>>>(wq_l, wk_l, wv_l, wo_l, f1_l, f2_l,
                g1, b1, g2, b2, bq + l * DIM, bk + l * DIM, bv + l * DIM,
                ffb1 + l * FFD, pKV, pQ, pWO, pF1, pF2, uw);

        // k -> b3, v -> b4 (fused)
        gemm_m<0, 1, 1><<<gkv, 256, 0, stream>>>(x2, pKV, wkv, ukv, muB, rstdB,
                b3, b4, NTOK, 512, DIM, KPAD);
        kvctx_mfma<<<NSEQ * HEADS, 256, 0, stream>>>(b3, b4, pj_l, ctxg);
        // q -> b3 (k dead)
        gemm_m<0, 1, 0><<<gd, 256, 0, stream>>>(x2, pQ, wqf, uq, muB, rstdB,
                b3, nullptr, NTOK, DIM, DIM, KPAD);
        // attn out -> b4 (v dead)
        qattn_mfma<<<NSEQ * HEADS * 2, 256, 0, stream>>>(b3, pj_l, ctxg, b4);
        // x1 += b4 @ wo + bo
        gemm_m<1, 0, 0><<<gd, 256, 0, stream>>>(b4, pWO, bo + l * DIM, nullptr,
                nullptr, nullptr, x1, nullptr, NTOK, DIM, DIM, KPAD);

        // fused FF (also writes next layer's LN1 stats into muB/rstdB)
        lnstats_kernel<<<NTOK / 4, 256, 0, stream>>>(x1, muC, rstdC);
        ff_fused<<<NTOK / 64, 256, 0, stream>>>(x1, pF1, pF2, u1, w1f,
                ffb2 + l * DIM, muC, rstdC, muB, rstdB, x2);
    }

    finalln_kernel<<<NTOK / 4, 256, 0, stream>>>(x1, x2, lnfg, lnfb, b3);
    float* partial = muB;
    float* pooled  = muB + (size_t)NSEQ * 16 * DIM;
    pool1_kernel<<<NSEQ * 16, 256, 0, stream>>>(b3, partial);
    pool2_kernel<<<NSEQ, 256, 0, stream>>>(partial, pooled);
    finalproj_kernel<<<NSEQ, 512, 0, stream>>>(pooled, pw, pb, out);
}

// Round 16
// 4327.318 us; speedup vs baseline: 1.3152x; 1.3152x over previous
//
#include <hip/hip_runtime.h>
#include <hip/hip_bf16.h>
#include <math.h>

#define DEPTH   6
#define DIM     200
#define HEADS   10
#define DH      20
#define NBF     59
#define FFD     800
#define DMODEL  512
#define NSEQ    64
#define SEQ     2048
#define NTOK    (NSEQ*SEQ)   // 131072
#define KPAD    224          // ceil(200/32)*32
#define BUFPAD  64
#define KNROW   40           // staged row stride (shorts) for kn/qn/proj
#define VROW    136          // vT row stride
#define KPROW   136          // kp row stride
#define QPROW   72           // qp / ctxT row stride
#define CTXR    21           // ctx rows stored (d=0..19 + ksum row 20)
#define HSROW   132          // ff hidden LDS row stride (66 dwords == 2 mod 32)
// panel element counts
#define PKV_E   (512*KPAD)
#define PQ_E    (256*KPAD)
#define PWO_E   (256*KPAD)
#define PF1_E   (896*KPAD)
#define PF2_E   (256*800)

typedef __hip_bfloat16 bf16;
typedef unsigned short u16;
typedef short s8v __attribute__((ext_vector_type(8)));
typedef short s4v __attribute__((ext_vector_type(4)));
typedef float f4v __attribute__((ext_vector_type(4)));

constexpr float SCALE = 0.4728708045015879f;   // 20^-0.25
constexpr float RATIO = 0.1301889109808239f;   // 59^-0.5
constexpr float KEPS  = 1e-4f;

__device__ __forceinline__ float b2f(bf16 v) { return __bfloat162float(v); }
__device__ __forceinline__ bf16 f2b(float v) { return __float2bfloat16(v); }
__device__ __forceinline__ float bfu(u16 u) {
    return __uint_as_float(((unsigned)u) << 16);
}
__device__ __forceinline__ u16 f2u(float v) {
    bf16 hb = __float2bfloat16(v);
    return *(u16*)&hb;
}
// tanh-form gelu: max |diff| vs exact-erf gelu ~5e-4, far below bf16 quantum
// of the hidden activations; overflow-safe (e->inf => factor->1).
__device__ __forceinline__ float gelu_f(float x) {
    float inner = 0.7978845608028654f * (x + 0.044715f * x * x * x);
    float e = __expf(2.f * inner);
    return x * (1.f - 1.f / (e + 1.f));
}
// async global -> LDS, 16B per lane; LDS dest = wave-uniform base + lane*16
__device__ __forceinline__ void gld_lds16(const short* g, short* l) {
    __builtin_amdgcn_global_load_lds(
        (const __attribute__((address_space(1))) void*)g,
        (__attribute__((address_space(3))) void*)l, 16, 0, 0);
}
#define MFMA16(a, b, c) __builtin_amdgcn_mfma_f32_16x16x32_bf16(a, b, c, 0, 0, 0)

// ---------------- sentinel: encodes ws_size(MB) into out[0] ----------------
__global__ void sentinel_kernel(float* out, float wsmb) {
    if (threadIdx.x == 0) out[0] = wsmb;
}

__global__ void zeropad_kernel(bf16* p1, bf16* p2, bf16* p3, bf16* p4) {
    int i = threadIdx.x;
    if (i < BUFPAD) {
        bf16 z = f2b(0.f);
        p1[i] = z; p2[i] = z; p3[i] = z; p4[i] = z;
    }
}

// ---- per-layer prep: all weight panels + LN-fold vectors, one launch ------
// uw layout (floats): [0..511]=ukv [512..1023]=wkv [1024..1279]=uq
// [1280..1535]=wq [1536..2431]=u1 [2432..3327]=w1
__global__ __launch_bounds__(256) void prep_layer(
        const float* __restrict__ wq, const float* __restrict__ wk,
        const float* __restrict__ wv, const float* __restrict__ wo,
        const float* __restrict__ f1, const float* __restrict__ f2,
        const float* __restrict__ g1, const float* __restrict__ b1,
        const float* __restrict__ g2, const float* __restrict__ b2,
        const float* __restrict__ bq, const float* __restrict__ bk,
        const float* __restrict__ bv, const float* __restrict__ f1b,
        bf16* __restrict__ pKV, bf16* __restrict__ pQ, bf16* __restrict__ pWO,
        bf16* __restrict__ pF1, bf16* __restrict__ pF2,
        float* __restrict__ uw) {
    int b = blockIdx.x, t = threadIdx.x;
    if (b < 448) {                      // pKV: rows 0..255 = k, 256..511 = v
        int idx = b * 256 + t;
        int row = idx / KPAD, k = idx % KPAD;
        float v = 0.f;
        if (k < DIM) {
            if (row < DIM) v = wk[(size_t)k * DIM + row] * g1[k];
            else if (row >= 256 && row < 256 + DIM)
                v = wv[(size_t)k * DIM + (row - 256)] * g1[k];
        }
        pKV[idx] = f2b(v);
    } else if (b < 672) {               // pQ
        int idx = (b - 448) * 256 + t;
        int row = idx / KPAD, k = idx % KPAD;
        float v = (row < DIM && k < DIM) ? wq[(size_t)k * DIM + row] * g1[k] : 0.f;
        pQ[idx] = f2b(v);
    } else if (b < 896) {               // pWO (no fold)
        int idx = (b - 672) * 256 + t;
        int row = idx / KPAD, k = idx % KPAD;
        float v = (row < DIM && k < DIM) ? wo[(size_t)k * DIM + row] : 0.f;
        pWO[idx] = f2b(v);
    } else if (b < 1680) {              // pF1 (g2-folded)
        int idx = (b - 896) * 256 + t;
        int row = idx / KPAD, k = idx % KPAD;
        float v = (row < FFD && k < DIM) ? f1[(size_t)k * FFD + row] * g2[k] : 0.f;
        pF1[idx] = f2b(v);
    } else if (b < 2480) {              // pF2 [256][800]
        int idx = (b - 1680) * 256 + t;
        int row = idx / 800, k = idx % 800;
        float v = (row < DIM) ? f2[(size_t)k * DIM + row] : 0.f;
        pF2[idx] = f2b(v);
    } else if (b < 2482) {              // u/w for fused KV
        int j = b - 2480;
        const float* W    = j ? wv : wk;
        const float* bias = j ? bv : bk;
        int n = t;
        float su = 0.f, sw = 0.f;
        if (n < DIM) {
            for (int k = 0; k < DIM; ++k) {
                float wvv = W[(size_t)k * DIM + n];
                su += g1[k] * wvv;
                sw += b1[k] * wvv;
            }
            sw += bias[n];
        }
        uw[j * 256 + n] = su;
        uw[512 + j * 256 + n] = sw;
    } else if (b == 2482) {             // u/w for Q
        int n = t;
        float su = 0.f, sw = 0.f;
        if (n < DIM) {
            for (int k = 0; k < DIM; ++k) {
                float wvv = wq[(size_t)k * DIM + n];
                su += g1[k] * wvv;
                sw += b1[k] * wvv;
            }
            sw += bq[n];
        }
        uw[1024 + n] = su;
        uw[1280 + n] = sw;
    } else {                            // u/w for FF1 (896 outputs)
        int n = (b - 2483) * 256 + t;
        if (n < 896) {
            float su = 0.f, sw = 0.f;
            if (n < FFD) {
                for (int k = 0; k < DIM; ++k) {
                    float wvv = f1[(size_t)k * FFD + n];
                    su += g2[k] * wvv;
                    sw += b2[k] * wvv;
                }
                sw += f1b[n];
            }
            uw[1536 + n] = su;
            uw[2432 + n] = sw;
        }
    }
}

// ---------------- embedding: tokens are 1 (x<=0) or 5 (x>0) ----------------
__global__ __launch_bounds__(256) void embed_kernel(const float* __restrict__ x,
        const float* __restrict__ emb, bf16* __restrict__ x1, bf16* __restrict__ x2) {
    int idx = blockIdx.x * 256 + threadIdx.x;      // NTOK*25
    if (idx >= NTOK * 25) return;
    int t = idx / 25, c = idx % 25;
    int row = (x[t] > 0.f) ? 5 : 1;
    const float4* e4 = (const float4*)(emb + row * DIM + c * 8);
    float4 e0 = e4[0], e1 = e4[1];
    s8v o;
    o[0] = (short)f2u(e0.x); o[1] = (short)f2u(e0.y);
    o[2] = (short)f2u(e0.z); o[3] = (short)f2u(e0.w);
    o[4] = (short)f2u(e1.x); o[5] = (short)f2u(e1.y);
    o[6] = (short)f2u(e1.z); o[7] = (short)f2u(e1.w);
    size_t off = (size_t)t * DIM + c * 8;
    *(s8v*)((short*)x1 + off) = o;
    *(s8v*)((short*)x2 + off) = o;
}

// ---------------- LN stats (one wave per token row of 200) ----------------
__global__ __launch_bounds__(256) void lnstats_kernel(const bf16* __restrict__ in,
        float* __restrict__ mu_o, float* __restrict__ rstd_o) {
    int lane = threadIdx.x & 63;
    size_t t = (size_t)blockIdx.x * 4 + (threadIdx.x >> 6);
    const u16* row = (const u16*)in + t * DIM;
    float v0 = 0.f, v1 = 0.f, v2 = 0.f, v3 = 0.f;
    if (lane < 50) {
        ushort4 u4 = ((const ushort4*)row)[lane];
        v0 = bfu(u4.x); v1 = bfu(u4.y); v2 = bfu(u4.z); v3 = bfu(u4.w);
    }
    float s = v0 + v1 + v2 + v3, qq = v0*v0 + v1*v1 + v2*v2 + v3*v3;
    #pragma unroll
    for (int o = 32; o > 0; o >>= 1) { s += __shfl_xor(s, o); qq += __shfl_xor(qq, o); }
    if (lane == 0) {
        float mu = s * (1.f / DIM);
        mu_o[t] = mu;
        rstd_o[t] = rsqrtf(qq * (1.f / DIM) - mu * mu + 1e-5f);
    }
}

__global__ __launch_bounds__(256) void finalln_kernel(const bf16* __restrict__ in1,
        const bf16* __restrict__ in2, const float* __restrict__ g,
        const float* __restrict__ b, bf16* __restrict__ out) {
    int lane = threadIdx.x & 63;
    size_t t = (size_t)blockIdx.x * 4 + (threadIdx.x >> 6);
    const u16* r1 = (const u16*)in1 + t * DIM;
    const u16* r2 = (const u16*)in2 + t * DIM;
    float v0 = 0.f, v1 = 0.f, v2 = 0.f, v3 = 0.f;
    if (lane < 50) {
        ushort4 a4 = ((const ushort4*)r1)[lane];
        ushort4 b4 = ((const ushort4*)r2)[lane];
        v0 = 0.5f * (bfu(a4.x) + bfu(b4.x));
        v1 = 0.5f * (bfu(a4.y) + bfu(b4.y));
        v2 = 0.5f * (bfu(a4.z) + bfu(b4.z));
        v3 = 0.5f * (bfu(a4.w) + bfu(b4.w));
    }
    float s = v0 + v1 + v2 + v3, qq = v0*v0 + v1*v1 + v2*v2 + v3*v3;
    #pragma unroll
    for (int o = 32; o > 0; o >>= 1) { s += __shfl_xor(s, o); qq += __shfl_xor(qq, o); }
    float mu = s * (1.f / DIM);
    float rstd = rsqrtf(qq * (1.f / DIM) - mu * mu + 1e-5f);
    if (lane < 50) {
        float4 g4 = ((const float4*)g)[lane];
        float4 b4f = ((const float4*)b)[lane];
        ushort4 o4;
        o4.x = f2u((v0 - mu) * rstd * g4.x + b4f.x);
        o4.y = f2u((v1 - mu) * rstd * g4.y + b4f.y);
        o4.z = f2u((v2 - mu) * rstd * g4.z + b4f.z);
        o4.w = f2u((v3 - mu) * rstd * g4.w + b4f.w);
        ((ushort4*)((u16*)out + t * DIM))[lane] = o4;
    }
}

// ---------------- MFMA GEMM: C = epi(A @ Bt^T) + LN-epilogue ----------------
// global_load_lds staging, both-sides XOR swizzle (r9 structure, proven).
template<int EPI, int LNE, int KV>
__global__ __launch_bounds__(256) void gemm_m(
        const bf16* __restrict__ A, const bf16* __restrict__ Bt,
        const float* __restrict__ wv_, const float* __restrict__ uv_,
        const float* __restrict__ mu, const float* __restrict__ rstd,
        bf16* __restrict__ C, bf16* __restrict__ C2,
        int M, int N, int K, int Kpad) {
    __shared__ __align__(16) short As[128 * 32];
    __shared__ __align__(16) short Bs[128 * 32];
    int bm = blockIdx.x * 128, bn = blockIdx.y * 128;
    int t = threadIdx.x, l = t & 63, w = t >> 6;
    int wr = (w >> 1) * 64, wc = (w & 1) * 64;
    int lr = l & 15, lk16 = l >> 4;
    f4v acc[4][4];
    #pragma unroll
    for (int i = 0; i < 4; ++i)
        #pragma unroll
        for (int j = 0; j < 4; ++j) acc[i][j] = (f4v){0.f, 0.f, 0.f, 0.f};

    const short* Ash = (const short*)A;
    const short* Bsh = (const short*)Bt;
    int srow0 = 32 * w + (l >> 2);
    int c16 = l & 3;
    for (int k0 = 0; k0 < Kpad; k0 += 32) {
        __syncthreads();
        #pragma unroll
        for (int j = 0; j < 2; ++j) {
            int row = srow0 + 16 * j;
            int xc = (c16 ^ ((row >> 1) & 3)) * 8;
            gld_lds16(Ash + (size_t)(bm + row) * K + k0 + xc,
                      &As[(32 * w + 16 * j) * 32]);
            gld_lds16(Bsh + (size_t)(bn + row) * Kpad + k0 + xc,
                      &Bs[(32 * w + 16 * j) * 32]);
        }
        __syncthreads();
        s8v a[4], b[4];
        #pragma unroll
        for (int fi = 0; fi < 4; ++fi) {
            int R = wr + fi * 16 + lr;
            a[fi] = *(const s8v*)&As[R * 32 + ((lk16 ^ ((R >> 1) & 3)) * 8)];
        }
        #pragma unroll
        for (int fj = 0; fj < 4; ++fj) {
            int R = wc + fj * 16 + lr;
            b[fj] = *(const s8v*)&Bs[R * 32 + ((lk16 ^ ((R >> 1) & 3)) * 8)];
        }
        #pragma unroll
        for (int fi = 0; fi < 4; ++fi)
            #pragma unroll
            for (int fj = 0; fj < 4; ++fj)
                acc[fi][fj] = MFMA16(a[fi], b[fj], acc[fi][fj]);
    }
    int r0 = (l >> 4) * 4;
    #pragma unroll
    for (int fi = 0; fi < 4; ++fi) {
        int rowb = bm + wr + fi * 16 + r0;
        float sr[4] = {1.f, 1.f, 1.f, 1.f}, tr[4] = {0.f, 0.f, 0.f, 0.f};
        if (LNE) {
            #pragma unroll
            for (int r = 0; r < 4; ++r) {
                sr[r] = rstd[rowb + r];
                tr[r] = mu[rowb + r] * sr[r];
            }
        }
        #pragma unroll
        for (int fj = 0; fj < 4; ++fj) {
            int col = bn + wc + fj * 16 + lr;
            if (KV) {
                int cc = col & 255;
                if (cc < DIM) {
                    bf16* dst = (col < 256) ? C : C2;
                    float ww = wv_[col], uu = uv_[col];
                    #pragma unroll
                    for (int r = 0; r < 4; ++r) {
                        size_t idx = (size_t)(rowb + r) * DIM + cc;
                        float v = sr[r] * acc[fi][fj][r] - tr[r] * uu + ww;
                        dst[idx] = f2b(v);
                    }
                }
            } else if (col < N) {
                float ww = wv_[col];
                float uu = LNE ? uv_[col] : 0.f;
                #pragma unroll
                for (int r = 0; r < 4; ++r) {
                    size_t idx = (size_t)(rowb + r) * N + col;
                    float v = LNE ? (sr[r] * acc[fi][fj][r] - tr[r] * uu + ww)
                                  : (acc[fi][fj][r] + ww);
                    if (EPI == 1) v += b2f(C[idx]);
                    if (EPI == 2) v = gelu_f(v);
                    C[idx] = f2b(v);
                }
            }
        }
    }
}

// ---------------- fused FF: x2 += gelu(LN(x1)@W1+b1) @ W2 + b2 --------------
// r14 proven version: BM=64, 2 blocks/CU, dbuf phase-1, hS swizzle, fused
// next-layer LN1 stats. (r15's reg-hoisted variant spilled; reverted.)
__global__ __launch_bounds__(256, 2) void ff_fused(
        const bf16* __restrict__ x1, const bf16* __restrict__ pF1,
        const bf16* __restrict__ pF2, const float* __restrict__ u1,
        const float* __restrict__ w1f, const float* __restrict__ fb2,
        const float* __restrict__ mu_in, const float* __restrict__ rstd_in,
        float* __restrict__ mu_out, float* __restrict__ rstd_out,
        bf16* __restrict__ x2) {
    __shared__ __align__(16) short Ax[64 * 256];    // 32KB
    __shared__ __align__(16) short Bs[2 * 128 * 32]; // 16KB (2 halves / full)
    __shared__ __align__(16) short hS[64 * HSROW];  // 16.5KB (stats overlay)
    int bm = blockIdx.x * 64;
    int t = threadIdx.x, l = t & 63, w = t >> 6;
    int wrA = (w >> 1) * 32;          // rows (both phases)
    int wcA = (w & 1) * 64;           // phase-1 hidden cols
    int wcB = (w & 1) * 128;          // phase-2 output cols
    int lr = l & 15, lk16 = l >> 4;
    int r0 = (l >> 4) * 4;
    const short* X1 = (const short*)x1;
    const short* F1 = (const short*)pF1;
    const short* F2 = (const short*)pF2;

    // ---- stage x1 tile once ----
    {
        int c = l & 31, rsub = l >> 5;
        #pragma unroll
        for (int j = 0; j < 8; ++j) {
            int row0 = w * 16 + j * 2;
            int row = row0 + rsub;
            gld_lds16(X1 + (size_t)(bm + row) * DIM + ((c ^ (row & 7)) * 8),
                      &Ax[row0 * 256]);
        }
    }

    f4v acc2[2][8];
    #pragma unroll
    for (int i = 0; i < 2; ++i)
        #pragma unroll
        for (int j = 0; j < 8; ++j) acc2[i][j] = (f4v){0.f, 0.f, 0.f, 0.f};

    int srow0 = 32 * w + (l >> 2);
    int c16 = l & 3;
    #pragma unroll 1
    for (int hc = 0; hc < 7; ++hc) {
        __syncthreads();   // prev phase-2 Bs reads done; (hc=0: drains nothing)
        // prologue: stage kt=0 into half 0
        #pragma unroll
        for (int j = 0; j < 2; ++j) {
            int row = srow0 + 16 * j;
            int xc = (c16 ^ ((row >> 1) & 3)) * 8;
            gld_lds16(F1 + (size_t)(hc * 128 + row) * KPAD + 0 + xc,
                      &Bs[(32 * w + 16 * j) * 32]);
        }
        __syncthreads();   // drains Ax (hc=0) + F1 kt0
        // ---- phase 1: h_chunk[64][128], dbuf, 1 barrier per kt ----
        f4v acc1[2][4];
        #pragma unroll
        for (int i = 0; i < 2; ++i)
            #pragma unroll
            for (int j = 0; j < 4; ++j) acc1[i][j] = (f4v){0.f, 0.f, 0.f, 0.f};
        #pragma unroll 1
        for (int kt = 0; kt < 7; ++kt) {
            if (kt < 6) {  // issue next k-tile into other half (no barrier)
                int k0n = (kt + 1) * 32;
                int hb = ((kt + 1) & 1) * 4096;
                #pragma unroll
                for (int j = 0; j < 2; ++j) {
                    int row = srow0 + 16 * j;
                    int xc = (c16 ^ ((row >> 1) & 3)) * 8;
                    gld_lds16(F1 + (size_t)(hc * 128 + row) * KPAD + k0n + xc,
                              &Bs[hb + (32 * w + 16 * j) * 32]);
                }
            }
            int hb = (kt & 1) * 4096;
            s8v a[2], b[4];
            int cg = kt * 4 + lk16;     // logical k-chunk 0..27
            #pragma unroll
            for (int fi = 0; fi < 2; ++fi) {
                int R = wrA + fi * 16 + lr;
                a[fi] = *(const s8v*)&Ax[R * 256 + ((cg ^ (R & 7)) * 8)];
            }
            #pragma unroll
            for (int fj = 0; fj < 4; ++fj) {
                int R = wcA + fj * 16 + lr;
                b[fj] = *(const s8v*)&Bs[hb + R * 32 + ((lk16 ^ ((R >> 1) & 3)) * 8)];
            }
            #pragma unroll
            for (int fi = 0; fi < 2; ++fi)
                #pragma unroll
                for (int fj = 0; fj < 4; ++fj)
                    acc1[fi][fj] = MFMA16(a[fi], b[fj], acc1[fi][fj]);
            __syncthreads();   // next half ready (vmcnt drained) + reads done
        }
        // h epilogue -> hS (stride HSROW, chunk ^ row&7 swizzle)
        #pragma unroll
        for (int fi = 0; fi < 2; ++fi) {
            int rowL = wrA + fi * 16 + r0;
            f4v rs = *(const f4v*)&rstd_in[bm + rowL];
            f4v mm = *(const f4v*)&mu_in[bm + rowL];
            #pragma unroll
            for (int fj = 0; fj < 4; ++fj) {
                int col = wcA + fj * 16 + lr;
                int gcol = hc * 128 + col;
                float uu = u1[gcol], ww = w1f[gcol];
                #pragma unroll
                for (int r = 0; r < 4; ++r) {
                    float v = rs[r] * acc1[fi][fj][r] - mm[r] * rs[r] * uu + ww;
                    v = gelu_f(v);
                    int rr = rowL + r;
                    hS[rr * HSROW + (((col >> 3) ^ (rr & 7)) * 8) + (col & 7)]
                        = (short)f2u(v);
                }
            }
        }
        // ---- phase 2: acc2 += h_chunk @ W2chunk (K=128) ----
        #pragma unroll 1
        for (int ks = 0; ks < 4; ++ks) {
            __syncthreads();   // hS visible (ks=0) / prev Bs reads done
            #pragma unroll
            for (int j = 0; j < 4; ++j) {
                int row = (w * 4 + j) * 16 + (l >> 2);
                int xc = (c16 ^ ((row >> 1) & 3)) * 8;
                gld_lds16(F2 + (size_t)row * 800 + hc * 128 + ks * 32 + xc,
                          &Bs[(w * 4 + j) * 16 * 32]);
            }
            __syncthreads();
            s8v a[2];
            int cg = ks * 4 + lk16;
            #pragma unroll
            for (int fi = 0; fi < 2; ++fi) {
                int R = wrA + fi * 16 + lr;
                a[fi] = *(const s8v*)&hS[R * HSROW + ((cg ^ (R & 7)) * 8)];
            }
            #pragma unroll
            for (int fj = 0; fj < 8; ++fj) {
                int Br = wcB + fj * 16 + lr;
                s8v bfr = *(const s8v*)&Bs[Br * 32 + ((lk16 ^ ((Br >> 1) & 3)) * 8)];
                #pragma unroll
                for (int fi = 0; fi < 2; ++fi)
                    acc2[fi][fj] = MFMA16(a[fi], bfr, acc2[fi][fj]);
            }
        }
    }
    // ---- final epilogue: x2 += acc2 + b2, plus next-layer LN1 stats ----
    __syncthreads();                 // all hS reads done; overlay stats on hS
    float* sp = (float*)hS;          // [64][2(half)][2(sum,sq)]
    float rsum[2][4], rsq[2][4];
    #pragma unroll
    for (int fi = 0; fi < 2; ++fi)
        #pragma unroll
        for (int r = 0; r < 4; ++r) { rsum[fi][r] = 0.f; rsq[fi][r] = 0.f; }
    #pragma unroll
    for (int fi = 0; fi < 2; ++fi) {
        int rowb = bm + wrA + fi * 16 + r0;
        #pragma unroll
        for (int fj = 0; fj < 8; ++fj) {
            int col = wcB + fj * 16 + lr;
            if (col < DIM) {
                float bb = fb2[col];
                #pragma unroll
                for (int r = 0; r < 4; ++r) {
                    size_t idx = (size_t)(rowb + r) * DIM + col;
                    float v = acc2[fi][fj][r] + bb + b2f(x2[idx]);
                    x2[idx] = f2b(v);
                    rsum[fi][r] += v;
                    rsq[fi][r] += v * v;
                }
            }
        }
    }
    // lane-reduce across the 16 lr lanes (cols), then cross-wave via LDS
    #pragma unroll
    for (int fi = 0; fi < 2; ++fi)
        #pragma unroll
        for (int r = 0; r < 4; ++r) {
            float s = rsum[fi][r], q = rsq[fi][r];
            #pragma unroll
            for (int o = 8; o > 0; o >>= 1) {
                s += __shfl_xor(s, o);
                q += __shfl_xor(q, o);
            }
            rsum[fi][r] = s; rsq[fi][r] = q;
        }
    if (lr == 0) {
        #pragma unroll
        for (int fi = 0; fi < 2; ++fi)
            #pragma unroll
            for (int r = 0; r < 4; ++r) {
                int rowL = wrA + fi * 16 + r0 + r;
                sp[rowL * 4 + (w & 1) * 2 + 0] = rsum[fi][r];
                sp[rowL * 4 + (w & 1) * 2 + 1] = rsq[fi][r];
            }
    }
    __syncthreads();
    if (t < 64) {
        float s = sp[t * 4 + 0] + sp[t * 4 + 2];
        float q = sp[t * 4 + 1] + sp[t * 4 + 3];
        float mu = s * (1.f / DIM);
        mu_out[bm + t] = mu;
        rstd_out[bm + t] = rsqrtf(q * (1.f / DIM) - mu * mu + 1e-5f);
    }
}

// ---- MFMA kvctx with ONLINE per-(n,h) max (flash-style) --------------------
__global__ __launch_bounds__(256) void kvctx_mfma(const bf16* __restrict__ k,
        const bf16* __restrict__ v, const float* __restrict__ proj,
        float* __restrict__ ctxg) {
    __shared__ __align__(16) short ph[64 * KNROW];
    __shared__ __align__(16) short pl[64 * KNROW];
    __shared__ __align__(16) short knh[128 * KNROW];
    __shared__ __align__(16) short knl[128 * KNROW];
    __shared__ __align__(16) short vT[32 * VROW];
    __shared__ __align__(16) short kp[64 * KPROW];
    __shared__ __align__(16) float diag[128];
    __shared__ float wmax[4];
    int nh = blockIdx.x, n = nh / HEADS, h = nh % HEADS;
    int t = threadIdx.x, l = t & 63, w = t >> 6;
    int lr = l & 15, lk = (l >> 4) * 8, l4 = (l >> 4) * 4;
    for (int i = t; i < 64 * 32; i += 256) {
        int m = i >> 5, d = i & 31;
        float val = (m < NBF && d < DH) ? proj[m * DH + d] : 0.f;
        u16 hi = f2u(val);
        ph[m * KNROW + d] = (short)hi;
        pl[m * KNROW + d] = (short)f2u(val - bfu(hi));
    }
    for (int i = t; i < 128 * 12; i += 256) {
        int s = i / 12, d = 20 + i % 12;
        knh[s * KNROW + d] = 0; knl[s * KNROW + d] = 0;
    }
    for (int i = t; i < 12 * 128; i += 256) {
        int d = 20 + (i >> 7), s = i & 127;
        vT[d * VROW + s] = (short)((d == 20) ? f2u(1.0f) : 0);
    }
    s8v ones;
    #pragma unroll
    for (int i = 0; i < 8; ++i) ones[i] = (short)f2u(1.0f);
    float Mrun = -3.0e38f;
    f4v cd0 = {0.f,0.f,0.f,0.f}, cd1 = {0.f,0.f,0.f,0.f};
    f4v vs0 = {0.f,0.f,0.f,0.f}, vs1 = {0.f,0.f,0.f,0.f};
    for (int c = 0; c < 16; ++c) {
        int s0 = c * 128;
        __syncthreads();
        if (t < 128) {          // waves 0,1: stage kn hi/lo + diag
            int s = t;
            const u16* kr = (const u16*)k + ((size_t)(n * SEQ + s0 + s)) * DIM + h * DH;
            float dg = 0.f;
            #pragma unroll
            for (int q5 = 0; q5 < 5; ++q5) {
                ushort4 u4 = ((const ushort4*)kr)[q5];
                float f0 = bfu(u4.x) * SCALE, f1 = bfu(u4.y) * SCALE;
                float f2_ = bfu(u4.z) * SCALE, f3 = bfu(u4.w) * SCALE;
                dg += f0*f0 + f1*f1 + f2_*f2_ + f3*f3;
                u16 h0 = f2u(f0), h1 = f2u(f1), h2 = f2u(f2_), h3 = f2u(f3);
                s4v hv = {(short)h0, (short)h1, (short)h2, (short)h3};
                *(s4v*)&knh[s * KNROW + q5 * 4] = hv;
                s4v lv = {(short)f2u(f0 - bfu(h0)), (short)f2u(f1 - bfu(h1)),
                          (short)f2u(f2_ - bfu(h2)), (short)f2u(f3 - bfu(h3))};
                *(s4v*)&knl[s * KNROW + q5 * 4] = lv;
            }
            diag[s] = 0.5f * dg;
        } else {                // waves 2,3: stage vT (scatter to [d][s])
            int s = t - 128;
            const u16* vr = (const u16*)v + ((size_t)(n * SEQ + s0 + s)) * DIM + h * DH;
            #pragma unroll
            for (int q5 = 0; q5 < 5; ++q5) {
                ushort4 u4 = ((const ushort4*)vr)[q5];
                vT[(q5 * 4 + 0) * VROW + s] = (short)u4.x;
                vT[(q5 * 4 + 1) * VROW + s] = (short)u4.y;
                vT[(q5 * 4 + 2) * VROW + s] = (short)u4.z;
                vT[(q5 * 4 + 3) * VROW + s] = (short)u4.w;
            }
        }
        __syncthreads();
        s8v ah0 = *(const s8v*)&knh[(32 * w + lr) * KNROW + lk];
        s8v al0 = *(const s8v*)&knl[(32 * w + lr) * KNROW + lk];
        s8v ah1 = *(const s8v*)&knh[(32 * w + 16 + lr) * KNROW + lk];
        s8v al1 = *(const s8v*)&knl[(32 * w + 16 + lr) * KNROW + lk];
        f4v dg0 = *(const f4v*)&diag[32 * w + l4];
        f4v dg1 = *(const f4v*)&diag[32 * w + 16 + l4];
        f4v D0[4], D1[4];
        #pragma unroll
        for (int mt = 0; mt < 4; ++mt) {
            s8v bh = *(const s8v*)&ph[(mt * 16 + lr) * KNROW + lk];
            s8v bl = *(const s8v*)&pl[(mt * 16 + lr) * KNROW + lk];
            f4v d0 = {0.f, 0.f, 0.f, 0.f}, d1 = {0.f, 0.f, 0.f, 0.f};
            d0 = MFMA16(ah0, bh, d0); d0 = MFMA16(ah0, bl, d0); d0 = MFMA16(al0, bh, d0);
            d1 = MFMA16(ah1, bh, d1); d1 = MFMA16(ah1, bl, d1); d1 = MFMA16(al1, bh, d1);
            D0[mt] = d0; D1[mt] = d1;
        }
        float mm = -3.0e38f;
        #pragma unroll
        for (int mt = 0; mt < 4; ++mt) {
            int lim = (mt < 3) ? 16 : (NBF - 48);
            if (lr < lim) {
                #pragma unroll
                for (int r = 0; r < 4; ++r)
                    mm = fmaxf(mm, fmaxf(D0[mt][r], D1[mt][r]));
            }
        }
        #pragma unroll
        for (int o = 32; o > 0; o >>= 1) mm = fmaxf(mm, __shfl_xor(mm, o));
        if (l == 0) wmax[w] = mm;
        __syncthreads();
        float Mnew = fmaxf(fmaxf(wmax[0], wmax[1]), fmaxf(wmax[2], wmax[3]));
        Mnew = fmaxf(Mrun, Mnew);
        float scl = __expf(Mrun - Mnew);
        #pragma unroll
        for (int r = 0; r < 4; ++r) { cd0[r] *= scl; cd1[r] *= scl; }
        Mrun = Mnew;
        #pragma unroll
        for (int mt = 0; mt < 4; ++mt) {
            int m = mt * 16 + lr;
            bool valid = m < NBF;
            s4v o0, o1;
            #pragma unroll
            for (int r = 0; r < 4; ++r) {
                float kp0 = valid ? __expf(D0[mt][r] - dg0[r] - Mnew) : 0.f;
                float kp1 = valid ? __expf(D1[mt][r] - dg1[r] - Mnew) : 0.f;
                o0[r] = (short)f2u(kp0);
                o1[r] = (short)f2u(kp1);
            }
            *(s4v*)&kp[m * KPROW + 32 * w + l4] = o0;
            *(s4v*)&kp[m * KPROW + 32 * w + 16 + l4] = o1;
        }
        __syncthreads();
        #pragma unroll
        for (int ks = 0; ks < 4; ++ks) {
            s8v a  = *(const s8v*)&kp[(16 * w + lr) * KPROW + ks * 32 + lk];
            s8v b0 = *(const s8v*)&vT[lr * VROW + ks * 32 + lk];
            s8v b1 = *(const s8v*)&vT[(16 + lr) * VROW + ks * 32 + lk];
            cd0 = MFMA16(a, b0, cd0);
            cd1 = MFMA16(a, b1, cd1);
            vs0 = MFMA16(ones, b0, vs0);
            vs1 = MFMA16(ones, b1, vs1);
        }
    }
    float* cg = ctxg + (size_t)nh * CTXR * 64;
    int m0 = 16 * w + l4;
    f4v r0v, r1v;
    #pragma unroll
    for (int r = 0; r < 4; ++r) {
        r0v[r] = RATIO * (cd0[r] + KEPS * vs0[r]);
        r1v[r] = RATIO * (cd1[r] + KEPS * vs1[r]);
    }
    *(f4v*)&cg[lr * 64 + m0] = r0v;
    if (lr < 5) *(f4v*)&cg[(16 + lr) * 64 + m0] = r1v;
}

// ---- MFMA qattn: out = (qp @ ctx) * dinv (den via ksum column) -------------
// split factor 4: each block handles 4 seq-chunks of 128 (grid = nh*4)
__global__ __launch_bounds__(256) void qattn_mfma(const bf16* __restrict__ q,
        const float* __restrict__ proj, const float* __restrict__ ctxg,
        bf16* __restrict__ ao) {
    __shared__ __align__(16) short ph[64 * KNROW];
    __shared__ __align__(16) short pl[64 * KNROW];
    __shared__ __align__(16) short qnh[128 * KNROW];
    __shared__ __align__(16) short qnl[128 * KNROW];
    __shared__ __align__(16) short qp[128 * QPROW];
    __shared__ __align__(16) short cT[32 * QPROW];
    __shared__ __align__(16) float dgs[128];
    __shared__ __align__(16) float osf[128][22];
    int b = blockIdx.x;
    int nh = b >> 2, sc = b & 3;
    int n = nh / HEADS, h = nh % HEADS;
    int t = threadIdx.x, l = t & 63, w = t >> 6;
    int lr = l & 15, lk = (l >> 4) * 8, l4 = (l >> 4) * 4;
    for (int i = t; i < 64 * 32; i += 256) {
        int m = i >> 5, d = i & 31;
        float val = (m < NBF && d < DH) ? proj[m * DH + d] : 0.f;
        u16 hi = f2u(val);
        ph[m * KNROW + d] = (short)hi;
        pl[m * KNROW + d] = (short)f2u(val - bfu(hi));
    }
    for (int i = t; i < 128 * 12; i += 256) {
        int s = i / 12, d = 20 + i % 12;
        qnh[s * KNROW + d] = 0; qnl[s * KNROW + d] = 0;
    }
    for (int i = t; i < 32 * 64; i += 256) {
        int d = i >> 6, m = i & 63;
        float val = (d < CTXR) ? ctxg[(size_t)nh * CTXR * 64 + d * 64 + m] : 0.f;
        cT[d * QPROW + m] = (short)f2u(val);
    }
    for (int c = 0; c < 4; ++c) {
        int s0 = (sc * 4 + c) * 128;
        __syncthreads();
        if (t < 128) {
            int s = t;
            const u16* qr = (const u16*)q + ((size_t)(n * SEQ + s0 + s)) * DIM + h * DH;
            float dg = 0.f;
            #pragma unroll
            for (int q5 = 0; q5 < 5; ++q5) {
                ushort4 u4 = ((const ushort4*)qr)[q5];
                float f0 = bfu(u4.x) * SCALE, f1 = bfu(u4.y) * SCALE;
                float f2_ = bfu(u4.z) * SCALE, f3 = bfu(u4.w) * SCALE;
                dg += f0*f0 + f1*f1 + f2_*f2_ + f3*f3;
                u16 h0 = f2u(f0), h1 = f2u(f1), h2 = f2u(f2_), h3 = f2u(f3);
                s4v hv = {(short)h0, (short)h1, (short)h2, (short)h3};
                *(s4v*)&qnh[s * KNROW + q5 * 4] = hv;
                s4v lv = {(short)f2u(f0 - bfu(h0)), (short)f2u(f1 - bfu(h1)),
                          (short)f2u(f2_ - bfu(h2)), (short)f2u(f3 - bfu(h3))};
                *(s4v*)&qnl[s * KNROW + q5 * 4] = lv;
            }
            dgs[s] = 0.5f * dg;
        }
        __syncthreads();
        s8v ah0 = *(const s8v*)&qnh[(32 * w + lr) * KNROW + lk];
        s8v al0 = *(const s8v*)&qnl[(32 * w + lr) * KNROW + lk];
        s8v ah1 = *(const s8v*)&qnh[(32 * w + 16 + lr) * KNROW + lk];
        s8v al1 = *(const s8v*)&qnl[(32 * w + 16 + lr) * KNROW + lk];
        f4v D0[4], D1[4];
        #pragma unroll
        for (int mt = 0; mt < 4; ++mt) {
            s8v bh = *(const s8v*)&ph[(mt * 16 + lr) * KNROW + lk];
            s8v bl = *(const s8v*)&pl[(mt * 16 + lr) * KNROW + lk];
            f4v d0 = {0.f, 0.f, 0.f, 0.f}, d1 = {0.f, 0.f, 0.f, 0.f};
            d0 = MFMA16(ah0, bh, d0); d0 = MFMA16(ah0, bl, d0); d0 = MFMA16(al0, bh, d0);
            d1 = MFMA16(ah1, bh, d1); d1 = MFMA16(ah1, bl, d1); d1 = MFMA16(al1, bh, d1);
            D0[mt] = d0; D1[mt] = d1;
        }
        f4v dg0 = *(const f4v*)&dgs[32 * w + l4];
        f4v dg1 = *(const f4v*)&dgs[32 * w + 16 + l4];
        float mx0[4], mx1[4];
        #pragma unroll
        for (int r = 0; r < 4; ++r) {
            float v3 = (lr < NBF - 48) ? D0[3][r] : -3.4e38f;
            float mm = fmaxf(fmaxf(D0[0][r], D0[1][r]), fmaxf(D0[2][r], v3));
            mm = fmaxf(mm, __shfl_xor(mm, 1));
            mm = fmaxf(mm, __shfl_xor(mm, 2));
            mm = fmaxf(mm, __shfl_xor(mm, 4));
            mm = fmaxf(mm, __shfl_xor(mm, 8));
            mx0[r] = mm;
            float u3 = (lr < NBF - 48) ? D1[3][r] : -3.4e38f;
            float nn = fmaxf(fmaxf(D1[0][r], D1[1][r]), fmaxf(D1[2][r], u3));
            nn = fmaxf(nn, __shfl_xor(nn, 1));
            nn = fmaxf(nn, __shfl_xor(nn, 2));
            nn = fmaxf(nn, __shfl_xor(nn, 4));
            nn = fmaxf(nn, __shfl_xor(nn, 8));
            mx1[r] = nn;
        }
        #pragma unroll
        for (int mt = 0; mt < 4; ++mt) {
            int m = mt * 16 + lr;
            bool valid = m < NBF;
            #pragma unroll
            for (int r = 0; r < 4; ++r) {
                float p0 = valid ? RATIO * (__expf(D0[mt][r] - dg0[r] - mx0[r]) + KEPS) : 0.f;
                float p1 = valid ? RATIO * (__expf(D1[mt][r] - dg1[r] - mx1[r]) + KEPS) : 0.f;
                qp[(32 * w + l4 + r) * QPROW + m] = (short)f2u(p0);
                qp[(32 * w + 16 + l4 + r) * QPROW + m] = (short)f2u(p1);
            }
        }
        __syncthreads();
        f4v o00 = {0.f,0.f,0.f,0.f}, o01 = {0.f,0.f,0.f,0.f};
        f4v o10 = {0.f,0.f,0.f,0.f}, o11 = {0.f,0.f,0.f,0.f};
        #pragma unroll
        for (int ks = 0; ks < 2; ++ks) {
            s8v a0 = *(const s8v*)&qp[(32 * w + lr) * QPROW + ks * 32 + lk];
            s8v a1 = *(const s8v*)&qp[(32 * w + 16 + lr) * QPROW + ks * 32 + lk];
            s8v b0 = *(const s8v*)&cT[lr * QPROW + ks * 32 + lk];
            s8v b1 = *(const s8v*)&cT[(16 + lr) * QPROW + ks * 32 + lk];
            o00 = MFMA16(a0, b0, o00); o01 = MFMA16(a0, b1, o01);
            o10 = MFMA16(a1, b0, o10); o11 = MFMA16(a1, b1, o11);
        }
        #pragma unroll
        for (int r = 0; r < 4; ++r) {
            osf[32 * w + l4 + r][lr] = o00[r];
            osf[32 * w + 16 + l4 + r][lr] = o10[r];
            if (lr < 5) {
                osf[32 * w + l4 + r][16 + lr] = o01[r];
                osf[32 * w + 16 + l4 + r][16 + lr] = o11[r];
            }
        }
        __syncthreads();
        if (t < 128) osf[t][21] = 1.f / osf[t][20];
        __syncthreads();
        int tokb = n * SEQ + s0;
        for (int idx = t; idx < 128 * 10; idx += 256) {
            int row = idx / 10, seg = idx % 10;
            float di = osf[row][21];
            ushort2 o2;
            o2.x = f2u(osf[row][seg * 2] * di);
            o2.y = f2u(osf[row][seg * 2 + 1] * di);
            *(ushort2*)((u16*)ao + (size_t)(tokb + row) * DIM + h * DH + seg * 2) = o2;
        }
    }
}

// ---------------- pooling ----------------
__global__ __launch_bounds__(256) void pool1_kernel(const bf16* __restrict__ hn,
        float* __restrict__ partial) {
    int n = blockIdx.x / 16, c = blockIdx.x % 16;
    int d = threadIdx.x;
    if (d >= DIM) return;
    float acc = 0.f;
    const bf16* base = hn + ((size_t)n * SEQ + c * 128) * DIM + d;
    for (int s = 0; s < 128; ++s) acc += b2f(base[(size_t)s * DIM]);
    partial[(size_t)blockIdx.x * DIM + d] = acc;
}

__global__ __launch_bounds__(256) void pool2_kernel(const float* __restrict__ partial,
        float* __restrict__ pooled) {
    int n = blockIdx.x, d = threadIdx.x;
    if (d >= DIM) return;
    float acc = 0.f;
    for (int c = 0; c < 16; ++c) acc += partial[(size_t)(n * 16 + c) * DIM + d];
    pooled[n * DIM + d] = acc * (1.f / SEQ);
}

__global__ __launch_bounds__(512) void finalproj_kernel(const float* __restrict__ pooled,
        const float* __restrict__ pw, const float* __restrict__ pb,
        float* __restrict__ out) {
    __shared__ float ps[DIM];
    int n = blockIdx.x;
    for (int i = threadIdx.x; i < DIM; i += 512) ps[i] = pooled[n * DIM + i];
    __syncthreads();
    int j = threadIdx.x;
    float acc = pb[j];
    for (int d = 0; d < DIM; ++d) acc += ps[d] * pw[d * DMODEL + j];
    out[n * DMODEL + j] = acc;
}

// ---------------- host launch ----------------
extern "C" void kernel_launch(void* const* d_in, const int* in_sizes, int n_in,
                              void* d_out, int out_size, void* d_ws, size_t ws_size,
                              hipStream_t stream) {
    (void)in_sizes; (void)n_in; (void)out_size;
    const float* x    = (const float*)d_in[0];
    const float* emb  = (const float*)d_in[1];
    const float* ln1g = (const float*)d_in[2];
    const float* ln1b = (const float*)d_in[3];
    const float* wq   = (const float*)d_in[4];
    const float* bq   = (const float*)d_in[5];
    const float* wk   = (const float*)d_in[6];
    const float* bk   = (const float*)d_in[7];
    const float* wv   = (const float*)d_in[8];
    const float* bv   = (const float*)d_in[9];
    const float* proj = (const float*)d_in[10];
    const float* wo   = (const float*)d_in[11];
    const float* bo   = (const float*)d_in[12];
    const float* ln2g = (const float*)d_in[13];
    const float* ln2b = (const float*)d_in[14];
    const float* ffw1 = (const float*)d_in[15];
    const float* ffb1 = (const float*)d_in[16];
    const float* ffw2 = (const float*)d_in[17];
    const float* ffb2 = (const float*)d_in[18];
    const float* lnfg = (const float*)d_in[19];
    const float* lnfb = (const float*)d_in[20];
    const float* pw   = (const float*)d_in[21];
    const float* pb   = (const float*)d_in[22];
    float* out = (float*)d_out;

    const size_t A_ = (size_t)NTOK * DIM;
    bf16* x1 = (bf16*)d_ws;
    bf16* x2 = x1 + A_ + BUFPAD;
    bf16* b3 = x2 + A_ + BUFPAD;     // k -> q
    bf16* b4 = b3 + A_ + BUFPAD;     // v -> attn out
    bf16* pKV = b4 + A_ + BUFPAD;
    bf16* pQ  = pKV + PKV_E;
    bf16* pWO = pQ + PQ_E;
    bf16* pF1 = pWO + PWO_E;
    bf16* pF2 = pF1 + PF1_E;
    float* muB   = (float*)(pF2 + PF2_E);      // x2 / LN1 stats
    float* rstdB = muB + NTOK;
    float* muC   = rstdB + NTOK;               // x1 / LN2 stats
    float* rstdC = muC + NTOK;
    float* uw    = rstdC + NTOK;               // 3328 floats
    float* ctxg  = uw + 3328;                  // 640 * 21 * 64 floats
    float* wsend = ctxg + (size_t)NSEQ * HEADS * CTXR * 64;

    float* ukv = uw,        *wkv = uw + 512;
    float* uq  = uw + 1024, *wqf = uw + 1280;
    float* u1  = uw + 1536, *w1f = uw + 2432;

    size_t need = (char*)wsend - (char*)d_ws;
    if (ws_size < need) {
        sentinel_kernel<<<1, 64, 0, stream>>>(out, (float)(ws_size >> 20));
        return;
    }

    zeropad_kernel<<<1, 64, 0, stream>>>(x1 + A_, x2 + A_, b3 + A_, b4 + A_);
    embed_kernel<<<(NTOK * 25 + 255) / 256, 256, 0, stream>>>(x, emb, x1, x2);
    // prime LN1 stats for layer 0 (subsequent layers: computed inside ff_fused)
    lnstats_kernel<<<NTOK / 4, 256, 0, stream>>>(x2, muB, rstdB);

    dim3 gkv(NTOK / 128, 4);
    dim3 gd(NTOK / 128, 2);
    for (int l = 0; l < DEPTH; ++l) {
        const float* wq_l = wq + (size_t)l * DIM * DIM;
        const float* wk_l = wk + (size_t)l * DIM * DIM;
        const float* wv_l = wv + (size_t)l * DIM * DIM;
        const float* wo_l = wo + (size_t)l * DIM * DIM;
        const float* f1_l = ffw1 + (size_t)l * DIM * FFD;
        const float* f2_l = ffw2 + (size_t)l * FFD * DIM;
        const float* pj_l = proj + (size_t)l * NBF * DH;
        const float* g1 = ln1g + l * DIM, *b1 = ln1b + l * DIM;
        const float* g2 = ln2g + l * DIM, *b2 = ln2b + l * DIM;

        prep_layer<<<2487, 256, 0, stream>>>(wq_l, wk_l, wv_l, wo_l, f1_l, f2_l,
                g1, b1, g2, b2, bq + l * DIM, bk + l * DIM, bv + l * DIM,
                ffb1 + l * FFD, pKV, pQ, pWO, pF1, pF2, uw);

        // k -> b3, v -> b4 (fused)
        gemm_m<0, 1, 1><<<gkv, 256, 0, stream>>>(x2, pKV, wkv, ukv, muB, rstdB,
                b3, b4, NTOK, 512, DIM, KPAD);
        kvctx_mfma<<<NSEQ * HEADS, 256, 0, stream>>>(b3, b4, pj_l, ctxg);
        // q -> b3 (k dead)
        gemm_m<0, 1, 0><<<gd, 256, 0, stream>>>(x2, pQ, wqf, uq, muB, rstdB,
                b3, nullptr, NTOK, DIM, DIM, KPAD);
        // attn out -> b4 (v dead)
        qattn_mfma<<<NSEQ * HEADS * 4, 256, 0, stream>>>(b3, pj_l, ctxg, b4);
        // x1 += b4 @ wo + bo
        gemm_m<1, 0, 0><<<gd, 256, 0, stream>>>(b4, pWO, bo + l * DIM, nullptr,
                nullptr, nullptr, x1, nullptr, NTOK, DIM, DIM, KPAD);

        // fused FF (also writes next layer's LN1 stats into muB/rstdB)
        lnstats_kernel<<<NTOK / 4, 256, 0, stream>>>(x1, muC, rstdC);
        ff_fused<<<NTOK / 64, 256, 0, stream>>>(x1, pF1, pF2, u1, w1f,
                ffb2 + l * DIM, muC, rstdC, muB, rstdB, x2);
    }

    finalln_kernel<<<NTOK / 4, 256, 0, stream>>>(x1, x2, lnfg, lnfb, b3);
    float* partial = muB;
    float* pooled  = muB + (size_t)NSEQ * 16 * DIM;
    pool1_kernel<<<NSEQ * 16, 256, 0, stream>>>(b3, partial);
    pool2_kernel<<<NSEQ, 256, 0, stream>>>(partial, pooled);
    finalproj_kernel<<<NSEQ, 512, 0, stream>>>(pooled, pw, pb, out);
}

// Round 17
// 4198.492 us; speedup vs baseline: 1.3556x; 1.0307x over previous
//
#include <hip/hip_runtime.h>
#include <hip/hip_bf16.h>
#include <math.h>

#define DEPTH   6
#define DIM     200
#define HEADS   10
#define DH      20
#define NBF     59
#define FFD     800
#define DMODEL  512
#define NSEQ    64
#define SEQ     2048
#define NTOK    (NSEQ*SEQ)   // 131072
#define KPAD    224          // ceil(200/32)*32
#define BUFPAD  64
#define KNROW   40           // staged row stride (shorts) for kn/qn/proj
#define VROW    136          // vT row stride
#define KPROW   136          // kp row stride
#define QPROW   72           // qp / ctxT row stride
#define CTXR    21           // ctx rows stored (d=0..19 + ksum row 20)
#define HSROW   132          // ff hidden LDS row stride (66 dwords == 2 mod 32)
#define HSTRIDE ((size_t)NTOK * DH)   // head-block stride in elements
// panel element counts
#define PKV_E   (512*KPAD)
#define PQ_E    (256*KPAD)
#define PWO_E   (256*KPAD)
#define PF1_E   (896*KPAD)
#define PF2_E   (256*800)

typedef __hip_bfloat16 bf16;
typedef unsigned short u16;
typedef short s8v __attribute__((ext_vector_type(8)));
typedef short s4v __attribute__((ext_vector_type(4)));
typedef float f4v __attribute__((ext_vector_type(4)));

constexpr float SCALE = 0.4728708045015879f;   // 20^-0.25
constexpr float RATIO = 0.1301889109808239f;   // 59^-0.5
constexpr float KEPS  = 1e-4f;

__device__ __forceinline__ float b2f(bf16 v) { return __bfloat162float(v); }
__device__ __forceinline__ bf16 f2b(float v) { return __float2bfloat16(v); }
__device__ __forceinline__ float bfu(u16 u) {
    return __uint_as_float(((unsigned)u) << 16);
}
__device__ __forceinline__ u16 f2u(float v) {
    bf16 hb = __float2bfloat16(v);
    return *(u16*)&hb;
}
// tanh-form gelu: max |diff| vs exact-erf gelu ~5e-4, far below bf16 quantum
__device__ __forceinline__ float gelu_f(float x) {
    float inner = 0.7978845608028654f * (x + 0.044715f * x * x * x);
    float e = __expf(2.f * inner);
    return x * (1.f - 1.f / (e + 1.f));
}
// async global -> LDS, 16B per lane; LDS dest = wave-uniform base + lane*16
__device__ __forceinline__ void gld_lds16(const short* g, short* l) {
    __builtin_amdgcn_global_load_lds(
        (const __attribute__((address_space(1))) void*)g,
        (__attribute__((address_space(3))) void*)l, 16, 0, 0);
}
#define MFMA16(a, b, c) __builtin_amdgcn_mfma_f32_16x16x32_bf16(a, b, c, 0, 0, 0)

// ---------------- sentinel: encodes ws_size(MB) into out[0] ----------------
__global__ void sentinel_kernel(float* out, float wsmb) {
    if (threadIdx.x == 0) out[0] = wsmb;
}

__global__ void zeropad_kernel(bf16* p1, bf16* p2, bf16* p3, bf16* p4) {
    int i = threadIdx.x;
    if (i < BUFPAD) {
        bf16 z = f2b(0.f);
        p1[i] = z; p2[i] = z; p3[i] = z; p4[i] = z;
    }
}

// ---- per-layer prep: all weight panels + LN-fold vectors, one launch ------
__global__ __launch_bounds__(256) void prep_layer(
        const float* __restrict__ wq, const float* __restrict__ wk,
        const float* __restrict__ wv, const float* __restrict__ wo,
        const float* __restrict__ f1, const float* __restrict__ f2,
        const float* __restrict__ g1, const float* __restrict__ b1,
        const float* __restrict__ g2, const float* __restrict__ b2,
        const float* __restrict__ bq, const float* __restrict__ bk,
        const float* __restrict__ bv, const float* __restrict__ f1b,
        bf16* __restrict__ pKV, bf16* __restrict__ pQ, bf16* __restrict__ pWO,
        bf16* __restrict__ pF1, bf16* __restrict__ pF2,
        float* __restrict__ uw) {
    int b = blockIdx.x, t = threadIdx.x;
    if (b < 448) {                      // pKV: rows 0..255 = k, 256..511 = v
        int idx = b * 256 + t;
        int row = idx / KPAD, k = idx % KPAD;
        float v = 0.f;
        if (k < DIM) {
            if (row < DIM) v = wk[(size_t)k * DIM + row] * g1[k];
            else if (row >= 256 && row < 256 + DIM)
                v = wv[(size_t)k * DIM + (row - 256)] * g1[k];
        }
        pKV[idx] = f2b(v);
    } else if (b < 672) {               // pQ
        int idx = (b - 448) * 256 + t;
        int row = idx / KPAD, k = idx % KPAD;
        float v = (row < DIM && k < DIM) ? wq[(size_t)k * DIM + row] * g1[k] : 0.f;
        pQ[idx] = f2b(v);
    } else if (b < 896) {               // pWO (no fold)
        int idx = (b - 672) * 256 + t;
        int row = idx / KPAD, k = idx % KPAD;
        float v = (row < DIM && k < DIM) ? wo[(size_t)k * DIM + row] : 0.f;
        pWO[idx] = f2b(v);
    } else if (b < 1680) {              // pF1 (g2-folded)
        int idx = (b - 896) * 256 + t;
        int row = idx / KPAD, k = idx % KPAD;
        float v = (row < FFD && k < DIM) ? f1[(size_t)k * FFD + row] * g2[k] : 0.f;
        pF1[idx] = f2b(v);
    } else if (b < 2480) {              // pF2 [256][800]
        int idx = (b - 1680) * 256 + t;
        int row = idx / 800, k = idx % 800;
        float v = (row < DIM) ? f2[(size_t)k * DIM + row] : 0.f;
        pF2[idx] = f2b(v);
    } else if (b < 2482) {              // u/w for fused KV
        int j = b - 2480;
        const float* W    = j ? wv : wk;
        const float* bias = j ? bv : bk;
        int n = t;
        float su = 0.f, sw = 0.f;
        if (n < DIM) {
            for (int k = 0; k < DIM; ++k) {
                float wvv = W[(size_t)k * DIM + n];
                su += g1[k] * wvv;
                sw += b1[k] * wvv;
            }
            sw += bias[n];
        }
        uw[j * 256 + n] = su;
        uw[512 + j * 256 + n] = sw;
    } else if (b == 2482) {             // u/w for Q
        int n = t;
        float su = 0.f, sw = 0.f;
        if (n < DIM) {
            for (int k = 0; k < DIM; ++k) {
                float wvv = wq[(size_t)k * DIM + n];
                su += g1[k] * wvv;
                sw += b1[k] * wvv;
            }
            sw += bq[n];
        }
        uw[1024 + n] = su;
        uw[1280 + n] = sw;
    } else {                            // u/w for FF1 (896 outputs)
        int n = (b - 2483) * 256 + t;
        if (n < 896) {
            float su = 0.f, sw = 0.f;
            if (n < FFD) {
                for (int k = 0; k < DIM; ++k) {
                    float wvv = f1[(size_t)k * FFD + n];
                    su += g2[k] * wvv;
                    sw += b2[k] * wvv;
                }
                sw += f1b[n];
            }
            uw[1536 + n] = su;
            uw[2432 + n] = sw;
        }
    }
}

// ---------------- embedding: tokens are 1 (x<=0) or 5 (x>0) ----------------
__global__ __launch_bounds__(256) void embed_kernel(const float* __restrict__ x,
        const float* __restrict__ emb, bf16* __restrict__ x1, bf16* __restrict__ x2) {
    int idx = blockIdx.x * 256 + threadIdx.x;      // NTOK*25
    if (idx >= NTOK * 25) return;
    int t = idx / 25, c = idx % 25;
    int row = (x[t] > 0.f) ? 5 : 1;
    const float4* e4 = (const float4*)(emb + row * DIM + c * 8);
    float4 e0 = e4[0], e1 = e4[1];
    s8v o;
    o[0] = (short)f2u(e0.x); o[1] = (short)f2u(e0.y);
    o[2] = (short)f2u(e0.z); o[3] = (short)f2u(e0.w);
    o[4] = (short)f2u(e1.x); o[5] = (short)f2u(e1.y);
    o[6] = (short)f2u(e1.z); o[7] = (short)f2u(e1.w);
    size_t off = (size_t)t * DIM + c * 8;
    *(s8v*)((short*)x1 + off) = o;
    *(s8v*)((short*)x2 + off) = o;
}

// ---------------- LN stats (one wave per token row of 200) ----------------
__global__ __launch_bounds__(256) void lnstats_kernel(const bf16* __restrict__ in,
        float* __restrict__ mu_o, float* __restrict__ rstd_o) {
    int lane = threadIdx.x & 63;
    size_t t = (size_t)blockIdx.x * 4 + (threadIdx.x >> 6);
    const u16* row = (const u16*)in + t * DIM;
    float v0 = 0.f, v1 = 0.f, v2 = 0.f, v3 = 0.f;
    if (lane < 50) {
        ushort4 u4 = ((const ushort4*)row)[lane];
        v0 = bfu(u4.x); v1 = bfu(u4.y); v2 = bfu(u4.z); v3 = bfu(u4.w);
    }
    float s = v0 + v1 + v2 + v3, qq = v0*v0 + v1*v1 + v2*v2 + v3*v3;
    #pragma unroll
    for (int o = 32; o > 0; o >>= 1) { s += __shfl_xor(s, o); qq += __shfl_xor(qq, o); }
    if (lane == 0) {
        float mu = s * (1.f / DIM);
        mu_o[t] = mu;
        rstd_o[t] = rsqrtf(qq * (1.f / DIM) - mu * mu + 1e-5f);
    }
}

__global__ __launch_bounds__(256) void finalln_kernel(const bf16* __restrict__ in1,
        const bf16* __restrict__ in2, const float* __restrict__ g,
        const float* __restrict__ b, bf16* __restrict__ out) {
    int lane = threadIdx.x & 63;
    size_t t = (size_t)blockIdx.x * 4 + (threadIdx.x >> 6);
    const u16* r1 = (const u16*)in1 + t * DIM;
    const u16* r2 = (const u16*)in2 + t * DIM;
    float v0 = 0.f, v1 = 0.f, v2 = 0.f, v3 = 0.f;
    if (lane < 50) {
        ushort4 a4 = ((const ushort4*)r1)[lane];
        ushort4 b4 = ((const ushort4*)r2)[lane];
        v0 = 0.5f * (bfu(a4.x) + bfu(b4.x));
        v1 = 0.5f * (bfu(a4.y) + bfu(b4.y));
        v2 = 0.5f * (bfu(a4.z) + bfu(b4.z));
        v3 = 0.5f * (bfu(a4.w) + bfu(b4.w));
    }
    float s = v0 + v1 + v2 + v3, qq = v0*v0 + v1*v1 + v2*v2 + v3*v3;
    #pragma unroll
    for (int o = 32; o > 0; o >>= 1) { s += __shfl_xor(s, o); qq += __shfl_xor(qq, o); }
    float mu = s * (1.f / DIM);
    float rstd = rsqrtf(qq * (1.f / DIM) - mu * mu + 1e-5f);
    if (lane < 50) {
        float4 g4 = ((const float4*)g)[lane];
        float4 b4f = ((const float4*)b)[lane];
        ushort4 o4;
        o4.x = f2u((v0 - mu) * rstd * g4.x + b4f.x);
        o4.y = f2u((v1 - mu) * rstd * g4.y + b4f.y);
        o4.z = f2u((v2 - mu) * rstd * g4.z + b4f.z);
        o4.w = f2u((v3 - mu) * rstd * g4.w + b4f.w);
        ((ushort4*)((u16*)out + t * DIM))[lane] = o4;
    }
}

// ---------------- MFMA GEMM: C = epi(A @ Bt^T) + LN-epilogue ----------------
// HB: head-blocked store layout [head][tok][DH] (k/v/q for coalesced attn
// reads). KV=1: N=512 panel, cols 0..255 -> C (k), 256..511 -> C2 (v).
template<int EPI, int LNE, int KV, int HB>
__global__ __launch_bounds__(256) void gemm_m(
        const bf16* __restrict__ A, const bf16* __restrict__ Bt,
        const float* __restrict__ wv_, const float* __restrict__ uv_,
        const float* __restrict__ mu, const float* __restrict__ rstd,
        bf16* __restrict__ C, bf16* __restrict__ C2,
        int M, int N, int K, int Kpad) {
    __shared__ __align__(16) short As[128 * 32];
    __shared__ __align__(16) short Bs[128 * 32];
    int bm = blockIdx.x * 128, bn = blockIdx.y * 128;
    int t = threadIdx.x, l = t & 63, w = t >> 6;
    int wr = (w >> 1) * 64, wc = (w & 1) * 64;
    int lr = l & 15, lk16 = l >> 4;
    f4v acc[4][4];
    #pragma unroll
    for (int i = 0; i < 4; ++i)
        #pragma unroll
        for (int j = 0; j < 4; ++j) acc[i][j] = (f4v){0.f, 0.f, 0.f, 0.f};

    const short* Ash = (const short*)A;
    const short* Bsh = (const short*)Bt;
    int srow0 = 32 * w + (l >> 2);
    int c16 = l & 3;
    for (int k0 = 0; k0 < Kpad; k0 += 32) {
        __syncthreads();
        #pragma unroll
        for (int j = 0; j < 2; ++j) {
            int row = srow0 + 16 * j;
            int xc = (c16 ^ ((row >> 1) & 3)) * 8;
            gld_lds16(Ash + (size_t)(bm + row) * K + k0 + xc,
                      &As[(32 * w + 16 * j) * 32]);
            gld_lds16(Bsh + (size_t)(bn + row) * Kpad + k0 + xc,
                      &Bs[(32 * w + 16 * j) * 32]);
        }
        __syncthreads();
        s8v a[4], b[4];
        #pragma unroll
        for (int fi = 0; fi < 4; ++fi) {
            int R = wr + fi * 16 + lr;
            a[fi] = *(const s8v*)&As[R * 32 + ((lk16 ^ ((R >> 1) & 3)) * 8)];
        }
        #pragma unroll
        for (int fj = 0; fj < 4; ++fj) {
            int R = wc + fj * 16 + lr;
            b[fj] = *(const s8v*)&Bs[R * 32 + ((lk16 ^ ((R >> 1) & 3)) * 8)];
        }
        #pragma unroll
        for (int fi = 0; fi < 4; ++fi)
            #pragma unroll
            for (int fj = 0; fj < 4; ++fj)
                acc[fi][fj] = MFMA16(a[fi], b[fj], acc[fi][fj]);
    }
    int r0 = (l >> 4) * 4;
    #pragma unroll
    for (int fi = 0; fi < 4; ++fi) {
        int rowb = bm + wr + fi * 16 + r0;
        float sr[4] = {1.f, 1.f, 1.f, 1.f}, tr[4] = {0.f, 0.f, 0.f, 0.f};
        if (LNE) {
            #pragma unroll
            for (int r = 0; r < 4; ++r) {
                sr[r] = rstd[rowb + r];
                tr[r] = mu[rowb + r] * sr[r];
            }
        }
        #pragma unroll
        for (int fj = 0; fj < 4; ++fj) {
            int col = bn + wc + fj * 16 + lr;
            if (KV) {
                int cc = col & 255;
                if (cc < DIM) {
                    bf16* dst = (col < 256) ? C : C2;
                    int hh = cc / DH, dd = cc % DH;
                    size_t base = (size_t)hh * HSTRIDE + dd;
                    float ww = wv_[col], uu = uv_[col];
                    #pragma unroll
                    for (int r = 0; r < 4; ++r) {
                        size_t idx = base + (size_t)(rowb + r) * DH;
                        float v = sr[r] * acc[fi][fj][r] - tr[r] * uu + ww;
                        dst[idx] = f2b(v);
                    }
                }
            } else if (col < N) {
                float ww = wv_[col];
                float uu = LNE ? uv_[col] : 0.f;
                #pragma unroll
                for (int r = 0; r < 4; ++r) {
                    size_t idx;
                    if (HB) {
                        int hh = col / DH, dd = col % DH;
                        idx = (size_t)hh * HSTRIDE + (size_t)(rowb + r) * DH + dd;
                    } else {
                        idx = (size_t)(rowb + r) * N + col;
                    }
                    float v = LNE ? (sr[r] * acc[fi][fj][r] - tr[r] * uu + ww)
                                  : (acc[fi][fj][r] + ww);
                    if (EPI == 1) v += b2f(C[idx]);
                    if (EPI == 2) v = gelu_f(v);
                    C[idx] = f2b(v);
                }
            }
        }
    }
}

// ---------------- fused FF: x2 += gelu(LN(x1)@W1+b1) @ W2 + b2 --------------
// r14 structure + F2 ks=0 pre-staged under the gelu epilogue.
__global__ __launch_bounds__(256, 2) void ff_fused(
        const bf16* __restrict__ x1, const bf16* __restrict__ pF1,
        const bf16* __restrict__ pF2, const float* __restrict__ u1,
        const float* __restrict__ w1f, const float* __restrict__ fb2,
        const float* __restrict__ mu_in, const float* __restrict__ rstd_in,
        float* __restrict__ mu_out, float* __restrict__ rstd_out,
        bf16* __restrict__ x2) {
    __shared__ __align__(16) short Ax[64 * 256];    // 32KB
    __shared__ __align__(16) short Bs[2 * 128 * 32]; // 16KB (2 halves / full)
    __shared__ __align__(16) short hS[64 * HSROW];  // 16.5KB (stats overlay)
    int bm = blockIdx.x * 64;
    int t = threadIdx.x, l = t & 63, w = t >> 6;
    int wrA = (w >> 1) * 32;          // rows (both phases)
    int wcA = (w & 1) * 64;           // phase-1 hidden cols
    int wcB = (w & 1) * 128;          // phase-2 output cols
    int lr = l & 15, lk16 = l >> 4;
    int r0 = (l >> 4) * 4;
    const short* X1 = (const short*)x1;
    const short* F1 = (const short*)pF1;
    const short* F2 = (const short*)pF2;

    // ---- stage x1 tile once ----
    {
        int c = l & 31, rsub = l >> 5;
        #pragma unroll
        for (int j = 0; j < 8; ++j) {
            int row0 = w * 16 + j * 2;
            int row = row0 + rsub;
            gld_lds16(X1 + (size_t)(bm + row) * DIM + ((c ^ (row & 7)) * 8),
                      &Ax[row0 * 256]);
        }
    }

    f4v acc2[2][8];
    #pragma unroll
    for (int i = 0; i < 2; ++i)
        #pragma unroll
        for (int j = 0; j < 8; ++j) acc2[i][j] = (f4v){0.f, 0.f, 0.f, 0.f};

    int srow0 = 32 * w + (l >> 2);
    int c16 = l & 3;
    #pragma unroll 1
    for (int hc = 0; hc < 7; ++hc) {
        __syncthreads();   // prev phase-2 Bs reads done; (hc=0: drains nothing)
        // prologue: stage kt=0 into half 0
        #pragma unroll
        for (int j = 0; j < 2; ++j) {
            int row = srow0 + 16 * j;
            int xc = (c16 ^ ((row >> 1) & 3)) * 8;
            gld_lds16(F1 + (size_t)(hc * 128 + row) * KPAD + 0 + xc,
                      &Bs[(32 * w + 16 * j) * 32]);
        }
        __syncthreads();   // drains Ax (hc=0) + F1 kt0
        // ---- phase 1: h_chunk[64][128], dbuf, 1 barrier per kt ----
        f4v acc1[2][4];
        #pragma unroll
        for (int i = 0; i < 2; ++i)
            #pragma unroll
            for (int j = 0; j < 4; ++j) acc1[i][j] = (f4v){0.f, 0.f, 0.f, 0.f};
        #pragma unroll 1
        for (int kt = 0; kt < 7; ++kt) {
            if (kt < 6) {  // issue next k-tile into other half (no barrier)
                int k0n = (kt + 1) * 32;
                int hb = ((kt + 1) & 1) * 4096;
                #pragma unroll
                for (int j = 0; j < 2; ++j) {
                    int row = srow0 + 16 * j;
                    int xc = (c16 ^ ((row >> 1) & 3)) * 8;
                    gld_lds16(F1 + (size_t)(hc * 128 + row) * KPAD + k0n + xc,
                              &Bs[hb + (32 * w + 16 * j) * 32]);
                }
            }
            int hb = (kt & 1) * 4096;
            s8v a[2], b[4];
            int cg = kt * 4 + lk16;     // logical k-chunk 0..27
            #pragma unroll
            for (int fi = 0; fi < 2; ++fi) {
                int R = wrA + fi * 16 + lr;
                a[fi] = *(const s8v*)&Ax[R * 256 + ((cg ^ (R & 7)) * 8)];
            }
            #pragma unroll
            for (int fj = 0; fj < 4; ++fj) {
                int R = wcA + fj * 16 + lr;
                b[fj] = *(const s8v*)&Bs[hb + R * 32 + ((lk16 ^ ((R >> 1) & 3)) * 8)];
            }
            #pragma unroll
            for (int fi = 0; fi < 2; ++fi)
                #pragma unroll
                for (int fj = 0; fj < 4; ++fj)
                    acc1[fi][fj] = MFMA16(a[fi], b[fj], acc1[fi][fj]);
            __syncthreads();   // next half ready (vmcnt drained) + reads done
        }
        // pre-stage F2 ks=0 (Bs free after last phase-1 barrier) — its HBM/L2
        // latency hides under the gelu epilogue below
        #pragma unroll
        for (int j = 0; j < 4; ++j) {
            int row = (w * 4 + j) * 16 + (l >> 2);
            int xc = (c16 ^ ((row >> 1) & 3)) * 8;
            gld_lds16(F2 + (size_t)row * 800 + hc * 128 + 0 + xc,
                      &Bs[(w * 4 + j) * 16 * 32]);
        }
        // h epilogue -> hS (stride HSROW, chunk ^ row&7 swizzle)
        #pragma unroll
        for (int fi = 0; fi < 2; ++fi) {
            int rowL = wrA + fi * 16 + r0;
            f4v rs = *(const f4v*)&rstd_in[bm + rowL];
            f4v mm = *(const f4v*)&mu_in[bm + rowL];
            #pragma unroll
            for (int fj = 0; fj < 4; ++fj) {
                int col = wcA + fj * 16 + lr;
                int gcol = hc * 128 + col;
                float uu = u1[gcol], ww = w1f[gcol];
                #pragma unroll
                for (int r = 0; r < 4; ++r) {
                    float v = rs[r] * acc1[fi][fj][r] - mm[r] * rs[r] * uu + ww;
                    v = gelu_f(v);
                    int rr = rowL + r;
                    hS[rr * HSROW + (((col >> 3) ^ (rr & 7)) * 8) + (col & 7)]
                        = (short)f2u(v);
                }
            }
        }
        // ---- phase 2: acc2 += h_chunk @ W2chunk (K=128) ----
        #pragma unroll 1
        for (int ks = 0; ks < 4; ++ks) {
            if (ks) {           // stage F2 ks (ks=0 already in flight)
                __syncthreads();   // prev Bs reads done
                #pragma unroll
                for (int j = 0; j < 4; ++j) {
                    int row = (w * 4 + j) * 16 + (l >> 2);
                    int xc = (c16 ^ ((row >> 1) & 3)) * 8;
                    gld_lds16(F2 + (size_t)row * 800 + hc * 128 + ks * 32 + xc,
                              &Bs[(w * 4 + j) * 16 * 32]);
                }
            }
            __syncthreads();    // F2(ks) ready + hS visible
            s8v a[2];
            int cg = ks * 4 + lk16;
            #pragma unroll
            for (int fi = 0; fi < 2; ++fi) {
                int R = wrA + fi * 16 + lr;
                a[fi] = *(const s8v*)&hS[R * HSROW + ((cg ^ (R & 7)) * 8)];
            }
            #pragma unroll
            for (int fj = 0; fj < 8; ++fj) {
                int Br = wcB + fj * 16 + lr;
                s8v bfr = *(const s8v*)&Bs[Br * 32 + ((lk16 ^ ((Br >> 1) & 3)) * 8)];
                #pragma unroll
                for (int fi = 0; fi < 2; ++fi)
                    acc2[fi][fj] = MFMA16(a[fi], bfr, acc2[fi][fj]);
            }
        }
    }
    // ---- final epilogue: x2 += acc2 + b2, plus next-layer LN1 stats ----
    __syncthreads();                 // all hS reads done; overlay stats on hS
    float* sp = (float*)hS;          // [64][2(half)][2(sum,sq)]
    float rsum[2][4], rsq[2][4];
    #pragma unroll
    for (int fi = 0; fi < 2; ++fi)
        #pragma unroll
        for (int r = 0; r < 4; ++r) { rsum[fi][r] = 0.f; rsq[fi][r] = 0.f; }
    #pragma unroll
    for (int fi = 0; fi < 2; ++fi) {
        int rowb = bm + wrA + fi * 16 + r0;
        #pragma unroll
        for (int fj = 0; fj < 8; ++fj) {
            int col = wcB + fj * 16 + lr;
            if (col < DIM) {
                float bb = fb2[col];
                #pragma unroll
                for (int r = 0; r < 4; ++r) {
                    size_t idx = (size_t)(rowb + r) * DIM + col;
                    float v = acc2[fi][fj][r] + bb + b2f(x2[idx]);
                    x2[idx] = f2b(v);
                    rsum[fi][r] += v;
                    rsq[fi][r] += v * v;
                }
            }
        }
    }
    // lane-reduce across the 16 lr lanes (cols), then cross-wave via LDS
    #pragma unroll
    for (int fi = 0; fi < 2; ++fi)
        #pragma unroll
        for (int r = 0; r < 4; ++r) {
            float s = rsum[fi][r], q = rsq[fi][r];
            #pragma unroll
            for (int o = 8; o > 0; o >>= 1) {
                s += __shfl_xor(s, o);
                q += __shfl_xor(q, o);
            }
            rsum[fi][r] = s; rsq[fi][r] = q;
        }
    if (lr == 0) {
        #pragma unroll
        for (int fi = 0; fi < 2; ++fi)
            #pragma unroll
            for (int r = 0; r < 4; ++r) {
                int rowL = wrA + fi * 16 + r0 + r;
                sp[rowL * 4 + (w & 1) * 2 + 0] = rsum[fi][r];
                sp[rowL * 4 + (w & 1) * 2 + 1] = rsq[fi][r];
            }
    }
    __syncthreads();
    if (t < 64) {
        float s = sp[t * 4 + 0] + sp[t * 4 + 2];
        float q = sp[t * 4 + 1] + sp[t * 4 + 3];
        float mu = s * (1.f / DIM);
        mu_out[bm + t] = mu;
        rstd_out[bm + t] = rsqrtf(q * (1.f / DIM) - mu * mu + 1e-5f);
    }
}

// ---- MFMA kvctx with ONLINE per-(n,h) max; k/v HEAD-BLOCKED [h][tok][20] ---
__global__ __launch_bounds__(256) void kvctx_mfma(const bf16* __restrict__ k,
        const bf16* __restrict__ v, const float* __restrict__ proj,
        float* __restrict__ ctxg) {
    __shared__ __align__(16) short ph[64 * KNROW];
    __shared__ __align__(16) short pl[64 * KNROW];
    __shared__ __align__(16) short knh[128 * KNROW];
    __shared__ __align__(16) short knl[128 * KNROW];
    __shared__ __align__(16) short vT[32 * VROW];
    __shared__ __align__(16) short kp[64 * KPROW];
    __shared__ __align__(16) float diag[128];
    __shared__ float wmax[4];
    int nh = blockIdx.x, n = nh / HEADS, h = nh % HEADS;
    int t = threadIdx.x, l = t & 63, w = t >> 6;
    int lr = l & 15, lk = (l >> 4) * 8, l4 = (l >> 4) * 4;
    const u16* kbase = (const u16*)k + (size_t)h * HSTRIDE;
    const u16* vbase = (const u16*)v + (size_t)h * HSTRIDE;
    for (int i = t; i < 64 * 32; i += 256) {
        int m = i >> 5, d = i & 31;
        float val = (m < NBF && d < DH) ? proj[m * DH + d] : 0.f;
        u16 hi = f2u(val);
        ph[m * KNROW + d] = (short)hi;
        pl[m * KNROW + d] = (short)f2u(val - bfu(hi));
    }
    for (int i = t; i < 128 * 12; i += 256) {
        int s = i / 12, d = 20 + i % 12;
        knh[s * KNROW + d] = 0; knl[s * KNROW + d] = 0;
    }
    for (int i = t; i < 12 * 128; i += 256) {
        int d = 20 + (i >> 7), s = i & 127;
        vT[d * VROW + s] = (short)((d == 20) ? f2u(1.0f) : 0);
    }
    s8v ones;
    #pragma unroll
    for (int i = 0; i < 8; ++i) ones[i] = (short)f2u(1.0f);
    float Mrun = -3.0e38f;
    f4v cd0 = {0.f,0.f,0.f,0.f}, cd1 = {0.f,0.f,0.f,0.f};
    f4v vs0 = {0.f,0.f,0.f,0.f}, vs1 = {0.f,0.f,0.f,0.f};
    for (int c = 0; c < 16; ++c) {
        int s0 = c * 128;
        __syncthreads();
        if (t < 128) {          // waves 0,1: stage kn hi/lo + diag
            int s = t;
            const u16* kr = kbase + (size_t)(n * SEQ + s0 + s) * DH;
            float dg = 0.f;
            #pragma unroll
            for (int q5 = 0; q5 < 5; ++q5) {
                ushort4 u4 = ((const ushort4*)kr)[q5];
                float f0 = bfu(u4.x) * SCALE, f1 = bfu(u4.y) * SCALE;
                float f2_ = bfu(u4.z) * SCALE, f3 = bfu(u4.w) * SCALE;
                dg += f0*f0 + f1*f1 + f2_*f2_ + f3*f3;
                u16 h0 = f2u(f0), h1 = f2u(f1), h2 = f2u(f2_), h3 = f2u(f3);
                s4v hv = {(short)h0, (short)h1, (short)h2, (short)h3};
                *(s4v*)&knh[s * KNROW + q5 * 4] = hv;
                s4v lv = {(short)f2u(f0 - bfu(h0)), (short)f2u(f1 - bfu(h1)),
                          (short)f2u(f2_ - bfu(h2)), (short)f2u(f3 - bfu(h3))};
                *(s4v*)&knl[s * KNROW + q5 * 4] = lv;
            }
            diag[s] = 0.5f * dg;
        } else {                // waves 2,3: stage vT (scatter to [d][s])
            int s = t - 128;
            const u16* vr = vbase + (size_t)(n * SEQ + s0 + s) * DH;
            #pragma unroll
            for (int q5 = 0; q5 < 5; ++q5) {
                ushort4 u4 = ((const ushort4*)vr)[q5];
                vT[(q5 * 4 + 0) * VROW + s] = (short)u4.x;
                vT[(q5 * 4 + 1) * VROW + s] = (short)u4.y;
                vT[(q5 * 4 + 2) * VROW + s] = (short)u4.z;
                vT[(q5 * 4 + 3) * VROW + s] = (short)u4.w;
            }
        }
        __syncthreads();
        s8v ah0 = *(const s8v*)&knh[(32 * w + lr) * KNROW + lk];
        s8v al0 = *(const s8v*)&knl[(32 * w + lr) * KNROW + lk];
        s8v ah1 = *(const s8v*)&knh[(32 * w + 16 + lr) * KNROW + lk];
        s8v al1 = *(const s8v*)&knl[(32 * w + 16 + lr) * KNROW + lk];
        f4v dg0 = *(const f4v*)&diag[32 * w + l4];
        f4v dg1 = *(const f4v*)&diag[32 * w + 16 + l4];
        f4v D0[4], D1[4];
        #pragma unroll
        for (int mt = 0; mt < 4; ++mt) {
            s8v bh = *(const s8v*)&ph[(mt * 16 + lr) * KNROW + lk];
            s8v bl = *(const s8v*)&pl[(mt * 16 + lr) * KNROW + lk];
            f4v d0 = {0.f, 0.f, 0.f, 0.f}, d1 = {0.f, 0.f, 0.f, 0.f};
            d0 = MFMA16(ah0, bh, d0); d0 = MFMA16(ah0, bl, d0); d0 = MFMA16(al0, bh, d0);
            d1 = MFMA16(ah1, bh, d1); d1 = MFMA16(ah1, bl, d1); d1 = MFMA16(al1, bh, d1);
            D0[mt] = d0; D1[mt] = d1;
        }
        float mm = -3.0e38f;
        #pragma unroll
        for (int mt = 0; mt < 4; ++mt) {
            int lim = (mt < 3) ? 16 : (NBF - 48);
            if (lr < lim) {
                #pragma unroll
                for (int r = 0; r < 4; ++r)
                    mm = fmaxf(mm, fmaxf(D0[mt][r], D1[mt][r]));
            }
        }
        #pragma unroll
        for (int o = 32; o > 0; o >>= 1) mm = fmaxf(mm, __shfl_xor(mm, o));
        if (l == 0) wmax[w] = mm;
        __syncthreads();
        float Mnew = fmaxf(fmaxf(wmax[0], wmax[1]), fmaxf(wmax[2], wmax[3]));
        Mnew = fmaxf(Mrun, Mnew);
        float scl = __expf(Mrun - Mnew);
        #pragma unroll
        for (int r = 0; r < 4; ++r) { cd0[r] *= scl; cd1[r] *= scl; }
        Mrun = Mnew;
        #pragma unroll
        for (int mt = 0; mt < 4; ++mt) {
            int m = mt * 16 + lr;
            bool valid = m < NBF;
            s4v o0, o1;
            #pragma unroll
            for (int r = 0; r < 4; ++r) {
                float kp0 = valid ? __expf(D0[mt][r] - dg0[r] - Mnew) : 0.f;
                float kp1 = valid ? __expf(D1[mt][r] - dg1[r] - Mnew) : 0.f;
                o0[r] = (short)f2u(kp0);
                o1[r] = (short)f2u(kp1);
            }
            *(s4v*)&kp[m * KPROW + 32 * w + l4] = o0;
            *(s4v*)&kp[m * KPROW + 32 * w + 16 + l4] = o1;
        }
        __syncthreads();
        #pragma unroll
        for (int ks = 0; ks < 4; ++ks) {
            s8v a  = *(const s8v*)&kp[(16 * w + lr) * KPROW + ks * 32 + lk];
            s8v b0 = *(const s8v*)&vT[lr * VROW + ks * 32 + lk];
            s8v b1 = *(const s8v*)&vT[(16 + lr) * VROW + ks * 32 + lk];
            cd0 = MFMA16(a, b0, cd0);
            cd1 = MFMA16(a, b1, cd1);
            vs0 = MFMA16(ones, b0, vs0);
            vs1 = MFMA16(ones, b1, vs1);
        }
    }
    float* cg = ctxg + (size_t)nh * CTXR * 64;
    int m0 = 16 * w + l4;
    f4v r0v, r1v;
    #pragma unroll
    for (int r = 0; r < 4; ++r) {
        r0v[r] = RATIO * (cd0[r] + KEPS * vs0[r]);
        r1v[r] = RATIO * (cd1[r] + KEPS * vs1[r]);
    }
    *(f4v*)&cg[lr * 64 + m0] = r0v;
    if (lr < 5) *(f4v*)&cg[(16 + lr) * 64 + m0] = r1v;
}

// ---- MFMA qattn: q HEAD-BLOCKED [h][tok][20]; split 4; ao [tok][DIM] -------
__global__ __launch_bounds__(256) void qattn_mfma(const bf16* __restrict__ q,
        const float* __restrict__ proj, const float* __restrict__ ctxg,
        bf16* __restrict__ ao) {
    __shared__ __align__(16) short ph[64 * KNROW];
    __shared__ __align__(16) short pl[64 * KNROW];
    __shared__ __align__(16) short qnh[128 * KNROW];
    __shared__ __align__(16) short qnl[128 * KNROW];
    __shared__ __align__(16) short qp[128 * QPROW];
    __shared__ __align__(16) short cT[32 * QPROW];
    __shared__ __align__(16) float dgs[128];
    __shared__ __align__(16) float osf[128][22];
    int b = blockIdx.x;
    int nh = b >> 2, sc = b & 3;
    int n = nh / HEADS, h = nh % HEADS;
    int t = threadIdx.x, l = t & 63, w = t >> 6;
    int lr = l & 15, lk = (l >> 4) * 8, l4 = (l >> 4) * 4;
    const u16* qbase = (const u16*)q + (size_t)h * HSTRIDE;
    for (int i = t; i < 64 * 32; i += 256) {
        int m = i >> 5, d = i & 31;
        float val = (m < NBF && d < DH) ? proj[m * DH + d] : 0.f;
        u16 hi = f2u(val);
        ph[m * KNROW + d] = (short)hi;
        pl[m * KNROW + d] = (short)f2u(val - bfu(hi));
    }
    for (int i = t; i < 128 * 12; i += 256) {
        int s = i / 12, d = 20 + i % 12;
        qnh[s * KNROW + d] = 0; qnl[s * KNROW + d] = 0;
    }
    for (int i = t; i < 32 * 64; i += 256) {
        int d = i >> 6, m = i & 63;
        float val = (d < CTXR) ? ctxg[(size_t)nh * CTXR * 64 + d * 64 + m] : 0.f;
        cT[d * QPROW + m] = (short)f2u(val);
    }
    for (int c = 0; c < 4; ++c) {
        int s0 = (sc * 4 + c) * 128;
        __syncthreads();
        if (t < 128) {
            int s = t;
            const u16* qr = qbase + (size_t)(n * SEQ + s0 + s) * DH;
            float dg = 0.f;
            #pragma unroll
            for (int q5 = 0; q5 < 5; ++q5) {
                ushort4 u4 = ((const ushort4*)qr)[q5];
                float f0 = bfu(u4.x) * SCALE, f1 = bfu(u4.y) * SCALE;
                float f2_ = bfu(u4.z) * SCALE, f3 = bfu(u4.w) * SCALE;
                dg += f0*f0 + f1*f1 + f2_*f2_ + f3*f3;
                u16 h0 = f2u(f0), h1 = f2u(f1), h2 = f2u(f2_), h3 = f2u(f3);
                s4v hv = {(short)h0, (short)h1, (short)h2, (short)h3};
                *(s4v*)&qnh[s * KNROW + q5 * 4] = hv;
                s4v lv = {(short)f2u(f0 - bfu(h0)), (short)f2u(f1 - bfu(h1)),
                          (short)f2u(f2_ - bfu(h2)), (short)f2u(f3 - bfu(h3))};
                *(s4v*)&qnl[s * KNROW + q5 * 4] = lv;
            }
            dgs[s] = 0.5f * dg;
        }
        __syncthreads();
        s8v ah0 = *(const s8v*)&qnh[(32 * w + lr) * KNROW + lk];
        s8v al0 = *(const s8v*)&qnl[(32 * w + lr) * KNROW + lk];
        s8v ah1 = *(const s8v*)&qnh[(32 * w + 16 + lr) * KNROW + lk];
        s8v al1 = *(const s8v*)&qnl[(32 * w + 16 + lr) * KNROW + lk];
        f4v D0[4], D1[4];
        #pragma unroll
        for (int mt = 0; mt < 4; ++mt) {
            s8v bh = *(const s8v*)&ph[(mt * 16 + lr) * KNROW + lk];
            s8v bl = *(const s8v*)&pl[(mt * 16 + lr) * KNROW + lk];
            f4v d0 = {0.f, 0.f, 0.f, 0.f}, d1 = {0.f, 0.f, 0.f, 0.f};
            d0 = MFMA16(ah0, bh, d0); d0 = MFMA16(ah0, bl, d0); d0 = MFMA16(al0, bh, d0);
            d1 = MFMA16(ah1, bh, d1); d1 = MFMA16(ah1, bl, d1); d1 = MFMA16(al1, bh, d1);
            D0[mt] = d0; D1[mt] = d1;
        }
        f4v dg0 = *(const f4v*)&dgs[32 * w + l4];
        f4v dg1 = *(const f4v*)&dgs[32 * w + 16 + l4];
        float mx0[4], mx1[4];
        #pragma unroll
        for (int r = 0; r < 4; ++r) {
            float v3 = (lr < NBF - 48) ? D0[3][r] : -3.4e38f;
            float mm = fmaxf(fmaxf(D0[0][r], D0[1][r]), fmaxf(D0[2][r], v3));
            mm = fmaxf(mm, __shfl_xor(mm, 1));
            mm = fmaxf(mm, __shfl_xor(mm, 2));
            mm = fmaxf(mm, __shfl_xor(mm, 4));
            mm = fmaxf(mm, __shfl_xor(mm, 8));
            mx0[r] = mm;
            float u3 = (lr < NBF - 48) ? D1[3][r] : -3.4e38f;
            float nn = fmaxf(fmaxf(D1[0][r], D1[1][r]), fmaxf(D1[2][r], u3));
            nn = fmaxf(nn, __shfl_xor(nn, 1));
            nn = fmaxf(nn, __shfl_xor(nn, 2));
            nn = fmaxf(nn, __shfl_xor(nn, 4));
            nn = fmaxf(nn, __shfl_xor(nn, 8));
            mx1[r] = nn;
        }
        #pragma unroll
        for (int mt = 0; mt < 4; ++mt) {
            int m = mt * 16 + lr;
            bool valid = m < NBF;
            #pragma unroll
            for (int r = 0; r < 4; ++r) {
                float p0 = valid ? RATIO * (__expf(D0[mt][r] - dg0[r] - mx0[r]) + KEPS) : 0.f;
                float p1 = valid ? RATIO * (__expf(D1[mt][r] - dg1[r] - mx1[r]) + KEPS) : 0.f;
                qp[(32 * w + l4 + r) * QPROW + m] = (short)f2u(p0);
                qp[(32 * w + 16 + l4 + r) * QPROW + m] = (short)f2u(p1);
            }
        }
        __syncthreads();
        f4v o00 = {0.f,0.f,0.f,0.f}, o01 = {0.f,0.f,0.f,0.f};
        f4v o10 = {0.f,0.f,0.f,0.f}, o11 = {0.f,0.f,0.f,0.f};
        #pragma unroll
        for (int ks = 0; ks < 2; ++ks) {
            s8v a0 = *(const s8v*)&qp[(32 * w + lr) * QPROW + ks * 32 + lk];
            s8v a1 = *(const s8v*)&qp[(32 * w + 16 + lr) * QPROW + ks * 32 + lk];
            s8v b0 = *(const s8v*)&cT[lr * QPROW + ks * 32 + lk];
            s8v b1 = *(const s8v*)&cT[(16 + lr) * QPROW + ks * 32 + lk];
            o00 = MFMA16(a0, b0, o00); o01 = MFMA16(a0, b1, o01);
            o10 = MFMA16(a1, b0, o10); o11 = MFMA16(a1, b1, o11);
        }
        #pragma unroll
        for (int r = 0; r < 4; ++r) {
            osf[32 * w + l4 + r][lr] = o00[r];
            osf[32 * w + 16 + l4 + r][lr] = o10[r];
            if (lr < 5) {
                osf[32 * w + l4 + r][16 + lr] = o01[r];
                osf[32 * w + 16 + l4 + r][16 + lr] = o11[r];
            }
        }
        __syncthreads();
        if (t < 128) osf[t][21] = 1.f / osf[t][20];
        __syncthreads();
        int tokb = n * SEQ + s0;
        for (int idx = t; idx < 128 * 10; idx += 256) {
            int row = idx / 10, seg = idx % 10;
            float di = osf[row][21];
            ushort2 o2;
            o2.x = f2u(osf[row][seg * 2] * di);
            o2.y = f2u(osf[row][seg * 2 + 1] * di);
            *(ushort2*)((u16*)ao + (size_t)(tokb + row) * DIM + h * DH + seg * 2) = o2;
        }
    }
}

// ---------------- pooling ----------------
__global__ __launch_bounds__(256) void pool1_kernel(const bf16* __restrict__ hn,
        float* __restrict__ partial) {
    int n = blockIdx.x / 16, c = blockIdx.x % 16;
    int d = threadIdx.x;
    if (d >= DIM) return;
    float acc = 0.f;
    const bf16* base = hn + ((size_t)n * SEQ + c * 128) * DIM + d;
    for (int s = 0; s < 128; ++s) acc += b2f(base[(size_t)s * DIM]);
    partial[(size_t)blockIdx.x * DIM + d] = acc;
}

__global__ __launch_bounds__(256) void pool2_kernel(const float* __restrict__ partial,
        float* __restrict__ pooled) {
    int n = blockIdx.x, d = threadIdx.x;
    if (d >= DIM) return;
    float acc = 0.f;
    for (int c = 0; c < 16; ++c) acc += partial[(size_t)(n * 16 + c) * DIM + d];
    pooled[n * DIM + d] = acc * (1.f / SEQ);
}

__global__ __launch_bounds__(512) void finalproj_kernel(const float* __restrict__ pooled,
        const float* __restrict__ pw, const float* __restrict__ pb,
        float* __restrict__ out) {
    __shared__ float ps[DIM];
    int n = blockIdx.x;
    for (int i = threadIdx.x; i < DIM; i += 512) ps[i] = pooled[n * DIM + i];
    __syncthreads();
    int j = threadIdx.x;
    float acc = pb[j];
    for (int d = 0; d < DIM; ++d) acc += ps[d] * pw[d * DMODEL + j];
    out[n * DMODEL + j] = acc;
}

// ---------------- host launch ----------------
extern "C" void kernel_launch(void* const* d_in, const int* in_sizes, int n_in,
                              void* d_out, int out_size, void* d_ws, size_t ws_size,
                              hipStream_t stream) {
    (void)in_sizes; (void)n_in; (void)out_size;
    const float* x    = (const float*)d_in[0];
    const float* emb  = (const float*)d_in[1];
    const float* ln1g = (const float*)d_in[2];
    const float* ln1b = (const float*)d_in[3];
    const float* wq   = (const float*)d_in[4];
    const float* bq   = (const float*)d_in[5];
    const float* wk   = (const float*)d_in[6];
    const float* bk   = (const float*)d_in[7];
    const float* wv   = (const float*)d_in[8];
    const float* bv   = (const float*)d_in[9];
    const float* proj = (const float*)d_in[10];
    const float* wo   = (const float*)d_in[11];
    const float* bo   = (const float*)d_in[12];
    const float* ln2g = (const float*)d_in[13];
    const float* ln2b = (const float*)d_in[14];
    const float* ffw1 = (const float*)d_in[15];
    const float* ffb1 = (const float*)d_in[16];
    const float* ffw2 = (const float*)d_in[17];
    const float* ffb2 = (const float*)d_in[18];
    const float* lnfg = (const float*)d_in[19];
    const float* lnfb = (const float*)d_in[20];
    const float* pw   = (const float*)d_in[21];
    const float* pb   = (const float*)d_in[22];
    float* out = (float*)d_out;

    const size_t A_ = (size_t)NTOK * DIM;
    bf16* x1 = (bf16*)d_ws;
    bf16* x2 = x1 + A_ + BUFPAD;
    bf16* b3 = x2 + A_ + BUFPAD;     // k -> q (head-blocked)
    bf16* b4 = b3 + A_ + BUFPAD;     // v (head-blocked) -> attn out [tok][DIM]
    bf16* pKV = b4 + A_ + BUFPAD;
    bf16* pQ  = pKV + PKV_E;
    bf16* pWO = pQ + PQ_E;
    bf16* pF1 = pWO + PWO_E;
    bf16* pF2 = pF1 + PF1_E;
    float* muB   = (float*)(pF2 + PF2_E);      // x2 / LN1 stats
    float* rstdB = muB + NTOK;
    float* muC   = rstdB + NTOK;               // x1 / LN2 stats
    float* rstdC = muC + NTOK;
    float* uw    = rstdC + NTOK;               // 3328 floats
    float* ctxg  = uw + 3328;                  // 640 * 21 * 64 floats
    float* wsend = ctxg + (size_t)NSEQ * HEADS * CTXR * 64;

    float* ukv = uw,        *wkv = uw + 512;
    float* uq  = uw + 1024, *wqf = uw + 1280;
    float* u1  = uw + 1536, *w1f = uw + 2432;

    size_t need = (char*)wsend - (char*)d_ws;
    if (ws_size < need) {
        sentinel_kernel<<<1, 64, 0, stream>>>(out, (float)(ws_size >> 20));
        return;
    }

    zeropad_kernel<<<1, 64, 0, stream>>>(x1 + A_, x2 + A_, b3 + A_, b4 + A_);
    embed_kernel<<<(NTOK * 25 + 255) / 256, 256, 0, stream>>>(x, emb, x1, x2);
    // prime LN1 stats for layer 0 (subsequent layers: computed inside ff_fused)
    lnstats_kernel<<<NTOK / 4, 256, 0, stream>>>(x2, muB, rstdB);

    dim3 gkv(NTOK / 128, 4);
    dim3 gd(NTOK / 128, 2);
    for (int l = 0; l < DEPTH; ++l) {
        const float* wq_l = wq + (size_t)l * DIM * DIM;
        const float* wk_l = wk + (size_t)l * DIM * DIM;
        const float* wv_l = wv + (size_t)l * DIM * DIM;
        const float* wo_l = wo + (size_t)l * DIM * DIM;
        const float* f1_l = ffw1 + (size_t)l * DIM * FFD;
        const float* f2_l = ffw2 + (size_t)l * FFD * DIM;
        const float* pj_l = proj + (size_t)l * NBF * DH;
        const float* g1 = ln1g + l * DIM, *b1 = ln1b + l * DIM;
        const float* g2 = ln2g + l * DIM, *b2 = ln2b + l * DIM;

        prep_layer<<<2487, 256, 0, stream>>>(wq_l, wk_l, wv_l, wo_l, f1_l, f2_l,
                g1, b1, g2, b2, bq + l * DIM, bk + l * DIM, bv + l * DIM,
                ffb1 + l * FFD, pKV, pQ, pWO, pF1, pF2, uw);

        // k -> b3, v -> b4 (fused, head-blocked stores)
        gemm_m<0, 1, 1, 0><<<gkv, 256, 0, stream>>>(x2, pKV, wkv, ukv, muB, rstdB,
                b3, b4, NTOK, 512, DIM, KPAD);
        kvctx_mfma<<<NSEQ * HEADS, 256, 0, stream>>>(b3, b4, pj_l, ctxg);
        // q -> b3 (k dead; head-blocked store)
        gemm_m<0, 1, 0, 1><<<gd, 256, 0, stream>>>(x2, pQ, wqf, uq, muB, rstdB,
                b3, nullptr, NTOK, DIM, DIM, KPAD);
        // attn out -> b4 (v dead; ao is [tok][DIM])
        qattn_mfma<<<NSEQ * HEADS * 4, 256, 0, stream>>>(b3, pj_l, ctxg, b4);
        // x1 += b4 @ wo + bo
        gemm_m<1, 0, 0, 0><<<gd, 256, 0, stream>>>(b4, pWO, bo + l * DIM, nullptr,
                nullptr, nullptr, x1, nullptr, NTOK, DIM, DIM, KPAD);

        // fused FF (also writes next layer's LN1 stats into muB/rstdB)
        lnstats_kernel<<<NTOK / 4, 256, 0, stream>>>(x1, muC, rstdC);
        ff_fused<<<NTOK / 64, 256, 0, stream>>>(x1, pF1, pF2, u1, w1f,
                ffb2 + l * DIM, muC, rstdC, muB, rstdB, x2);
    }

    finalln_kernel<<<NTOK / 4, 256, 0, stream>>>(x1, x2, lnfg, lnfb, b3);
    float* partial = muB;
    float* pooled  = muB + (size_t)NSEQ * 16 * DIM;
    pool1_kernel<<<NSEQ * 16, 256, 0, stream>>>(b3, partial);
    pool2_kernel<<<NSEQ, 256, 0, stream>>>(partial, pooled);
    finalproj_kernel<<<NSEQ, 512, 0, stream>>>(pooled, pw, pb, out);
}

// Round 18
// 3856.231 us; speedup vs baseline: 1.4759x; 1.0888x over previous
//
#include <hip/hip_runtime.h>
#include <hip/hip_bf16.h>
#include <math.h>

#define DEPTH   6
#define DIM     200
#define HEADS   10
#define DH      20
#define NBF     59
#define FFD     800
#define DMODEL  512
#define NSEQ    64
#define SEQ     2048
#define NTOK    (NSEQ*SEQ)   // 131072
#define KPAD    224          // ceil(200/32)*32
#define BUFPAD  64
#define KNROW   40           // staged row stride (shorts) for kn/qn/proj
#define VROW    136          // vT row stride
#define KPROW   136          // kp row stride
#define QPROW   72           // qp / ctxT row stride
#define CTXR    21           // ctx rows stored (d=0..19 + ksum row 20)
#define HSROW   132          // ff hidden LDS row stride (66 dwords == 2 mod 32)
#define HSTRIDE ((size_t)NTOK * DH)   // head-block stride in elements
// panel element counts
#define PKV_E   (512*KPAD)
#define PQ_E    (256*KPAD)
#define PWO_E   (256*KPAD)
#define PF1_E   (896*KPAD)
#define PF2_E   (256*800)

typedef __hip_bfloat16 bf16;
typedef unsigned short u16;
typedef short s8v __attribute__((ext_vector_type(8)));
typedef short s4v __attribute__((ext_vector_type(4)));
typedef float f4v __attribute__((ext_vector_type(4)));

constexpr float SCALE = 0.4728708045015879f;   // 20^-0.25
constexpr float RATIO = 0.1301889109808239f;   // 59^-0.5
constexpr float KEPS  = 1e-4f;

__device__ __forceinline__ float b2f(bf16 v) { return __bfloat162float(v); }
__device__ __forceinline__ bf16 f2b(float v) { return __float2bfloat16(v); }
__device__ __forceinline__ float bfu(u16 u) {
    return __uint_as_float(((unsigned)u) << 16);
}
__device__ __forceinline__ u16 f2u(float v) {
    bf16 hb = __float2bfloat16(v);
    return *(u16*)&hb;
}
// tanh-form gelu
__device__ __forceinline__ float gelu_f(float x) {
    float inner = 0.7978845608028654f * (x + 0.044715f * x * x * x);
    float e = __expf(2.f * inner);
    return x * (1.f - 1.f / (e + 1.f));
}
// async global -> LDS, 16B per lane; LDS dest = wave-uniform base + lane*16
__device__ __forceinline__ void gld_lds16(const short* g, short* l) {
    __builtin_amdgcn_global_load_lds(
        (const __attribute__((address_space(1))) void*)g,
        (__attribute__((address_space(3))) void*)l, 16, 0, 0);
}
#define MFMA16(a, b, c) __builtin_amdgcn_mfma_f32_16x16x32_bf16(a, b, c, 0, 0, 0)

// ---------------- sentinel ----------------
__global__ void sentinel_kernel(float* out, float wsmb) {
    if (threadIdx.x == 0) out[0] = wsmb;
}

__global__ void zeropad_kernel(bf16* p1, bf16* p2, bf16* p3, bf16* p4) {
    int i = threadIdx.x;
    if (i < BUFPAD) {
        bf16 z = f2b(0.f);
        p1[i] = z; p2[i] = z; p3[i] = z; p4[i] = z;
    }
}

// ---- per-layer prep: all weight panels + LN-fold vectors, one launch ------
__global__ __launch_bounds__(256) void prep_layer(
        const float* __restrict__ wq, const float* __restrict__ wk,
        const float* __restrict__ wv, const float* __restrict__ wo,
        const float* __restrict__ f1, const float* __restrict__ f2,
        const float* __restrict__ g1, const float* __restrict__ b1,
        const float* __restrict__ g2, const float* __restrict__ b2,
        const float* __restrict__ bq, const float* __restrict__ bk,
        const float* __restrict__ bv, const float* __restrict__ f1b,
        bf16* __restrict__ pKV, bf16* __restrict__ pQ, bf16* __restrict__ pWO,
        bf16* __restrict__ pF1, bf16* __restrict__ pF2,
        float* __restrict__ uw) {
    int b = blockIdx.x, t = threadIdx.x;
    if (b < 448) {                      // pKV: rows 0..255 = k, 256..511 = v
        int idx = b * 256 + t;
        int row = idx / KPAD, k = idx % KPAD;
        float v = 0.f;
        if (k < DIM) {
            if (row < DIM) v = wk[(size_t)k * DIM + row] * g1[k];
            else if (row >= 256 && row < 256 + DIM)
                v = wv[(size_t)k * DIM + (row - 256)] * g1[k];
        }
        pKV[idx] = f2b(v);
    } else if (b < 672) {               // pQ
        int idx = (b - 448) * 256 + t;
        int row = idx / KPAD, k = idx % KPAD;
        float v = (row < DIM && k < DIM) ? wq[(size_t)k * DIM + row] * g1[k] : 0.f;
        pQ[idx] = f2b(v);
    } else if (b < 896) {               // pWO (no fold)
        int idx = (b - 672) * 256 + t;
        int row = idx / KPAD, k = idx % KPAD;
        float v = (row < DIM && k < DIM) ? wo[(size_t)k * DIM + row] : 0.f;
        pWO[idx] = f2b(v);
    } else if (b < 1680) {              // pF1 (g2-folded)
        int idx = (b - 896) * 256 + t;
        int row = idx / KPAD, k = idx % KPAD;
        float v = (row < FFD && k < DIM) ? f1[(size_t)k * FFD + row] * g2[k] : 0.f;
        pF1[idx] = f2b(v);
    } else if (b < 2480) {              // pF2 [256][800]
        int idx = (b - 1680) * 256 + t;
        int row = idx / 800, k = idx % 800;
        float v = (row < DIM) ? f2[(size_t)k * DIM + row] : 0.f;
        pF2[idx] = f2b(v);
    } else if (b < 2482) {              // u/w for fused KV
        int j = b - 2480;
        const float* W    = j ? wv : wk;
        const float* bias = j ? bv : bk;
        int n = t;
        float su = 0.f, sw = 0.f;
        if (n < DIM) {
            for (int k = 0; k < DIM; ++k) {
                float wvv = W[(size_t)k * DIM + n];
                su += g1[k] * wvv;
                sw += b1[k] * wvv;
            }
            sw += bias[n];
        }
        uw[j * 256 + n] = su;
        uw[512 + j * 256 + n] = sw;
    } else if (b == 2482) {             // u/w for Q
        int n = t;
        float su = 0.f, sw = 0.f;
        if (n < DIM) {
            for (int k = 0; k < DIM; ++k) {
                float wvv = wq[(size_t)k * DIM + n];
                su += g1[k] * wvv;
                sw += b1[k] * wvv;
            }
            sw += bq[n];
        }
        uw[1024 + n] = su;
        uw[1280 + n] = sw;
    } else {                            // u/w for FF1 (896 outputs)
        int n = (b - 2483) * 256 + t;
        if (n < 896) {
            float su = 0.f, sw = 0.f;
            if (n < FFD) {
                for (int k = 0; k < DIM; ++k) {
                    float wvv = f1[(size_t)k * FFD + n];
                    su += g2[k] * wvv;
                    sw += b2[k] * wvv;
                }
                sw += f1b[n];
            }
            uw[1536 + n] = su;
            uw[2432 + n] = sw;
        }
    }
}

// ---------------- embedding ----------------
__global__ __launch_bounds__(256) void embed_kernel(const float* __restrict__ x,
        const float* __restrict__ emb, bf16* __restrict__ x1, bf16* __restrict__ x2) {
    int idx = blockIdx.x * 256 + threadIdx.x;      // NTOK*25
    if (idx >= NTOK * 25) return;
    int t = idx / 25, c = idx % 25;
    int row = (x[t] > 0.f) ? 5 : 1;
    const float4* e4 = (const float4*)(emb + row * DIM + c * 8);
    float4 e0 = e4[0], e1 = e4[1];
    s8v o;
    o[0] = (short)f2u(e0.x); o[1] = (short)f2u(e0.y);
    o[2] = (short)f2u(e0.z); o[3] = (short)f2u(e0.w);
    o[4] = (short)f2u(e1.x); o[5] = (short)f2u(e1.y);
    o[6] = (short)f2u(e1.z); o[7] = (short)f2u(e1.w);
    size_t off = (size_t)t * DIM + c * 8;
    *(s8v*)((short*)x1 + off) = o;
    *(s8v*)((short*)x2 + off) = o;
}

// ---------------- LN stats (one wave per token row of 200) ----------------
__global__ __launch_bounds__(256) void lnstats_kernel(const bf16* __restrict__ in,
        float* __restrict__ mu_o, float* __restrict__ rstd_o) {
    int lane = threadIdx.x & 63;
    size_t t = (size_t)blockIdx.x * 4 + (threadIdx.x >> 6);
    const u16* row = (const u16*)in + t * DIM;
    float v0 = 0.f, v1 = 0.f, v2 = 0.f, v3 = 0.f;
    if (lane < 50) {
        ushort4 u4 = ((const ushort4*)row)[lane];
        v0 = bfu(u4.x); v1 = bfu(u4.y); v2 = bfu(u4.z); v3 = bfu(u4.w);
    }
    float s = v0 + v1 + v2 + v3, qq = v0*v0 + v1*v1 + v2*v2 + v3*v3;
    #pragma unroll
    for (int o = 32; o > 0; o >>= 1) { s += __shfl_xor(s, o); qq += __shfl_xor(qq, o); }
    if (lane == 0) {
        float mu = s * (1.f / DIM);
        mu_o[t] = mu;
        rstd_o[t] = rsqrtf(qq * (1.f / DIM) - mu * mu + 1e-5f);
    }
}

__global__ __launch_bounds__(256) void finalln_kernel(const bf16* __restrict__ in1,
        const bf16* __restrict__ in2, const float* __restrict__ g,
        const float* __restrict__ b, bf16* __restrict__ out) {
    int lane = threadIdx.x & 63;
    size_t t = (size_t)blockIdx.x * 4 + (threadIdx.x >> 6);
    const u16* r1 = (const u16*)in1 + t * DIM;
    const u16* r2 = (const u16*)in2 + t * DIM;
    float v0 = 0.f, v1 = 0.f, v2 = 0.f, v3 = 0.f;
    if (lane < 50) {
        ushort4 a4 = ((const ushort4*)r1)[lane];
        ushort4 b4 = ((const ushort4*)r2)[lane];
        v0 = 0.5f * (bfu(a4.x) + bfu(b4.x));
        v1 = 0.5f * (bfu(a4.y) + bfu(b4.y));
        v2 = 0.5f * (bfu(a4.z) + bfu(b4.z));
        v3 = 0.5f * (bfu(a4.w) + bfu(b4.w));
    }
    float s = v0 + v1 + v2 + v3, qq = v0*v0 + v1*v1 + v2*v2 + v3*v3;
    #pragma unroll
    for (int o = 32; o > 0; o >>= 1) { s += __shfl_xor(s, o); qq += __shfl_xor(qq, o); }
    float mu = s * (1.f / DIM);
    float rstd = rsqrtf(qq * (1.f / DIM) - mu * mu + 1e-5f);
    if (lane < 50) {
        float4 g4 = ((const float4*)g)[lane];
        float4 b4f = ((const float4*)b)[lane];
        ushort4 o4;
        o4.x = f2u((v0 - mu) * rstd * g4.x + b4f.x);
        o4.y = f2u((v1 - mu) * rstd * g4.y + b4f.y);
        o4.z = f2u((v2 - mu) * rstd * g4.z + b4f.z);
        o4.w = f2u((v3 - mu) * rstd * g4.w + b4f.w);
        ((ushort4*)((u16*)out + t * DIM))[lane] = o4;
    }
}

// ---------------- mat_fused: ff-phase1-style GEMM for KV / Q / WO ----------
// MODE 0: KV (4 chunks, LN-fold, head-blocked k/v stores)
// MODE 1: Q  (2 chunks, LN-fold, head-blocked q store)
// MODE 2: WO (2 chunks, x1 += acc + bias; fused LN2 stats out)
// BM=64 rows/block; A staged to LDS ONCE; B panel double-buffered (1 bar/kt).
template<int MODE>
__global__ __launch_bounds__(256, 2) void mat_fused(
        const bf16* __restrict__ A, const bf16* __restrict__ panel,
        const float* __restrict__ uvec, const float* __restrict__ wvec,
        const float* __restrict__ mu_in, const float* __restrict__ rstd_in,
        bf16* __restrict__ dst0, bf16* __restrict__ dst1,
        float* __restrict__ mu_out, float* __restrict__ rstd_out) {
    constexpr int NCH = (MODE == 0) ? 4 : 2;
    __shared__ __align__(16) short Ax[64 * 256];     // 32KB
    __shared__ __align__(16) short Bs[2 * 128 * 32]; // 16KB (2 halves)
    int bm = blockIdx.x * 64;
    int t = threadIdx.x, l = t & 63, w = t >> 6;
    int wrA = (w >> 1) * 32;
    int wcA = (w & 1) * 64;
    int lr = l & 15, lk16 = l >> 4;
    int r0 = (l >> 4) * 4;
    const short* Ash = (const short*)A;
    const short* P = (const short*)panel;

    // ---- stage A tile once ----
    {
        int c = l & 31, rsub = l >> 5;
        #pragma unroll
        for (int j = 0; j < 8; ++j) {
            int row0 = w * 16 + j * 2;
            int row = row0 + rsub;
            gld_lds16(Ash + (size_t)(bm + row) * DIM + ((c ^ (row & 7)) * 8),
                      &Ax[row0 * 256]);
        }
    }

    float rsum[2][4], rsq[2][4];
    #pragma unroll
    for (int fi = 0; fi < 2; ++fi)
        #pragma unroll
        for (int r = 0; r < 4; ++r) { rsum[fi][r] = 0.f; rsq[fi][r] = 0.f; }

    int srow0 = 32 * w + (l >> 2);
    int c16 = l & 3;
    #pragma unroll 1
    for (int ch = 0; ch < NCH; ++ch) {
        __syncthreads();   // prev chunk's Bs reads done (ch=0: no-op ordering)
        // prologue: stage kt=0 into half 0
        #pragma unroll
        for (int j = 0; j < 2; ++j) {
            int row = srow0 + 16 * j;
            int xc = (c16 ^ ((row >> 1) & 3)) * 8;
            gld_lds16(P + (size_t)(ch * 128 + row) * KPAD + 0 + xc,
                      &Bs[(32 * w + 16 * j) * 32]);
        }
        __syncthreads();   // drains Ax (ch=0) + B kt0
        f4v acc1[2][4];
        #pragma unroll
        for (int i = 0; i < 2; ++i)
            #pragma unroll
            for (int j = 0; j < 4; ++j) acc1[i][j] = (f4v){0.f, 0.f, 0.f, 0.f};
        #pragma unroll 1
        for (int kt = 0; kt < 7; ++kt) {
            if (kt < 6) {  // issue next k-tile into other half
                int k0n = (kt + 1) * 32;
                int hb = ((kt + 1) & 1) * 4096;
                #pragma unroll
                for (int j = 0; j < 2; ++j) {
                    int row = srow0 + 16 * j;
                    int xc = (c16 ^ ((row >> 1) & 3)) * 8;
                    gld_lds16(P + (size_t)(ch * 128 + row) * KPAD + k0n + xc,
                              &Bs[hb + (32 * w + 16 * j) * 32]);
                }
            }
            int hb = (kt & 1) * 4096;
            s8v a[2], b[4];
            int cg = kt * 4 + lk16;
            #pragma unroll
            for (int fi = 0; fi < 2; ++fi) {
                int R = wrA + fi * 16 + lr;
                a[fi] = *(const s8v*)&Ax[R * 256 + ((cg ^ (R & 7)) * 8)];
            }
            #pragma unroll
            for (int fj = 0; fj < 4; ++fj) {
                int R = wcA + fj * 16 + lr;
                b[fj] = *(const s8v*)&Bs[hb + R * 32 + ((lk16 ^ ((R >> 1) & 3)) * 8)];
            }
            #pragma unroll
            for (int fi = 0; fi < 2; ++fi)
                #pragma unroll
                for (int fj = 0; fj < 4; ++fj)
                    acc1[fi][fj] = MFMA16(a[fi], b[fj], acc1[fi][fj]);
            __syncthreads();   // next half ready (vmcnt drained) + reads done
        }
        // ---- per-chunk epilogue ----
        #pragma unroll
        for (int fi = 0; fi < 2; ++fi) {
            int rowb = bm + wrA + fi * 16 + r0;
            f4v rs, mm;
            if (MODE != 2) {
                rs = *(const f4v*)&rstd_in[rowb];
                mm = *(const f4v*)&mu_in[rowb];
            }
            #pragma unroll
            for (int fj = 0; fj < 4; ++fj) {
                int col = ch * 128 + wcA + fj * 16 + lr;
                if (MODE == 0) {
                    int cc = col & 255;
                    if (cc < DIM) {
                        bf16* dst = (col < 256) ? dst0 : dst1;
                        int hh = cc / DH, dd = cc % DH;
                        float ww = wvec[col], uu = uvec[col];
                        #pragma unroll
                        for (int r = 0; r < 4; ++r) {
                            size_t idx = (size_t)hh * HSTRIDE
                                       + (size_t)(rowb + r) * DH + dd;
                            float v = rs[r] * acc1[fi][fj][r]
                                    - mm[r] * rs[r] * uu + ww;
                            dst[idx] = f2b(v);
                        }
                    }
                } else if (MODE == 1) {
                    if (col < DIM) {
                        int hh = col / DH, dd = col % DH;
                        float ww = wvec[col], uu = uvec[col];
                        #pragma unroll
                        for (int r = 0; r < 4; ++r) {
                            size_t idx = (size_t)hh * HSTRIDE
                                       + (size_t)(rowb + r) * DH + dd;
                            float v = rs[r] * acc1[fi][fj][r]
                                    - mm[r] * rs[r] * uu + ww;
                            dst0[idx] = f2b(v);
                        }
                    }
                } else {   // MODE 2: x1 += acc + bias; accumulate LN2 stats
                    if (col < DIM) {
                        float bb = wvec[col];
                        #pragma unroll
                        for (int r = 0; r < 4; ++r) {
                            size_t idx = (size_t)(rowb + r) * DIM + col;
                            float v = acc1[fi][fj][r] + bb + b2f(dst0[idx]);
                            dst0[idx] = f2b(v);
                            rsum[fi][r] += v;
                            rsq[fi][r] += v * v;
                        }
                    }
                }
            }
        }
    }
    if (MODE == 2) {
        // lane-reduce over 16 lr lanes, then cross-half combine via Bs scratch
        #pragma unroll
        for (int fi = 0; fi < 2; ++fi)
            #pragma unroll
            for (int r = 0; r < 4; ++r) {
                float s = rsum[fi][r], q = rsq[fi][r];
                #pragma unroll
                for (int o = 8; o > 0; o >>= 1) {
                    s += __shfl_xor(s, o);
                    q += __shfl_xor(q, o);
                }
                rsum[fi][r] = s; rsq[fi][r] = q;
            }
        float* sp = (float*)Bs;      // [64][2(half)][2(sum,sq)] — Bs dead now
        if (lr == 0) {
            #pragma unroll
            for (int fi = 0; fi < 2; ++fi)
                #pragma unroll
                for (int r = 0; r < 4; ++r) {
                    int rowL = wrA + fi * 16 + r0 + r;
                    sp[rowL * 4 + (w & 1) * 2 + 0] = rsum[fi][r];
                    sp[rowL * 4 + (w & 1) * 2 + 1] = rsq[fi][r];
                }
        }
        __syncthreads();
        if (t < 64) {
            float s = sp[t * 4 + 0] + sp[t * 4 + 2];
            float q = sp[t * 4 + 1] + sp[t * 4 + 3];
            float mu = s * (1.f / DIM);
            mu_out[bm + t] = mu;
            rstd_out[bm + t] = rsqrtf(q * (1.f / DIM) - mu * mu + 1e-5f);
        }
    }
}

// ---------------- fused FF: x2 += gelu(LN(x1)@W1+b1) @ W2 + b2 --------------
__global__ __launch_bounds__(256, 2) void ff_fused(
        const bf16* __restrict__ x1, const bf16* __restrict__ pF1,
        const bf16* __restrict__ pF2, const float* __restrict__ u1,
        const float* __restrict__ w1f, const float* __restrict__ fb2,
        const float* __restrict__ mu_in, const float* __restrict__ rstd_in,
        float* __restrict__ mu_out, float* __restrict__ rstd_out,
        bf16* __restrict__ x2) {
    __shared__ __align__(16) short Ax[64 * 256];    // 32KB
    __shared__ __align__(16) short Bs[2 * 128 * 32]; // 16KB (2 halves / full)
    __shared__ __align__(16) short hS[64 * HSROW];  // 16.5KB (stats overlay)
    int bm = blockIdx.x * 64;
    int t = threadIdx.x, l = t & 63, w = t >> 6;
    int wrA = (w >> 1) * 32;          // rows (both phases)
    int wcA = (w & 1) * 64;           // phase-1 hidden cols
    int wcB = (w & 1) * 128;          // phase-2 output cols
    int lr = l & 15, lk16 = l >> 4;
    int r0 = (l >> 4) * 4;
    const short* X1 = (const short*)x1;
    const short* F1 = (const short*)pF1;
    const short* F2 = (const short*)pF2;

    // ---- stage x1 tile once ----
    {
        int c = l & 31, rsub = l >> 5;
        #pragma unroll
        for (int j = 0; j < 8; ++j) {
            int row0 = w * 16 + j * 2;
            int row = row0 + rsub;
            gld_lds16(X1 + (size_t)(bm + row) * DIM + ((c ^ (row & 7)) * 8),
                      &Ax[row0 * 256]);
        }
    }

    f4v acc2[2][8];
    #pragma unroll
    for (int i = 0; i < 2; ++i)
        #pragma unroll
        for (int j = 0; j < 8; ++j) acc2[i][j] = (f4v){0.f, 0.f, 0.f, 0.f};

    int srow0 = 32 * w + (l >> 2);
    int c16 = l & 3;
    #pragma unroll 1
    for (int hc = 0; hc < 7; ++hc) {
        __syncthreads();   // prev phase-2 Bs reads done; (hc=0: drains nothing)
        // prologue: stage kt=0 into half 0
        #pragma unroll
        for (int j = 0; j < 2; ++j) {
            int row = srow0 + 16 * j;
            int xc = (c16 ^ ((row >> 1) & 3)) * 8;
            gld_lds16(F1 + (size_t)(hc * 128 + row) * KPAD + 0 + xc,
                      &Bs[(32 * w + 16 * j) * 32]);
        }
        __syncthreads();   // drains Ax (hc=0) + F1 kt0
        // ---- phase 1: h_chunk[64][128], dbuf, 1 barrier per kt ----
        f4v acc1[2][4];
        #pragma unroll
        for (int i = 0; i < 2; ++i)
            #pragma unroll
            for (int j = 0; j < 4; ++j) acc1[i][j] = (f4v){0.f, 0.f, 0.f, 0.f};
        #pragma unroll 1
        for (int kt = 0; kt < 7; ++kt) {
            if (kt < 6) {  // issue next k-tile into other half (no barrier)
                int k0n = (kt + 1) * 32;
                int hb = ((kt + 1) & 1) * 4096;
                #pragma unroll
                for (int j = 0; j < 2; ++j) {
                    int row = srow0 + 16 * j;
                    int xc = (c16 ^ ((row >> 1) & 3)) * 8;
                    gld_lds16(F1 + (size_t)(hc * 128 + row) * KPAD + k0n + xc,
                              &Bs[hb + (32 * w + 16 * j) * 32]);
                }
            }
            int hb = (kt & 1) * 4096;
            s8v a[2], b[4];
            int cg = kt * 4 + lk16;     // logical k-chunk 0..27
            #pragma unroll
            for (int fi = 0; fi < 2; ++fi) {
                int R = wrA + fi * 16 + lr;
                a[fi] = *(const s8v*)&Ax[R * 256 + ((cg ^ (R & 7)) * 8)];
            }
            #pragma unroll
            for (int fj = 0; fj < 4; ++fj) {
                int R = wcA + fj * 16 + lr;
                b[fj] = *(const s8v*)&Bs[hb + R * 32 + ((lk16 ^ ((R >> 1) & 3)) * 8)];
            }
            #pragma unroll
            for (int fi = 0; fi < 2; ++fi)
                #pragma unroll
                for (int fj = 0; fj < 4; ++fj)
                    acc1[fi][fj] = MFMA16(a[fi], b[fj], acc1[fi][fj]);
            __syncthreads();   // next half ready (vmcnt drained) + reads done
        }
        // pre-stage F2 ks=0 (Bs free after last phase-1 barrier)
        #pragma unroll
        for (int j = 0; j < 4; ++j) {
            int row = (w * 4 + j) * 16 + (l >> 2);
            int xc = (c16 ^ ((row >> 1) & 3)) * 8;
            gld_lds16(F2 + (size_t)row * 800 + hc * 128 + 0 + xc,
                      &Bs[(w * 4 + j) * 16 * 32]);
        }
        // h epilogue -> hS (stride HSROW, chunk ^ row&7 swizzle)
        #pragma unroll
        for (int fi = 0; fi < 2; ++fi) {
            int rowL = wrA + fi * 16 + r0;
            f4v rs = *(const f4v*)&rstd_in[bm + rowL];
            f4v mm = *(const f4v*)&mu_in[bm + rowL];
            #pragma unroll
            for (int fj = 0; fj < 4; ++fj) {
                int col = wcA + fj * 16 + lr;
                int gcol = hc * 128 + col;
                float uu = u1[gcol], ww = w1f[gcol];
                #pragma unroll
                for (int r = 0; r < 4; ++r) {
                    float v = rs[r] * acc1[fi][fj][r] - mm[r] * rs[r] * uu + ww;
                    v = gelu_f(v);
                    int rr = rowL + r;
                    hS[rr * HSROW + (((col >> 3) ^ (rr & 7)) * 8) + (col & 7)]
                        = (short)f2u(v);
                }
            }
        }
        // ---- phase 2: acc2 += h_chunk @ W2chunk (K=128) ----
        #pragma unroll 1
        for (int ks = 0; ks < 4; ++ks) {
            if (ks) {           // stage F2 ks (ks=0 already in flight)
                __syncthreads();   // prev Bs reads done
                #pragma unroll
                for (int j = 0; j < 4; ++j) {
                    int row = (w * 4 + j) * 16 + (l >> 2);
                    int xc = (c16 ^ ((row >> 1) & 3)) * 8;
                    gld_lds16(F2 + (size_t)row * 800 + hc * 128 + ks * 32 + xc,
                              &Bs[(w * 4 + j) * 16 * 32]);
                }
            }
            __syncthreads();    // F2(ks) ready + hS visible
            s8v a[2];
            int cg = ks * 4 + lk16;
            #pragma unroll
            for (int fi = 0; fi < 2; ++fi) {
                int R = wrA + fi * 16 + lr;
                a[fi] = *(const s8v*)&hS[R * HSROW + ((cg ^ (R & 7)) * 8)];
            }
            #pragma unroll
            for (int fj = 0; fj < 8; ++fj) {
                int Br = wcB + fj * 16 + lr;
                s8v bfr = *(const s8v*)&Bs[Br * 32 + ((lk16 ^ ((Br >> 1) & 3)) * 8)];
                #pragma unroll
                for (int fi = 0; fi < 2; ++fi)
                    acc2[fi][fj] = MFMA16(a[fi], bfr, acc2[fi][fj]);
            }
        }
    }
    // ---- final epilogue: x2 += acc2 + b2, plus next-layer LN1 stats ----
    __syncthreads();                 // all hS reads done; overlay stats on hS
    float* sp = (float*)hS;          // [64][2(half)][2(sum,sq)]
    float rsum[2][4], rsq[2][4];
    #pragma unroll
    for (int fi = 0; fi < 2; ++fi)
        #pragma unroll
        for (int r = 0; r < 4; ++r) { rsum[fi][r] = 0.f; rsq[fi][r] = 0.f; }
    #pragma unroll
    for (int fi = 0; fi < 2; ++fi) {
        int rowb = bm + wrA + fi * 16 + r0;
        #pragma unroll
        for (int fj = 0; fj < 8; ++fj) {
            int col = wcB + fj * 16 + lr;
            if (col < DIM) {
                float bb = fb2[col];
                #pragma unroll
                for (int r = 0; r < 4; ++r) {
                    size_t idx = (size_t)(rowb + r) * DIM + col;
                    float v = acc2[fi][fj][r] + bb + b2f(x2[idx]);
                    x2[idx] = f2b(v);
                    rsum[fi][r] += v;
                    rsq[fi][r] += v * v;
                }
            }
        }
    }
    #pragma unroll
    for (int fi = 0; fi < 2; ++fi)
        #pragma unroll
        for (int r = 0; r < 4; ++r) {
            float s = rsum[fi][r], q = rsq[fi][r];
            #pragma unroll
            for (int o = 8; o > 0; o >>= 1) {
                s += __shfl_xor(s, o);
                q += __shfl_xor(q, o);
            }
            rsum[fi][r] = s; rsq[fi][r] = q;
        }
    if (lr == 0) {
        #pragma unroll
        for (int fi = 0; fi < 2; ++fi)
            #pragma unroll
            for (int r = 0; r < 4; ++r) {
                int rowL = wrA + fi * 16 + r0 + r;
                sp[rowL * 4 + (w & 1) * 2 + 0] = rsum[fi][r];
                sp[rowL * 4 + (w & 1) * 2 + 1] = rsq[fi][r];
            }
    }
    __syncthreads();
    if (t < 64) {
        float s = sp[t * 4 + 0] + sp[t * 4 + 2];
        float q = sp[t * 4 + 1] + sp[t * 4 + 3];
        float mu = s * (1.f / DIM);
        mu_out[bm + t] = mu;
        rstd_out[bm + t] = rsqrtf(q * (1.f / DIM) - mu * mu + 1e-5f);
    }
}

// ---- MFMA kvctx with ONLINE per-(n,h) max; k/v HEAD-BLOCKED [h][tok][20] ---
__global__ __launch_bounds__(256) void kvctx_mfma(const bf16* __restrict__ k,
        const bf16* __restrict__ v, const float* __restrict__ proj,
        float* __restrict__ ctxg) {
    __shared__ __align__(16) short ph[64 * KNROW];
    __shared__ __align__(16) short pl[64 * KNROW];
    __shared__ __align__(16) short knh[128 * KNROW];
    __shared__ __align__(16) short knl[128 * KNROW];
    __shared__ __align__(16) short vT[32 * VROW];
    __shared__ __align__(16) short kp[64 * KPROW];
    __shared__ __align__(16) float diag[128];
    __shared__ float wmax[4];
    int nh = blockIdx.x, n = nh / HEADS, h = nh % HEADS;
    int t = threadIdx.x, l = t & 63, w = t >> 6;
    int lr = l & 15, lk = (l >> 4) * 8, l4 = (l >> 4) * 4;
    const u16* kbase = (const u16*)k + (size_t)h * HSTRIDE;
    const u16* vbase = (const u16*)v + (size_t)h * HSTRIDE;
    for (int i = t; i < 64 * 32; i += 256) {
        int m = i >> 5, d = i & 31;
        float val = (m < NBF && d < DH) ? proj[m * DH + d] : 0.f;
        u16 hi = f2u(val);
        ph[m * KNROW + d] = (short)hi;
        pl[m * KNROW + d] = (short)f2u(val - bfu(hi));
    }
    for (int i = t; i < 128 * 12; i += 256) {
        int s = i / 12, d = 20 + i % 12;
        knh[s * KNROW + d] = 0; knl[s * KNROW + d] = 0;
    }
    for (int i = t; i < 12 * 128; i += 256) {
        int d = 20 + (i >> 7), s = i & 127;
        vT[d * VROW + s] = (short)((d == 20) ? f2u(1.0f) : 0);
    }
    s8v ones;
    #pragma unroll
    for (int i = 0; i < 8; ++i) ones[i] = (short)f2u(1.0f);
    float Mrun = -3.0e38f;
    f4v cd0 = {0.f,0.f,0.f,0.f}, cd1 = {0.f,0.f,0.f,0.f};
    f4v vs0 = {0.f,0.f,0.f,0.f}, vs1 = {0.f,0.f,0.f,0.f};
    for (int c = 0; c < 16; ++c) {
        int s0 = c * 128;
        __syncthreads();
        if (t < 128) {          // waves 0,1: stage kn hi/lo + diag
            int s = t;
            const u16* kr = kbase + (size_t)(n * SEQ + s0 + s) * DH;
            float dg = 0.f;
            #pragma unroll
            for (int q5 = 0; q5 < 5; ++q5) {
                ushort4 u4 = ((const ushort4*)kr)[q5];
                float f0 = bfu(u4.x) * SCALE, f1 = bfu(u4.y) * SCALE;
                float f2_ = bfu(u4.z) * SCALE, f3 = bfu(u4.w) * SCALE;
                dg += f0*f0 + f1*f1 + f2_*f2_ + f3*f3;
                u16 h0 = f2u(f0), h1 = f2u(f1), h2 = f2u(f2_), h3 = f2u(f3);
                s4v hv = {(short)h0, (short)h1, (short)h2, (short)h3};
                *(s4v*)&knh[s * KNROW + q5 * 4] = hv;
                s4v lv = {(short)f2u(f0 - bfu(h0)), (short)f2u(f1 - bfu(h1)),
                          (short)f2u(f2_ - bfu(h2)), (short)f2u(f3 - bfu(h3))};
                *(s4v*)&knl[s * KNROW + q5 * 4] = lv;
            }
            diag[s] = 0.5f * dg;
        } else {                // waves 2,3: stage vT (scatter to [d][s])
            int s = t - 128;
            const u16* vr = vbase + (size_t)(n * SEQ + s0 + s) * DH;
            #pragma unroll
            for (int q5 = 0; q5 < 5; ++q5) {
                ushort4 u4 = ((const ushort4*)vr)[q5];
                vT[(q5 * 4 + 0) * VROW + s] = (short)u4.x;
                vT[(q5 * 4 + 1) * VROW + s] = (short)u4.y;
                vT[(q5 * 4 + 2) * VROW + s] = (short)u4.z;
                vT[(q5 * 4 + 3) * VROW + s] = (short)u4.w;
            }
        }
        __syncthreads();
        s8v ah0 = *(const s8v*)&knh[(32 * w + lr) * KNROW + lk];
        s8v al0 = *(const s8v*)&knl[(32 * w + lr) * KNROW + lk];
        s8v ah1 = *(const s8v*)&knh[(32 * w + 16 + lr) * KNROW + lk];
        s8v al1 = *(const s8v*)&knl[(32 * w + 16 + lr) * KNROW + lk];
        f4v dg0 = *(const f4v*)&diag[32 * w + l4];
        f4v dg1 = *(const f4v*)&diag[32 * w + 16 + l4];
        f4v D0[4], D1[4];
        #pragma unroll
        for (int mt = 0; mt < 4; ++mt) {
            s8v bh = *(const s8v*)&ph[(mt * 16 + lr) * KNROW + lk];
            s8v bl = *(const s8v*)&pl[(mt * 16 + lr) * KNROW + lk];
            f4v d0 = {0.f, 0.f, 0.f, 0.f}, d1 = {0.f, 0.f, 0.f, 0.f};
            d0 = MFMA16(ah0, bh, d0); d0 = MFMA16(ah0, bl, d0); d0 = MFMA16(al0, bh, d0);
            d1 = MFMA16(ah1, bh, d1); d1 = MFMA16(ah1, bl, d1); d1 = MFMA16(al1, bh, d1);
            D0[mt] = d0; D1[mt] = d1;
        }
        float mm = -3.0e38f;
        #pragma unroll
        for (int mt = 0; mt < 4; ++mt) {
            int lim = (mt < 3) ? 16 : (NBF - 48);
            if (lr < lim) {
                #pragma unroll
                for (int r = 0; r < 4; ++r)
                    mm = fmaxf(mm, fmaxf(D0[mt][r], D1[mt][r]));
            }
        }
        #pragma unroll
        for (int o = 32; o > 0; o >>= 1) mm = fmaxf(mm, __shfl_xor(mm, o));
        if (l == 0) wmax[w] = mm;
        __syncthreads();
        float Mnew = fmaxf(fmaxf(wmax[0], wmax[1]), fmaxf(wmax[2], wmax[3]));
        Mnew = fmaxf(Mrun, Mnew);
        float scl = __expf(Mrun - Mnew);
        #pragma unroll
        for (int r = 0; r < 4; ++r) { cd0[r] *= scl; cd1[r] *= scl; }
        Mrun = Mnew;
        #pragma unroll
        for (int mt = 0; mt < 4; ++mt) {
            int m = mt * 16 + lr;
            bool valid = m < NBF;
            s4v o0, o1;
            #pragma unroll
            for (int r = 0; r < 4; ++r) {
                float kp0 = valid ? __expf(D0[mt][r] - dg0[r] - Mnew) : 0.f;
                float kp1 = valid ? __expf(D1[mt][r] - dg1[r] - Mnew) : 0.f;
                o0[r] = (short)f2u(kp0);
                o1[r] = (short)f2u(kp1);
            }
            *(s4v*)&kp[m * KPROW + 32 * w + l4] = o0;
            *(s4v*)&kp[m * KPROW + 32 * w + 16 + l4] = o1;
        }
        __syncthreads();
        #pragma unroll
        for (int ks = 0; ks < 4; ++ks) {
            s8v a  = *(const s8v*)&kp[(16 * w + lr) * KPROW + ks * 32 + lk];
            s8v b0 = *(const s8v*)&vT[lr * VROW + ks * 32 + lk];
            s8v b1 = *(const s8v*)&vT[(16 + lr) * VROW + ks * 32 + lk];
            cd0 = MFMA16(a, b0, cd0);
            cd1 = MFMA16(a, b1, cd1);
            vs0 = MFMA16(ones, b0, vs0);
            vs1 = MFMA16(ones, b1, vs1);
        }
    }
    float* cg = ctxg + (size_t)nh * CTXR * 64;
    int m0 = 16 * w + l4;
    f4v r0v, r1v;
    #pragma unroll
    for (int r = 0; r < 4; ++r) {
        r0v[r] = RATIO * (cd0[r] + KEPS * vs0[r]);
        r1v[r] = RATIO * (cd1[r] + KEPS * vs1[r]);
    }
    *(f4v*)&cg[lr * 64 + m0] = r0v;
    if (lr < 5) *(f4v*)&cg[(16 + lr) * 64 + m0] = r1v;
}

// ---- MFMA qattn: q HEAD-BLOCKED [h][tok][20]; split 4; ao [tok][DIM] -------
__global__ __launch_bounds__(256) void qattn_mfma(const bf16* __restrict__ q,
        const float* __restrict__ proj, const float* __restrict__ ctxg,
        bf16* __restrict__ ao) {
    __shared__ __align__(16) short ph[64 * KNROW];
    __shared__ __align__(16) short pl[64 * KNROW];
    __shared__ __align__(16) short qnh[128 * KNROW];
    __shared__ __align__(16) short qnl[128 * KNROW];
    __shared__ __align__(16) short qp[128 * QPROW];
    __shared__ __align__(16) short cT[32 * QPROW];
    __shared__ __align__(16) float dgs[128];
    __shared__ __align__(16) float osf[128][22];
    int b = blockIdx.x;
    int nh = b >> 2, sc = b & 3;
    int n = nh / HEADS, h = nh % HEADS;
    int t = threadIdx.x, l = t & 63, w = t >> 6;
    int lr = l & 15, lk = (l >> 4) * 8, l4 = (l >> 4) * 4;
    const u16* qbase = (const u16*)q + (size_t)h * HSTRIDE;
    for (int i = t; i < 64 * 32; i += 256) {
        int m = i >> 5, d = i & 31;
        float val = (m < NBF && d < DH) ? proj[m * DH + d] : 0.f;
        u16 hi = f2u(val);
        ph[m * KNROW + d] = (short)hi;
        pl[m * KNROW + d] = (short)f2u(val - bfu(hi));
    }
    for (int i = t; i < 128 * 12; i += 256) {
        int s = i / 12, d = 20 + i % 12;
        qnh[s * KNROW + d] = 0; qnl[s * KNROW + d] = 0;
    }
    for (int i = t; i < 32 * 64; i += 256) {
        int d = i >> 6, m = i & 63;
        float val = (d < CTXR) ? ctxg[(size_t)nh * CTXR * 64 + d * 64 + m] : 0.f;
        cT[d * QPROW + m] = (short)f2u(val);
    }
    for (int c = 0; c < 4; ++c) {
        int s0 = (sc * 4 + c) * 128;
        __syncthreads();
        if (t < 128) {
            int s = t;
            const u16* qr = qbase + (size_t)(n * SEQ + s0 + s) * DH;
            float dg = 0.f;
            #pragma unroll
            for (int q5 = 0; q5 < 5; ++q5) {
                ushort4 u4 = ((const ushort4*)qr)[q5];
                float f0 = bfu(u4.x) * SCALE, f1 = bfu(u4.y) * SCALE;
                float f2_ = bfu(u4.z) * SCALE, f3 = bfu(u4.w) * SCALE;
                dg += f0*f0 + f1*f1 + f2_*f2_ + f3*f3;
                u16 h0 = f2u(f0), h1 = f2u(f1), h2 = f2u(f2_), h3 = f2u(f3);
                s4v hv = {(short)h0, (short)h1, (short)h2, (short)h3};
                *(s4v*)&qnh[s * KNROW + q5 * 4] = hv;
                s4v lv = {(short)f2u(f0 - bfu(h0)), (short)f2u(f1 - bfu(h1)),
                          (short)f2u(f2_ - bfu(h2)), (short)f2u(f3 - bfu(h3))};
                *(s4v*)&qnl[s * KNROW + q5 * 4] = lv;
            }
            dgs[s] = 0.5f * dg;
        }
        __syncthreads();
        s8v ah0 = *(const s8v*)&qnh[(32 * w + lr) * KNROW + lk];
        s8v al0 = *(const s8v*)&qnl[(32 * w + lr) * KNROW + lk];
        s8v ah1 = *(const s8v*)&qnh[(32 * w + 16 + lr) * KNROW + lk];
        s8v al1 = *(const s8v*)&qnl[(32 * w + 16 + lr) * KNROW + lk];
        f4v D0[4], D1[4];
        #pragma unroll
        for (int mt = 0; mt < 4; ++mt) {
            s8v bh = *(const s8v*)&ph[(mt * 16 + lr) * KNROW + lk];
            s8v bl = *(const s8v*)&pl[(mt * 16 + lr) * KNROW + lk];
            f4v d0 = {0.f, 0.f, 0.f, 0.f}, d1 = {0.f, 0.f, 0.f, 0.f};
            d0 = MFMA16(ah0, bh, d0); d0 = MFMA16(ah0, bl, d0); d0 = MFMA16(al0, bh, d0);
            d1 = MFMA16(ah1, bh, d1); d1 = MFMA16(ah1, bl, d1); d1 = MFMA16(al1, bh, d1);
            D0[mt] = d0; D1[mt] = d1;
        }
        f4v dg0 = *(const f4v*)&dgs[32 * w + l4];
        f4v dg1 = *(const f4v*)&dgs[32 * w + 16 + l4];
        float mx0[4], mx1[4];
        #pragma unroll
        for (int r = 0; r < 4; ++r) {
            float v3 = (lr < NBF - 48) ? D0[3][r] : -3.4e38f;
            float mm = fmaxf(fmaxf(D0[0][r], D0[1][r]), fmaxf(D0[2][r], v3));
            mm = fmaxf(mm, __shfl_xor(mm, 1));
            mm = fmaxf(mm, __shfl_xor(mm, 2));
            mm = fmaxf(mm, __shfl_xor(mm, 4));
            mm = fmaxf(mm, __shfl_xor(mm, 8));
            mx0[r] = mm;
            float u3 = (lr < NBF - 48) ? D1[3][r] : -3.4e38f;
            float nn = fmaxf(fmaxf(D1[0][r], D1[1][r]), fmaxf(D1[2][r], u3));
            nn = fmaxf(nn, __shfl_xor(nn, 1));
            nn = fmaxf(nn, __shfl_xor(nn, 2));
            nn = fmaxf(nn, __shfl_xor(nn, 4));
            nn = fmaxf(nn, __shfl_xor(nn, 8));
            mx1[r] = nn;
        }
        #pragma unroll
        for (int mt = 0; mt < 4; ++mt) {
            int m = mt * 16 + lr;
            bool valid = m < NBF;
            #pragma unroll
            for (int r = 0; r < 4; ++r) {
                float p0 = valid ? RATIO * (__expf(D0[mt][r] - dg0[r] - mx0[r]) + KEPS) : 0.f;
                float p1 = valid ? RATIO * (__expf(D1[mt][r] - dg1[r] - mx1[r]) + KEPS) : 0.f;
                qp[(32 * w + l4 + r) * QPROW + m] = (short)f2u(p0);
                qp[(32 * w + 16 + l4 + r) * QPROW + m] = (short)f2u(p1);
            }
        }
        __syncthreads();
        f4v o00 = {0.f,0.f,0.f,0.f}, o01 = {0.f,0.f,0.f,0.f};
        f4v o10 = {0.f,0.f,0.f,0.f}, o11 = {0.f,0.f,0.f,0.f};
        #pragma unroll
        for (int ks = 0; ks < 2; ++ks) {
            s8v a0 = *(const s8v*)&qp[(32 * w + lr) * QPROW + ks * 32 + lk];
            s8v a1 = *(const s8v*)&qp[(32 * w + 16 + lr) * QPROW + ks * 32 + lk];
            s8v b0 = *(const s8v*)&cT[lr * QPROW + ks * 32 + lk];
            s8v b1 = *(const s8v*)&cT[(16 + lr) * QPROW + ks * 32 + lk];
            o00 = MFMA16(a0, b0, o00); o01 = MFMA16(a0, b1, o01);
            o10 = MFMA16(a1, b0, o10); o11 = MFMA16(a1, b1, o11);
        }
        #pragma unroll
        for (int r = 0; r < 4; ++r) {
            osf[32 * w + l4 + r][lr] = o00[r];
            osf[32 * w + 16 + l4 + r][lr] = o10[r];
            if (lr < 5) {
                osf[32 * w + l4 + r][16 + lr] = o01[r];
                osf[32 * w + 16 + l4 + r][16 + lr] = o11[r];
            }
        }
        __syncthreads();
        if (t < 128) osf[t][21] = 1.f / osf[t][20];
        __syncthreads();
        int tokb = n * SEQ + s0;
        for (int idx = t; idx < 128 * 10; idx += 256) {
            int row = idx / 10, seg = idx % 10;
            float di = osf[row][21];
            ushort2 o2;
            o2.x = f2u(osf[row][seg * 2] * di);
            o2.y = f2u(osf[row][seg * 2 + 1] * di);
            *(ushort2*)((u16*)ao + (size_t)(tokb + row) * DIM + h * DH + seg * 2) = o2;
        }
    }
}

// ---------------- pooling ----------------
__global__ __launch_bounds__(256) void pool1_kernel(const bf16* __restrict__ hn,
        float* __restrict__ partial) {
    int n = blockIdx.x / 16, c = blockIdx.x % 16;
    int d = threadIdx.x;
    if (d >= DIM) return;
    float acc = 0.f;
    const bf16* base = hn + ((size_t)n * SEQ + c * 128) * DIM + d;
    for (int s = 0; s < 128; ++s) acc += b2f(base[(size_t)s * DIM]);
    partial[(size_t)blockIdx.x * DIM + d] = acc;
}

__global__ __launch_bounds__(256) void pool2_kernel(const float* __restrict__ partial,
        float* __restrict__ pooled) {
    int n = blockIdx.x, d = threadIdx.x;
    if (d >= DIM) return;
    float acc = 0.f;
    for (int c = 0; c < 16; ++c) acc += partial[(size_t)(n * 16 + c) * DIM + d];
    pooled[n * DIM + d] = acc * (1.f / SEQ);
}

__global__ __launch_bounds__(512) void finalproj_kernel(const float* __restrict__ pooled,
        const float* __restrict__ pw, const float* __restrict__ pb,
        float* __restrict__ out) {
    __shared__ float ps[DIM];
    int n = blockIdx.x;
    for (int i = threadIdx.x; i < DIM; i += 512) ps[i] = pooled[n * DIM + i];
    __syncthreads();
    int j = threadIdx.x;
    float acc = pb[j];
    for (int d = 0; d < DIM; ++d) acc += ps[d] * pw[d * DMODEL + j];
    out[n * DMODEL + j] = acc;
}

// ---------------- host launch ----------------
extern "C" void kernel_launch(void* const* d_in, const int* in_sizes, int n_in,
                              void* d_out, int out_size, void* d_ws, size_t ws_size,
                              hipStream_t stream) {
    (void)in_sizes; (void)n_in; (void)out_size;
    const float* x    = (const float*)d_in[0];
    const float* emb  = (const float*)d_in[1];
    const float* ln1g = (const float*)d_in[2];
    const float* ln1b = (const float*)d_in[3];
    const float* wq   = (const float*)d_in[4];
    const float* bq   = (const float*)d_in[5];
    const float* wk   = (const float*)d_in[6];
    const float* bk   = (const float*)d_in[7];
    const float* wv   = (const float*)d_in[8];
    const float* bv   = (const float*)d_in[9];
    const float* proj = (const float*)d_in[10];
    const float* wo   = (const float*)d_in[11];
    const float* bo   = (const float*)d_in[12];
    const float* ln2g = (const float*)d_in[13];
    const float* ln2b = (const float*)d_in[14];
    const float* ffw1 = (const float*)d_in[15];
    const float* ffb1 = (const float*)d_in[16];
    const float* ffw2 = (const float*)d_in[17];
    const float* ffb2 = (const float*)d_in[18];
    const float* lnfg = (const float*)d_in[19];
    const float* lnfb = (const float*)d_in[20];
    const float* pw   = (const float*)d_in[21];
    const float* pb   = (const float*)d_in[22];
    float* out = (float*)d_out;

    const size_t A_ = (size_t)NTOK * DIM;
    bf16* x1 = (bf16*)d_ws;
    bf16* x2 = x1 + A_ + BUFPAD;
    bf16* b3 = x2 + A_ + BUFPAD;     // k -> q (head-blocked)
    bf16* b4 = b3 + A_ + BUFPAD;     // v (head-blocked) -> attn out [tok][DIM]
    bf16* pKV = b4 + A_ + BUFPAD;
    bf16* pQ  = pKV + PKV_E;
    bf16* pWO = pQ + PQ_E;
    bf16* pF1 = pWO + PWO_E;
    bf16* pF2 = pF1 + PF1_E;
    float* muB   = (float*)(pF2 + PF2_E);      // x2 / LN1 stats
    float* rstdB = muB + NTOK;
    float* muC   = rstdB + NTOK;               // x1 / LN2 stats
    float* rstdC = muC + NTOK;
    float* uw    = rstdC + NTOK;               // 3328 floats
    float* ctxg  = uw + 3328;                  // 640 * 21 * 64 floats
    float* wsend = ctxg + (size_t)NSEQ * HEADS * CTXR * 64;

    float* ukv = uw,        *wkv = uw + 512;
    float* uq  = uw + 1024, *wqf = uw + 1280;
    float* u1  = uw + 1536, *w1f = uw + 2432;

    size_t need = (char*)wsend - (char*)d_ws;
    if (ws_size < need) {
        sentinel_kernel<<<1, 64, 0, stream>>>(out, (float)(ws_size >> 20));
        return;
    }

    zeropad_kernel<<<1, 64, 0, stream>>>(x1 + A_, x2 + A_, b3 + A_, b4 + A_);
    embed_kernel<<<(NTOK * 25 + 255) / 256, 256, 0, stream>>>(x, emb, x1, x2);
    // prime LN1 stats for layer 0 (subsequent layers: computed inside ff_fused)
    lnstats_kernel<<<NTOK / 4, 256, 0, stream>>>(x2, muB, rstdB);

    for (int l = 0; l < DEPTH; ++l) {
        const float* wq_l = wq + (size_t)l * DIM * DIM;
        const float* wk_l = wk + (size_t)l * DIM * DIM;
        const float* wv_l = wv + (size_t)l * DIM * DIM;
        const float* wo_l = wo + (size_t)l * DIM * DIM;
        const float* f1_l = ffw1 + (size_t)l * DIM * FFD;
        const float* f2_l = ffw2 + (size_t)l * FFD * DIM;
        const float* pj_l = proj + (size_t)l * NBF * DH;
        const float* g1 = ln1g + l * DIM, *b1 = ln1b + l * DIM;
        const float* g2 = ln2g + l * DIM, *b2 = ln2b + l * DIM;

        prep_layer<<<2487, 256, 0, stream>>>(wq_l, wk_l, wv_l, wo_l, f1_l, f2_l,
                g1, b1, g2, b2, bq + l * DIM, bk + l * DIM, bv + l * DIM,
                ffb1 + l * FFD, pKV, pQ, pWO, pF1, pF2, uw);

        // k -> b3, v -> b4 (head-blocked, LN1-fold)
        mat_fused<0><<<NTOK / 64, 256, 0, stream>>>(x2, pKV, ukv, wkv,
                muB, rstdB, b3, b4, nullptr, nullptr);
        kvctx_mfma<<<NSEQ * HEADS, 256, 0, stream>>>(b3, b4, pj_l, ctxg);
        // q -> b3 (k dead; head-blocked, LN1-fold)
        mat_fused<1><<<NTOK / 64, 256, 0, stream>>>(x2, pQ, uq, wqf,
                muB, rstdB, b3, nullptr, nullptr, nullptr);
        // attn out -> b4 (v dead; ao is [tok][DIM])
        qattn_mfma<<<NSEQ * HEADS * 4, 256, 0, stream>>>(b3, pj_l, ctxg, b4);
        // x1 += b4 @ wo + bo, fused LN2 stats -> muC/rstdC
        mat_fused<2><<<NTOK / 64, 256, 0, stream>>>(b4, pWO, nullptr, bo + l * DIM,
                nullptr, nullptr, x1, nullptr, muC, rstdC);

        // fused FF (writes next layer's LN1 stats into muB/rstdB)
        ff_fused<<<NTOK / 64, 256, 0, stream>>>(x1, pF1, pF2, u1, w1f,
                ffb2 + l * DIM, muC, rstdC, muB, rstdB, x2);
    }

    finalln_kernel<<<NTOK / 4, 256, 0, stream>>>(x1, x2, lnfg, lnfb, b3);
    float* partial = muB;
    float* pooled  = muB + (size_t)NSEQ * 16 * DIM;
    pool1_kernel<<<NSEQ * 16, 256, 0, stream>>>(b3, partial);
    pool2_kernel<<<NSEQ, 256, 0, stream>>>(partial, pooled);
    finalproj_kernel<<<NSEQ, 512, 0, stream>>>(pooled, pw, pb, out);
}